// Round 7
// baseline (721.191 us; speedup 1.0000x reference)
//
#include <hip/hip_runtime.h>
#include <cstdint>
#include <cstddef>

#define NB1      16384      // 2^14 first-level radix bins
#define L1SHIFT  18         // key >> 18 -> 14-bit bin
#define CAP      4096       // compaction buffer per task (power of 2 for bitonic)
#define K_TOP    1000
#define NCAND    5000
#define NIMG     8
#define NLVL     5
#define NTASK    40
#define NPOST    300
#define NEGF     (-1e9f)
#define NWORDS   79         // ceil(5000/64)

typedef unsigned long long u64;

struct Ptrs {
    const float* lg[5];
    const float* dl[5];
};

__device__ __forceinline__ unsigned key_of(float f) {
    unsigned u = __float_as_uint(f);
    return (u & 0x80000000u) ? ~u : (u | 0x80000000u);
}
__device__ __forceinline__ float key_to_float(unsigned k) {
    unsigned u = (k & 0x80000000u) ? (k ^ 0x80000000u) : ~k;
    return __uint_as_float(u);
}

// ---------------- zero scratch ----------------
__global__ void kZero(unsigned* p, size_t n) {
    size_t i = (size_t)blockIdx.x * blockDim.x + threadIdx.x;
    size_t st = (size_t)gridDim.x * blockDim.x;
    for (; i < n; i += st) p[i] = 0u;
}

// ---------------- pass 1: LDS-privatized 14-bit histogram per (img,lvl) ----------------
__global__ __launch_bounds__(1024) void kHist(const float* __restrict__ lg,
                                              int m, int lvl,
                                              unsigned* __restrict__ hist) {
    int img  = blockIdx.y;
    int task = img * NLVL + lvl;
    __shared__ unsigned h[NB1];
    for (int i = threadIdx.x; i < NB1; i += 1024) h[i] = 0u;
    __syncthreads();
    int m4 = m >> 2;                       // all level sizes divisible by 4
    int chunk4 = (m4 + gridDim.x - 1) / (int)gridDim.x;
    int start4 = blockIdx.x * chunk4;
    int end4   = min(start4 + chunk4, m4);
    const float4* src = (const float4*)(lg + (size_t)img * m);
    for (int i = start4 + threadIdx.x; i < end4; i += 1024) {
        float4 v = src[i];
        atomicAdd(&h[key_of(v.x) >> L1SHIFT], 1u);
        atomicAdd(&h[key_of(v.y) >> L1SHIFT], 1u);
        atomicAdd(&h[key_of(v.z) >> L1SHIFT], 1u);
        atomicAdd(&h[key_of(v.w) >> L1SHIFT], 1u);
    }
    __syncthreads();
    unsigned* gh = hist + (size_t)task * NB1;
    for (int i = threadIdx.x; i < NB1; i += 1024) {
        unsigned c = h[i];
        if (c) atomicAdd(&gh[i], c);
    }
}

// ---------------- pass 2: find 14-bit prefix of the K-th largest ----------------
__global__ __launch_bounds__(256) void kSelectBin(const unsigned* __restrict__ hist,
                                                  unsigned* __restrict__ tinfo,
                                                  unsigned* __restrict__ cnt) {
    int task = blockIdx.x;
    const unsigned* h = hist + (size_t)task * NB1;
    __shared__ unsigned sblk[256];
    __shared__ unsigned sbin[64];
    __shared__ int sh_tb;
    __shared__ unsigned sh_rem;
    int t = threadIdx.x;
    unsigned s = 0;
    for (int i = 0; i < 64; ++i) s += h[t * 64 + i];
    sblk[t] = s;
    __syncthreads();
    if (t == 0) {
        unsigned rem = K_TOP; int tb = 0;
        for (int b = 255; b >= 0; --b) {
            if (sblk[b] < rem) rem -= sblk[b];
            else { tb = b; break; }
        }
        sh_tb = tb; sh_rem = rem;
    }
    __syncthreads();
    if (t < 64) sbin[t] = h[sh_tb * 64 + t];
    __syncthreads();
    if (t == 0) {
        unsigned rem = sh_rem; int pfx = sh_tb * 64;
        for (int b = 63; b >= 0; --b) {
            if (sbin[b] < rem) rem -= sbin[b];
            else { pfx = sh_tb * 64 + b; break; }
        }
        tinfo[task * 2]     = (unsigned)pfx;
        tinfo[task * 2 + 1] = rem;
        cnt[task] = 0u;
    }
}

// ---------------- pass 3: compact all keys with bin >= prefix ----------------
__global__ void kCompact(const float* __restrict__ lg, int m, int lvl,
                         const unsigned* __restrict__ tinfo,
                         unsigned* __restrict__ cnt,
                         u64* __restrict__ compbuf) {
    int img = blockIdx.y;
    int task = img * NLVL + lvl;
    unsigned pfx = tinfo[task * 2];
    int j = blockIdx.x * blockDim.x + threadIdx.x;
    if (j < m) {
        unsigned key = key_of(lg[(size_t)img * m + j]);
        if ((key >> L1SHIFT) >= pfx) {
            unsigned pos = atomicAdd(&cnt[task], 1u);
            if (pos < CAP)
                compbuf[(size_t)task * CAP + pos] =
                    ((u64)key << 32) | (unsigned)(~j);
        }
    }
}

// ---------------- pass 4: sort candidates, decode boxes, resort by masked score ----
__global__ __launch_bounds__(1024) void kSortSelect(
        Ptrs p,
        const unsigned* __restrict__ cnt,
        const u64* __restrict__ compbuf,
        float* __restrict__ cscore,
        float4* __restrict__ cbox,
        float4* __restrict__ cobox,
        float* __restrict__ carea,
        unsigned* __restrict__ cog) {
    int task = blockIdx.x;
    int img = task / NLVL, lvl = task % NLVL;
    __shared__ u64 sortbuf[CAP + 1024];   // 40 KB; phase-2 reused as float farr[10240]
    __shared__ u64 buf2[1024];
    u64* buf = sortbuf;
    int n = min((int)cnt[task], CAP);
    for (int i = threadIdx.x; i < CAP; i += 1024)
        buf[i] = (i < n) ? compbuf[(size_t)task * CAP + i] : 0ULL;
    __syncthreads();
    for (int k = 2; k <= CAP; k <<= 1) {
        for (int j2 = k >> 1; j2 > 0; j2 >>= 1) {
            for (int i = threadIdx.x; i < CAP; i += 1024) {
                int pp = i ^ j2;
                if (pp > i) {
                    u64 A = buf[i], B = buf[pp];
                    bool up = ((i & k) == 0);
                    if (up ? (A < B) : (A > B)) { buf[i] = B; buf[pp] = A; }
                }
            }
            __syncthreads();
        }
    }
    const int   MS[5]     = {516096, 129024, 32256, 8064, 2016};
    const int   GW[5]     = {512, 256, 128, 64, 32};
    const float STRIDEF[5]= {4.f, 8.f, 16.f, 32.f, 64.f};
    const int   SIZEI[5]  = {32, 64, 128, 256, 512};
    int r = threadIdx.x;
    float sm = 0.f, x0 = 0.f, y0 = 0.f, x1 = 0.f, y1 = 0.f;
    float b0 = 0.f, b1 = 0.f, b2 = 0.f, b3 = 0.f, area = 0.f;
    if (r < K_TOP) {
        u64 c = buf[r];
        int idx = (int)(~(unsigned)c);
        int m = MS[lvl];
        if ((unsigned)idx >= (unsigned)m) idx = 0;   // safety (never expected)
        const float* lg = p.lg[lvl];
        const float* dl = p.dl[lvl];
        float score = lg[(size_t)img * m + idx];
        int a   = idx % 3;
        int loc = idx / 3;
        int gw  = GW[lvl];
        int x = loc % gw, y = loc / gw;
        double ssz = (double)SIZEI[lvl];
        double arr = (a == 0) ? 0.5 : ((a == 1) ? 1.0 : 2.0);
        double wd = sqrt(ssz * ssz / arr);
        double hd = arr * wd;
        float sx = (float)x * STRIDEF[lvl];
        float sy = (float)y * STRIDEF[lvl];
        float a0 = sx + (float)(-wd * 0.5);
        float a1 = sy + (float)(-hd * 0.5);
        float a2 = sx + (float)( wd * 0.5);
        float a3 = sy + (float)( hd * 0.5);
        float aw = a2 - a0, ah = a3 - a1;
        float acx = a0 + 0.5f * aw, acy = a1 + 0.5f * ah;
        size_t db = ((size_t)img * m + idx) * 4;
        float dx = dl[db], dy = dl[db + 1], dwv = dl[db + 2], dhv = dl[db + 3];
        const float CL = 4.135166556742356f;   // log(1000/16)
        float pw = expf(fminf(dwv, CL)) * aw;
        float ph = expf(fminf(dhv, CL)) * ah;
        float pcx = dx * aw + acx;
        float pcy = dy * ah + acy;
        x0 = pcx - 0.5f * pw; y0 = pcy - 0.5f * ph;
        x1 = pcx + 0.5f * pw; y1 = pcy + 0.5f * ph;
        x0 = fminf(fmaxf(x0, 0.f), 2048.f);
        x1 = fminf(fmaxf(x1, 0.f), 2048.f);
        y0 = fminf(fmaxf(y0, 0.f), 1344.f);
        y1 = fminf(fmaxf(y1, 0.f), 1344.f);
        bool keep = ((x1 - x0) > 0.f) && ((y1 - y0) > 0.f);
        sm = keep ? score : NEGF;
        float off = (float)lvl * 2049.0f;
        b0 = x0 + off; b1 = y0 + off; b2 = x1 + off; b3 = y1 + off;
        area = (b2 - b0) * (b3 - b1);
    }
    __syncthreads();                 // all buf reads done before reuse as farr
    float* farr = (float*)sortbuf;   // [0,1000) score  [1000,2000) area
                                     // [2000,6000) clip box  [6000,10000) offset box
    if (r < K_TOP) {
        farr[r] = sm;
        farr[1000 + r] = area;
        farr[2000 + 4 * r]     = x0;
        farr[2000 + 4 * r + 1] = y0;
        farr[2000 + 4 * r + 2] = x1;
        farr[2000 + 4 * r + 3] = y1;
        farr[6000 + 4 * r]     = b0;
        farr[6000 + 4 * r + 1] = b1;
        farr[6000 + 4 * r + 2] = b2;
        farr[6000 + 4 * r + 3] = b3;
    }
    buf2[r] = (r < K_TOP)
        ? (((u64)key_of(sm) << 32) | (unsigned)(~(unsigned)(lvl * K_TOP + r)))
        : 0ULL;
    __syncthreads();
    for (int k = 2; k <= 1024; k <<= 1) {
        for (int j2 = k >> 1; j2 > 0; j2 >>= 1) {
            int i = r, pp = i ^ j2;
            if (pp > i) {
                u64 A = buf2[i], B = buf2[pp];
                bool up = ((i & k) == 0);
                if (up ? (A < B) : (A > B)) { buf2[i] = B; buf2[pp] = A; }
            }
            __syncthreads();
        }
    }
    if (r < K_TOP) {
        u64 c2 = buf2[r];
        unsigned g2 = ~(unsigned)c2;
        int rsrc = (int)g2 - lvl * K_TOP;    // original within-level rank
        int ci = img * NCAND + lvl * K_TOP + r;
        cscore[ci] = farr[rsrc];
        carea[ci]  = farr[1000 + rsrc];
        cbox[ci]  = make_float4(farr[2000 + 4 * rsrc],     farr[2000 + 4 * rsrc + 1],
                                farr[2000 + 4 * rsrc + 2], farr[2000 + 4 * rsrc + 3]);
        cobox[ci] = make_float4(farr[6000 + 4 * rsrc],     farr[6000 + 4 * rsrc + 1],
                                farr[6000 + 4 * rsrc + 2], farr[6000 + 4 * rsrc + 3]);
        cog[ci] = (unsigned)rsrc;
    }
}

// ---------------- pass 5a: merge 5 sorted lists into global sorted order ----------------
__global__ __launch_bounds__(1024) void kMerge(
        const float* __restrict__ cscore,
        const float4* __restrict__ cbox,
        const float4* __restrict__ cobox,
        const float* __restrict__ carea,
        const unsigned* __restrict__ cog,
        float* __restrict__ ssc,
        float4* __restrict__ sob,
        float* __restrict__ sar,
        float4* __restrict__ sclip) {
    int img = blockIdx.x;
    __shared__ u64 comp[NCAND];
    for (int g = threadIdx.x; g < NCAND; g += 1024) {
        int lv = g / K_TOP;
        unsigned og = (unsigned)(lv * K_TOP) + cog[img * NCAND + g];
        comp[g] = ((u64)key_of(cscore[img * NCAND + g]) << 32) | (unsigned)(~og);
    }
    __syncthreads();
    for (int g = threadIdx.x; g < NCAND; g += 1024) {
        u64 c = comp[g];
        int lv = g / K_TOP;
        int pos = g - lv * K_TOP;    // elements > c within own (desc-sorted) level
        for (int lv2 = 0; lv2 < NLVL; ++lv2) {
            if (lv2 == lv) continue;
            int base = lv2 * K_TOP;
            int lo = 0, hi = K_TOP;
            while (lo < hi) {
                int mid = (lo + hi) >> 1;
                if (comp[base + mid] > c) lo = mid + 1; else hi = mid;
            }
            pos += lo;               // count of elements > c (composites unique)
        }
        int src = img * NCAND + g;
        int dst = img * NCAND + pos;
        ssc[dst]   = cscore[src];
        sob[dst]   = cobox[src];
        sar[dst]   = carea[src];
        sclip[dst] = cbox[src];
    }
}

// ---------------- pass 5b+5c fused: scan with on-demand suppression ----------------
// Diagonal 64x64 IoU blocks computed in-kernel (shfl broadcast, no matrix);
// suppression of future words computed lazily at each word boundary from the
// pending emitted boxes (<=64), swept 1024-wide over future candidates.
__global__ __launch_bounds__(1024) void kScan(
        const float* __restrict__ ssc,
        const float4* __restrict__ sclip,
        const float4* __restrict__ sob,
        const float* __restrict__ sar,
        float* __restrict__ out) {
    int img = blockIdx.x;
    int tid = threadIdx.x;
    int lane = tid & 63;
    int wave = tid >> 6;
    __shared__ u64 maskS[NWORDS + 1];
    __shared__ u64 diagS[NWORDS * 64];
    __shared__ float sscS[NCAND];
    __shared__ unsigned pendS[64];
    __shared__ float4 pboxS[64];
    __shared__ float parS[64];
    const int imgb = img * NCAND;

    for (int w = tid; w < NWORDS + 1; w += 1024) maskS[w] = 0ULL;
    for (int k = tid; k < NCAND; k += 1024) sscS[k] = ssc[imgb + k];
    // diagonal blocks: wave handles block w; lane holds box j=w*64+lane;
    // row box broadcast via shfl from lane r. Bit ordering matches ballot lane.
    for (int w = wave; w < NWORDS; w += 16) {
        int j = w * 64 + lane;
        bool inb = (j < NCAND);
        float4 bj = make_float4(0.f, 0.f, 0.f, 0.f);
        float arj = 0.f;
        if (inb) { bj = sob[imgb + j]; arj = sar[imgb + j]; }
        for (int r = 0; r < 64; ++r) {
            float bix = __shfl(bj.x, r, 64), biy = __shfl(bj.y, r, 64);
            float biz = __shfl(bj.z, r, 64), biw = __shfl(bj.w, r, 64);
            float ari = __shfl(arj, r, 64);
            bool pred = false;
            if (inb) {
                float ltx = fmaxf(bj.x, bix), lty = fmaxf(bj.y, biy);
                float rbx = fminf(bj.z, biz), rby = fminf(bj.w, biw);
                float wx = fmaxf(rbx - ltx, 0.f), wy = fmaxf(rby - lty, 0.f);
                float inter = wx * wy;
                float denom = (arj + ari) - inter + 1e-9f;
                pred = (inter / denom) > 0.7f;
            }
            u64 bits = __ballot(pred);
            if (lane == 0) diagS[w * 64 + r] = bits;
        }
    }
    __syncthreads();

    int emitted = 0;
    bool done = false;
    for (int w = 0; w < NWORDS && !done; ++w) {
        u64 cur = ~maskS[w];                       // uniform across all threads
        if (w == NWORDS - 1) cur &= (1ULL << (NCAND - (NWORDS - 1) * 64)) - 1ULL;
        int npend = 0;
        while (cur) {
            int b = __builtin_ctzll(cur);
            int i = w * 64 + b;
            float sc = sscS[i];
            if (sc <= -5.0e8f) { done = true; break; }   // all later invalid too
            if (tid == 0) {
                float4 cb = sclip[imgb + i];
                float* o = out + ((size_t)img * NPOST + emitted) * 5;
                o[0] = cb.x; o[1] = cb.y; o[2] = cb.z; o[3] = cb.w; o[4] = sc;
            }
            ++emitted;
            if (emitted == NPOST) { done = true; break; }
            u64 rw = diagS[w * 64 + b];       // same-word suppression (LDS)
            cur &= ~rw;
            cur &= ~(1ULL << b);
            if (tid == 0) pendS[npend] = (unsigned)i;
            ++npend;                          // uniform
        }
        if (!done && npend) {
            __syncthreads();                  // pendS visible to all waves
            if (tid < npend) {
                unsigned ip = pendS[tid];
                pboxS[tid] = sob[imgb + ip];
                parS[tid]  = sar[imgb + ip];
            }
            __syncthreads();
            int jbase = (w + 1) * 64;
            for (int off2 = jbase + tid; off2 - tid < NCAND - 64 + 63; off2 += 1024) {
                int j = off2;
                if (j - lane >= NCAND) break;   // whole wave out of range
                bool inb = (j < NCAND);
                float4 bj = make_float4(0.f, 0.f, 0.f, 0.f);
                float arj = 0.f;
                if (inb) { bj = sob[imgb + j]; arj = sar[imgb + j]; }
                bool supp = false;
                for (int k0 = 0; k0 < npend; ++k0) {
                    float4 bp = pboxS[k0];
                    float arp = parS[k0];
                    float ltx = fmaxf(bj.x, bp.x), lty = fmaxf(bj.y, bp.y);
                    float rbx = fminf(bj.z, bp.z), rby = fminf(bj.w, bp.w);
                    float wx = fmaxf(rbx - ltx, 0.f), wy = fmaxf(rby - lty, 0.f);
                    float inter = wx * wy;
                    float denom = (arj + arp) - inter + 1e-9f;
                    supp |= (inter / denom) > 0.7f;
                }
                supp &= inb;
                u64 bits = __ballot(supp);
                if (lane == 0 && inb) maskS[j >> 6] |= bits;
            }
        }
        __syncthreads();
    }
    for (int rr = emitted + tid; rr < NPOST; rr += 1024) {
        float* o = out + ((size_t)img * NPOST + rr) * 5;
        o[0] = 0.f; o[1] = 0.f; o[2] = 0.f; o[3] = 0.f; o[4] = NEGF;
    }
}

// ---------------- fallback: round-1 sequential NMS (used only if ws too small) ----------------
__global__ __launch_bounds__(1024) void kNMS(
        const float* __restrict__ cscore,
        const float4* __restrict__ cbox,
        const float4* __restrict__ cobox,
        const float* __restrict__ carea,
        float* __restrict__ out) {
    int img = blockIdx.x;
    int tid = threadIdx.x;
    __shared__ u64 warr[16];
    __shared__ float bb[5];
    float s[5], b0[5], b1[5], b2[5], b3[5], ar[5];
#pragma unroll
    for (int k = 0; k < 5; ++k) {
        int j = tid + k * 1024;
        if (j < NCAND) {
            int ci = img * NCAND + j;
            s[k] = cscore[ci];
            float4 b = cobox[ci];
            b0[k] = b.x; b1[k] = b.y; b2[k] = b.z; b3[k] = b.w;
            ar[k] = carea[ci];
        } else {
            s[k] = -3.4e38f;
            b0[k] = b1[k] = b2[k] = b3[k] = 0.f; ar[k] = 0.f;
        }
    }
    for (int step = 0; step < NPOST; ++step) {
        u64 comp = 0ULL;
#pragma unroll
        for (int k = 0; k < 5; ++k) {
            int j = tid + k * 1024;
            unsigned kk = key_of(s[k]);
            u64 c = ((u64)kk << 32) | (unsigned)(~j);
            comp = (c > comp) ? c : comp;
        }
#pragma unroll
        for (int off2 = 32; off2 >= 1; off2 >>= 1) {
            u64 o = __shfl_xor(comp, off2, 64);
            comp = (o > comp) ? o : comp;
        }
        if ((tid & 63) == 0) warr[tid >> 6] = comp;
        __syncthreads();
        u64 best = warr[0];
#pragma unroll
        for (int w = 1; w < 16; ++w) {
            u64 o = warr[w];
            best = (o > best) ? o : best;
        }
        int bidx = (int)(~(unsigned)best);
        float bscore = key_to_float((unsigned)(best >> 32));
        bool valid = bscore > -5.0e8f;
#pragma unroll
        for (int k = 0; k < 5; ++k) {
            int j = tid + k * 1024;
            if (j == bidx) {
                bb[0] = b0[k]; bb[1] = b1[k]; bb[2] = b2[k]; bb[3] = b3[k]; bb[4] = ar[k];
                float* o = out + ((size_t)img * NPOST + step) * 5;
                if (valid) {
                    float4 gb = cbox[img * NCAND + j];
                    o[0] = gb.x; o[1] = gb.y; o[2] = gb.z; o[3] = gb.w; o[4] = bscore;
                } else {
                    o[0] = 0.f; o[1] = 0.f; o[2] = 0.f; o[3] = 0.f; o[4] = NEGF;
                }
            }
        }
        __syncthreads();
        float ib0 = bb[0], ib1 = bb[1], ib2 = bb[2], ib3 = bb[3], iar = bb[4];
#pragma unroll
        for (int k = 0; k < 5; ++k) {
            int j = tid + k * 1024;
            float ltx = fmaxf(b0[k], ib0), lty = fmaxf(b1[k], ib1);
            float rbx = fminf(b2[k], ib2), rby = fminf(b3[k], ib3);
            float wx = fmaxf(rbx - ltx, 0.f), wy = fmaxf(rby - lty, 0.f);
            float inter = wx * wy;
            float denom = ar[k] + iar;
            denom = denom - inter;
            denom = denom + 1e-9f;
            float iou = inter / denom;
            if (iou > 0.7f) s[k] = NEGF;
            if (j == bidx) s[k] = NEGF;
        }
    }
}

extern "C" void kernel_launch(void* const* d_in, const int* in_sizes, int n_in,
                              void* d_out, int out_size, void* d_ws, size_t ws_size,
                              hipStream_t stream) {
    const int MS[5] = {516096, 129024, 32256, 8064, 2016};
    Ptrs P;
    for (int l = 0; l < 5; ++l) {
        P.lg[l] = (const float*)d_in[2 * l];
        P.dl[l] = (const float*)d_in[2 * l + 1];
    }
    char* w = (char*)d_ws;
    size_t off = 0;
    auto alloc = [&](size_t bytes) -> void* {
        void* pp = (void*)(w + off);
        off = (off + bytes + 255) & ~(size_t)255;
        return pp;
    };
    unsigned* hist  = (unsigned*)alloc((size_t)NTASK * NB1 * 4);
    unsigned* tinfo = (unsigned*)alloc(NTASK * 2 * 4);
    unsigned* cnt   = (unsigned*)alloc(NTASK * 4);
    u64* compb      = (u64*)alloc((size_t)NTASK * CAP * 8);
    float*  cscore  = (float*)alloc((size_t)NTASK * K_TOP * 4);
    float4* cbox    = (float4*)alloc((size_t)NTASK * K_TOP * 16);
    float4* cobox   = (float4*)alloc((size_t)NTASK * K_TOP * 16);
    float*  carea   = (float*)alloc((size_t)NTASK * K_TOP * 4);
    unsigned* cog   = (unsigned*)alloc((size_t)NTASK * K_TOP * 4);
    // NMS scratch
    float*  ssc     = (float*)alloc((size_t)NIMG * NCAND * 4);
    float4* sob     = (float4*)alloc((size_t)NIMG * NCAND * 16);
    float*  sar     = (float*)alloc((size_t)NIMG * NCAND * 4);
    float4* sclip   = (float4*)alloc((size_t)NIMG * NCAND * 16);
    size_t need = off;
    (void)in_sizes; (void)n_in; (void)out_size;

    size_t nhz = (size_t)NTASK * NB1;
    kZero<<<2048, 256, 0, stream>>>(hist, nhz);
    for (int l = 0; l < 5; ++l) {
        int m4 = MS[l] >> 2;
        int gx = (m4 + 8191) / 8192;       // ~32K elements per block
        dim3 g(gx, NIMG);
        kHist<<<g, 1024, 0, stream>>>(P.lg[l], MS[l], l, hist);
    }
    kSelectBin<<<NTASK, 256, 0, stream>>>(hist, tinfo, cnt);
    for (int l = 0; l < 5; ++l) {
        dim3 g((MS[l] + 255) / 256, NIMG);
        kCompact<<<g, 256, 0, stream>>>(P.lg[l], MS[l], l, tinfo, cnt, compb);
    }
    kSortSelect<<<NTASK, 1024, 0, stream>>>(P, cnt, compb, cscore, cbox, cobox, carea, cog);

    if (ws_size >= need) {
        kMerge<<<NIMG, 1024, 0, stream>>>(cscore, cbox, cobox, carea, cog,
                                          ssc, sob, sar, sclip);
        kScan<<<NIMG, 1024, 0, stream>>>(ssc, sclip, sob, sar, (float*)d_out);
    } else {
        kNMS<<<NIMG, 1024, 0, stream>>>(cscore, cbox, cobox, carea, (float*)d_out);
    }
}

// Round 8
// 641.030 us; speedup vs baseline: 1.1251x; 1.1251x over previous
//
#include <hip/hip_runtime.h>
#include <cstdint>
#include <cstddef>

#define NB1      16384      // 2^14 first-level radix bins
#define L1SHIFT  18         // key >> 18 -> 14-bit bin
#define CAP      4096       // compaction buffer per task (power of 2 for bitonic)
#define K_TOP    1000
#define NCAND    5000
#define NIMG     8
#define NLVL     5
#define NTASK    40
#define NPOST    300
#define NEGF     (-1e9f)
#define NWORDS   79         // ceil(5000/64)

typedef unsigned long long u64;

struct Ptrs {
    const float* lg[5];
    const float* dl[5];
};

__device__ __forceinline__ unsigned key_of(float f) {
    unsigned u = __float_as_uint(f);
    return (u & 0x80000000u) ? ~u : (u | 0x80000000u);
}
__device__ __forceinline__ float key_to_float(unsigned k) {
    unsigned u = (k & 0x80000000u) ? (k ^ 0x80000000u) : ~k;
    return __uint_as_float(u);
}

// ---------------- zero scratch ----------------
__global__ void kZero(unsigned* p, size_t n) {
    size_t i = (size_t)blockIdx.x * blockDim.x + threadIdx.x;
    size_t st = (size_t)gridDim.x * blockDim.x;
    for (; i < n; i += st) p[i] = 0u;
}

// ---------------- pass 1: LDS-privatized 14-bit histogram per (img,lvl) ----------------
__global__ __launch_bounds__(1024) void kHist(const float* __restrict__ lg,
                                              int m, int lvl,
                                              unsigned* __restrict__ hist) {
    int img  = blockIdx.y;
    int task = img * NLVL + lvl;
    __shared__ unsigned h[NB1];
    for (int i = threadIdx.x; i < NB1; i += 1024) h[i] = 0u;
    __syncthreads();
    int m4 = m >> 2;                       // all level sizes divisible by 4
    int chunk4 = (m4 + gridDim.x - 1) / (int)gridDim.x;
    int start4 = blockIdx.x * chunk4;
    int end4   = min(start4 + chunk4, m4);
    const float4* src = (const float4*)(lg + (size_t)img * m);
    for (int i = start4 + threadIdx.x; i < end4; i += 1024) {
        float4 v = src[i];
        atomicAdd(&h[key_of(v.x) >> L1SHIFT], 1u);
        atomicAdd(&h[key_of(v.y) >> L1SHIFT], 1u);
        atomicAdd(&h[key_of(v.z) >> L1SHIFT], 1u);
        atomicAdd(&h[key_of(v.w) >> L1SHIFT], 1u);
    }
    __syncthreads();
    unsigned* gh = hist + (size_t)task * NB1;
    for (int i = threadIdx.x; i < NB1; i += 1024) {
        unsigned c = h[i];
        if (c) atomicAdd(&gh[i], c);
    }
}

// ---------------- pass 2: find 14-bit prefix of the K-th largest ----------------
__global__ __launch_bounds__(256) void kSelectBin(const unsigned* __restrict__ hist,
                                                  unsigned* __restrict__ tinfo,
                                                  unsigned* __restrict__ cnt) {
    int task = blockIdx.x;
    const unsigned* h = hist + (size_t)task * NB1;
    __shared__ unsigned sblk[256];
    __shared__ unsigned sbin[64];
    __shared__ int sh_tb;
    __shared__ unsigned sh_rem;
    int t = threadIdx.x;
    unsigned s = 0;
    for (int i = 0; i < 64; ++i) s += h[t * 64 + i];
    sblk[t] = s;
    __syncthreads();
    if (t == 0) {
        unsigned rem = K_TOP; int tb = 0;
        for (int b = 255; b >= 0; --b) {
            if (sblk[b] < rem) rem -= sblk[b];
            else { tb = b; break; }
        }
        sh_tb = tb; sh_rem = rem;
    }
    __syncthreads();
    if (t < 64) sbin[t] = h[sh_tb * 64 + t];
    __syncthreads();
    if (t == 0) {
        unsigned rem = sh_rem; int pfx = sh_tb * 64;
        for (int b = 63; b >= 0; --b) {
            if (sbin[b] < rem) rem -= sbin[b];
            else { pfx = sh_tb * 64 + b; break; }
        }
        tinfo[task * 2]     = (unsigned)pfx;
        tinfo[task * 2 + 1] = rem;
        cnt[task] = 0u;
    }
}

// ---------------- pass 3: compact all keys with bin >= prefix ----------------
__global__ void kCompact(const float* __restrict__ lg, int m, int lvl,
                         const unsigned* __restrict__ tinfo,
                         unsigned* __restrict__ cnt,
                         u64* __restrict__ compbuf) {
    int img = blockIdx.y;
    int task = img * NLVL + lvl;
    unsigned pfx = tinfo[task * 2];
    int j = blockIdx.x * blockDim.x + threadIdx.x;
    if (j < m) {
        unsigned key = key_of(lg[(size_t)img * m + j]);
        if ((key >> L1SHIFT) >= pfx) {
            unsigned pos = atomicAdd(&cnt[task], 1u);
            if (pos < CAP)
                compbuf[(size_t)task * CAP + pos] =
                    ((u64)key << 32) | (unsigned)(~j);
        }
    }
}

// ---------------- pass 4: sort candidates, decode boxes, resort by masked score ----
__global__ __launch_bounds__(1024) void kSortSelect(
        Ptrs p,
        const unsigned* __restrict__ cnt,
        const u64* __restrict__ compbuf,
        float* __restrict__ cscore,
        float4* __restrict__ cbox,
        float4* __restrict__ cobox,
        float* __restrict__ carea,
        unsigned* __restrict__ cog) {
    int task = blockIdx.x;
    int img = task / NLVL, lvl = task % NLVL;
    __shared__ u64 sortbuf[CAP + 1024];   // 40 KB; phase-2 reused as float farr[10240]
    __shared__ u64 buf2[1024];
    u64* buf = sortbuf;
    int n = min((int)cnt[task], CAP);
    for (int i = threadIdx.x; i < CAP; i += 1024)
        buf[i] = (i < n) ? compbuf[(size_t)task * CAP + i] : 0ULL;
    __syncthreads();
    for (int k = 2; k <= CAP; k <<= 1) {
        for (int j2 = k >> 1; j2 > 0; j2 >>= 1) {
            for (int i = threadIdx.x; i < CAP; i += 1024) {
                int pp = i ^ j2;
                if (pp > i) {
                    u64 A = buf[i], B = buf[pp];
                    bool up = ((i & k) == 0);
                    if (up ? (A < B) : (A > B)) { buf[i] = B; buf[pp] = A; }
                }
            }
            __syncthreads();
        }
    }
    const int   MS[5]     = {516096, 129024, 32256, 8064, 2016};
    const int   GW[5]     = {512, 256, 128, 64, 32};
    const float STRIDEF[5]= {4.f, 8.f, 16.f, 32.f, 64.f};
    const int   SIZEI[5]  = {32, 64, 128, 256, 512};
    int r = threadIdx.x;
    float sm = 0.f, x0 = 0.f, y0 = 0.f, x1 = 0.f, y1 = 0.f;
    float b0 = 0.f, b1 = 0.f, b2 = 0.f, b3 = 0.f, area = 0.f;
    if (r < K_TOP) {
        u64 c = buf[r];
        int idx = (int)(~(unsigned)c);
        int m = MS[lvl];
        if ((unsigned)idx >= (unsigned)m) idx = 0;   // safety (never expected)
        const float* lg = p.lg[lvl];
        const float* dl = p.dl[lvl];
        float score = lg[(size_t)img * m + idx];
        int a   = idx % 3;
        int loc = idx / 3;
        int gw  = GW[lvl];
        int x = loc % gw, y = loc / gw;
        double ssz = (double)SIZEI[lvl];
        double arr = (a == 0) ? 0.5 : ((a == 1) ? 1.0 : 2.0);
        double wd = sqrt(ssz * ssz / arr);
        double hd = arr * wd;
        float sx = (float)x * STRIDEF[lvl];
        float sy = (float)y * STRIDEF[lvl];
        float a0 = sx + (float)(-wd * 0.5);
        float a1 = sy + (float)(-hd * 0.5);
        float a2 = sx + (float)( wd * 0.5);
        float a3 = sy + (float)( hd * 0.5);
        float aw = a2 - a0, ah = a3 - a1;
        float acx = a0 + 0.5f * aw, acy = a1 + 0.5f * ah;
        size_t db = ((size_t)img * m + idx) * 4;
        float dx = dl[db], dy = dl[db + 1], dwv = dl[db + 2], dhv = dl[db + 3];
        const float CL = 4.135166556742356f;   // log(1000/16)
        float pw = expf(fminf(dwv, CL)) * aw;
        float ph = expf(fminf(dhv, CL)) * ah;
        float pcx = dx * aw + acx;
        float pcy = dy * ah + acy;
        x0 = pcx - 0.5f * pw; y0 = pcy - 0.5f * ph;
        x1 = pcx + 0.5f * pw; y1 = pcy + 0.5f * ph;
        x0 = fminf(fmaxf(x0, 0.f), 2048.f);
        x1 = fminf(fmaxf(x1, 0.f), 2048.f);
        y0 = fminf(fmaxf(y0, 0.f), 1344.f);
        y1 = fminf(fmaxf(y1, 0.f), 1344.f);
        bool keep = ((x1 - x0) > 0.f) && ((y1 - y0) > 0.f);
        sm = keep ? score : NEGF;
        float off = (float)lvl * 2049.0f;
        b0 = x0 + off; b1 = y0 + off; b2 = x1 + off; b3 = y1 + off;
        area = (b2 - b0) * (b3 - b1);
    }
    __syncthreads();                 // all buf reads done before reuse as farr
    float* farr = (float*)sortbuf;   // [0,1000) score  [1000,2000) area
                                     // [2000,6000) clip box  [6000,10000) offset box
    if (r < K_TOP) {
        farr[r] = sm;
        farr[1000 + r] = area;
        farr[2000 + 4 * r]     = x0;
        farr[2000 + 4 * r + 1] = y0;
        farr[2000 + 4 * r + 2] = x1;
        farr[2000 + 4 * r + 3] = y1;
        farr[6000 + 4 * r]     = b0;
        farr[6000 + 4 * r + 1] = b1;
        farr[6000 + 4 * r + 2] = b2;
        farr[6000 + 4 * r + 3] = b3;
    }
    buf2[r] = (r < K_TOP)
        ? (((u64)key_of(sm) << 32) | (unsigned)(~(unsigned)(lvl * K_TOP + r)))
        : 0ULL;
    __syncthreads();
    for (int k = 2; k <= 1024; k <<= 1) {
        for (int j2 = k >> 1; j2 > 0; j2 >>= 1) {
            int i = r, pp = i ^ j2;
            if (pp > i) {
                u64 A = buf2[i], B = buf2[pp];
                bool up = ((i & k) == 0);
                if (up ? (A < B) : (A > B)) { buf2[i] = B; buf2[pp] = A; }
            }
            __syncthreads();
        }
    }
    if (r < K_TOP) {
        u64 c2 = buf2[r];
        unsigned g2 = ~(unsigned)c2;
        int rsrc = (int)g2 - lvl * K_TOP;    // original within-level rank
        int ci = img * NCAND + lvl * K_TOP + r;
        cscore[ci] = farr[rsrc];
        carea[ci]  = farr[1000 + rsrc];
        cbox[ci]  = make_float4(farr[2000 + 4 * rsrc],     farr[2000 + 4 * rsrc + 1],
                                farr[2000 + 4 * rsrc + 2], farr[2000 + 4 * rsrc + 3]);
        cobox[ci] = make_float4(farr[6000 + 4 * rsrc],     farr[6000 + 4 * rsrc + 1],
                                farr[6000 + 4 * rsrc + 2], farr[6000 + 4 * rsrc + 3]);
        cog[ci] = (unsigned)rsrc;
    }
}

// ---------------- pass 5a: merge 5 sorted lists into global sorted order ----------------
__global__ __launch_bounds__(1024) void kMerge(
        const float* __restrict__ cscore,
        const float4* __restrict__ cbox,
        const float4* __restrict__ cobox,
        const float* __restrict__ carea,
        const unsigned* __restrict__ cog,
        float* __restrict__ ssc,
        float4* __restrict__ sob,
        float* __restrict__ sar,
        float4* __restrict__ sclip) {
    int img = blockIdx.x;
    __shared__ u64 comp[NCAND];
    for (int g = threadIdx.x; g < NCAND; g += 1024) {
        int lv = g / K_TOP;
        unsigned og = (unsigned)(lv * K_TOP) + cog[img * NCAND + g];
        comp[g] = ((u64)key_of(cscore[img * NCAND + g]) << 32) | (unsigned)(~og);
    }
    __syncthreads();
    for (int g = threadIdx.x; g < NCAND; g += 1024) {
        u64 c = comp[g];
        int lv = g / K_TOP;
        int pos = g - lv * K_TOP;    // elements > c within own (desc-sorted) level
        for (int lv2 = 0; lv2 < NLVL; ++lv2) {
            if (lv2 == lv) continue;
            int base = lv2 * K_TOP;
            int lo = 0, hi = K_TOP;
            while (lo < hi) {
                int mid = (lo + hi) >> 1;
                if (comp[base + mid] > c) lo = mid + 1; else hi = mid;
            }
            pos += lo;               // count of elements > c (composites unique)
        }
        int src = img * NCAND + g;
        int dst = img * NCAND + pos;
        ssc[dst]   = cscore[src];
        sob[dst]   = cobox[src];
        sar[dst]   = carea[src];
        sclip[dst] = cbox[src];
    }
}

// ---------------- pass 5b: diagonal 64x64 IoU blocks only ----------------
// block (w, img), 64 threads: lane = column j = w*64+lane; rows broadcast from LDS.
__global__ __launch_bounds__(64) void kIouDiag(
        const float4* __restrict__ sob,
        const float* __restrict__ sar,
        u64* __restrict__ diagG) {
    int w    = blockIdx.x;
    int img  = blockIdx.y;
    int lane = threadIdx.x;
    int j = w * 64 + lane;
    int imgb = img * NCAND;
    __shared__ float4 bxS[64];
    __shared__ float  arS[64];
    __shared__ u64 wordsS[64];
    bool inb = (j < NCAND);
    float4 bj = make_float4(0.f, 0.f, 0.f, 0.f);
    float arj = 0.f;
    if (inb) { bj = sob[imgb + j]; arj = sar[imgb + j]; }
    bxS[lane] = bj; arS[lane] = arj;
    __syncthreads();
    for (int r = 0; r < 64; ++r) {
        float4 bp = bxS[r];            // row box (broadcast read)
        float arp = arS[r];
        float ltx = fmaxf(bj.x, bp.x), lty = fmaxf(bj.y, bp.y);
        float rbx = fminf(bj.z, bp.z), rby = fminf(bj.w, bp.w);
        float wx = fmaxf(rbx - ltx, 0.f), wy = fmaxf(rby - lty, 0.f);
        float inter = wx * wy;
        float denom = (arj + arp) - inter + 1e-9f;
        bool pred = inb && ((inter / denom) > 0.7f);
        u64 bits = __ballot(pred);
        if (lane == 0) wordsS[r] = bits;
    }
    __syncthreads();
    diagG[(size_t)img * (NWORDS * 64) + w * 64 + lane] = wordsS[lane];
}

// ---------------- pass 5c: scan; candidates register-resident; lazy flush ----------------
// 1024 threads. Thread tid holds candidates j = tid + k*1024 (k=0..4) in registers.
// Serial emission (redundant on all threads) uses only LDS diagS; at each word
// boundary the pending boxes (pushed to LDS from owner registers) suppress all
// future candidates via register IoU + ballot -> maskS. No global loads in loop.
__global__ __launch_bounds__(1024) void kScan(
        const float* __restrict__ ssc,
        const float4* __restrict__ sclip,
        const float4* __restrict__ sob,
        const float* __restrict__ sar,
        const u64* __restrict__ diagG,
        float* __restrict__ out) {
    int img = blockIdx.x;
    int tid = threadIdx.x;
    int lane = tid & 63;
    int wave = tid >> 6;
    __shared__ u64 diagS[NWORDS * 64];
    __shared__ u64 maskS[NWORDS + 1];
    __shared__ float4 pboxS[64];
    __shared__ float  parS[64];
    __shared__ unsigned emS[NPOST];
    __shared__ int nvS;
    const int imgb = img * NCAND;

    if (tid == 0) nvS = NCAND;
    for (int w = tid; w < NWORDS + 1; w += 1024) maskS[w] = 0ULL;
    for (int idx = tid; idx < NWORDS * 64; idx += 1024)
        diagS[idx] = diagG[(size_t)img * (NWORDS * 64) + idx];
    __syncthreads();

    float4 rb0, rb1, rb2, rb3, rb4;
    float rar0, rar1, rar2, rar3, rar4;
#define LOADC(K, RB, RA) { \
        int j = tid + (K) * 1024; \
        if (j < NCAND) { \
            RB = sob[imgb + j]; RA = sar[imgb + j]; \
            if (ssc[imgb + j] <= -5.0e8f) atomicMin(&nvS, j); \
        } else { RB = make_float4(0.f, 0.f, 0.f, 0.f); RA = 0.f; } }
    LOADC(0, rb0, rar0) LOADC(1, rb1, rar1) LOADC(2, rb2, rar2)
    LOADC(3, rb3, rar3) LOADC(4, rb4, rar4)
#undef LOADC
    __syncthreads();
    int nv = nvS;                      // uniform: first invalid sorted index

    int emitted = 0;
    bool done = false;
    for (int w = 0; w < NWORDS && !done; ++w) {
        u64 cur = ~maskS[w];
        if (w == NWORDS - 1) cur &= (1ULL << (NCAND - (NWORDS - 1) * 64)) - 1ULL;
        int npend = 0;
        while (cur) {
            int b = __builtin_ctzll(cur);
            int i = w * 64 + b;
            if (i >= nv) { done = true; break; }    // scores descending: rest invalid
            if (tid == 0) emS[emitted] = (unsigned)i;
            ++emitted;
            if (emitted == NPOST) { done = true; break; }
            u64 rw = diagS[w * 64 + b];             // same-word suppression
            cur &= ~rw;
            cur &= ~(1ULL << b);
            if (tid == (i & 1023)) {                // owner pushes box from registers
                int kk = i >> 10;
                float4 pb; float pa;
                if (kk == 0)      { pb = rb0; pa = rar0; }
                else if (kk == 1) { pb = rb1; pa = rar1; }
                else if (kk == 2) { pb = rb2; pa = rar2; }
                else if (kk == 3) { pb = rb3; pa = rar3; }
                else              { pb = rb4; pa = rar4; }
                pboxS[npend] = pb; parS[npend] = pa;
            }
            ++npend;                                // uniform
        }
        if (!done && npend) {
            __syncthreads();                        // pboxS visible to all waves
#define PHASE(K, RB, RA) { \
            bool supp = false; \
            for (int k0 = 0; k0 < npend; ++k0) { \
                float4 bp = pboxS[k0]; float arp = parS[k0]; \
                float ltx = fmaxf(RB.x, bp.x), lty = fmaxf(RB.y, bp.y); \
                float rbx = fminf(RB.z, bp.z), rby = fminf(RB.w, bp.w); \
                float wx = fmaxf(rbx - ltx, 0.f), wy = fmaxf(rby - lty, 0.f); \
                float inter = wx * wy; \
                float denom = (RA + arp) - inter + 1e-9f; \
                supp |= (inter / denom) > 0.7f; \
            } \
            u64 bits = __ballot(supp); \
            if (lane == 0) maskS[wave + (K) * 16] |= bits; }
            PHASE(0, rb0, rar0) PHASE(1, rb1, rar1) PHASE(2, rb2, rar2)
            PHASE(3, rb3, rar3) PHASE(4, rb4, rar4)
#undef PHASE
            __syncthreads();                        // maskS updates visible
        }
    }
    __syncthreads();                                // emS visible
    for (int rr = tid; rr < NPOST; rr += 1024) {
        float* o = out + ((size_t)img * NPOST + rr) * 5;
        if (rr < emitted) {
            unsigned i = emS[rr];
            float4 cb = sclip[imgb + i];
            float sc = ssc[imgb + i];
            o[0] = cb.x; o[1] = cb.y; o[2] = cb.z; o[3] = cb.w; o[4] = sc;
        } else {
            o[0] = 0.f; o[1] = 0.f; o[2] = 0.f; o[3] = 0.f; o[4] = NEGF;
        }
    }
}

// ---------------- fallback: round-1 sequential NMS (used only if ws too small) ----------------
__global__ __launch_bounds__(1024) void kNMS(
        const float* __restrict__ cscore,
        const float4* __restrict__ cbox,
        const float4* __restrict__ cobox,
        const float* __restrict__ carea,
        float* __restrict__ out) {
    int img = blockIdx.x;
    int tid = threadIdx.x;
    __shared__ u64 warr[16];
    __shared__ float bb[5];
    float s[5], b0[5], b1[5], b2[5], b3[5], ar[5];
#pragma unroll
    for (int k = 0; k < 5; ++k) {
        int j = tid + k * 1024;
        if (j < NCAND) {
            int ci = img * NCAND + j;
            s[k] = cscore[ci];
            float4 b = cobox[ci];
            b0[k] = b.x; b1[k] = b.y; b2[k] = b.z; b3[k] = b.w;
            ar[k] = carea[ci];
        } else {
            s[k] = -3.4e38f;
            b0[k] = b1[k] = b2[k] = b3[k] = 0.f; ar[k] = 0.f;
        }
    }
    for (int step = 0; step < NPOST; ++step) {
        u64 comp = 0ULL;
#pragma unroll
        for (int k = 0; k < 5; ++k) {
            int j = tid + k * 1024;
            unsigned kk = key_of(s[k]);
            u64 c = ((u64)kk << 32) | (unsigned)(~j);
            comp = (c > comp) ? c : comp;
        }
#pragma unroll
        for (int off2 = 32; off2 >= 1; off2 >>= 1) {
            u64 o = __shfl_xor(comp, off2, 64);
            comp = (o > comp) ? o : comp;
        }
        if ((tid & 63) == 0) warr[tid >> 6] = comp;
        __syncthreads();
        u64 best = warr[0];
#pragma unroll
        for (int w = 1; w < 16; ++w) {
            u64 o = warr[w];
            best = (o > best) ? o : best;
        }
        int bidx = (int)(~(unsigned)best);
        float bscore = key_to_float((unsigned)(best >> 32));
        bool valid = bscore > -5.0e8f;
#pragma unroll
        for (int k = 0; k < 5; ++k) {
            int j = tid + k * 1024;
            if (j == bidx) {
                bb[0] = b0[k]; bb[1] = b1[k]; bb[2] = b2[k]; bb[3] = b3[k]; bb[4] = ar[k];
                float* o = out + ((size_t)img * NPOST + step) * 5;
                if (valid) {
                    float4 gb = cbox[img * NCAND + j];
                    o[0] = gb.x; o[1] = gb.y; o[2] = gb.z; o[3] = gb.w; o[4] = bscore;
                } else {
                    o[0] = 0.f; o[1] = 0.f; o[2] = 0.f; o[3] = 0.f; o[4] = NEGF;
                }
            }
        }
        __syncthreads();
        float ib0 = bb[0], ib1 = bb[1], ib2 = bb[2], ib3 = bb[3], iar = bb[4];
#pragma unroll
        for (int k = 0; k < 5; ++k) {
            int j = tid + k * 1024;
            float ltx = fmaxf(b0[k], ib0), lty = fmaxf(b1[k], ib1);
            float rbx = fminf(b2[k], ib2), rby = fminf(b3[k], ib3);
            float wx = fmaxf(rbx - ltx, 0.f), wy = fmaxf(rby - lty, 0.f);
            float inter = wx * wy;
            float denom = ar[k] + iar;
            denom = denom - inter;
            denom = denom + 1e-9f;
            float iou = inter / denom;
            if (iou > 0.7f) s[k] = NEGF;
            if (j == bidx) s[k] = NEGF;
        }
    }
}

extern "C" void kernel_launch(void* const* d_in, const int* in_sizes, int n_in,
                              void* d_out, int out_size, void* d_ws, size_t ws_size,
                              hipStream_t stream) {
    const int MS[5] = {516096, 129024, 32256, 8064, 2016};
    Ptrs P;
    for (int l = 0; l < 5; ++l) {
        P.lg[l] = (const float*)d_in[2 * l];
        P.dl[l] = (const float*)d_in[2 * l + 1];
    }
    char* w = (char*)d_ws;
    size_t off = 0;
    auto alloc = [&](size_t bytes) -> void* {
        void* pp = (void*)(w + off);
        off = (off + bytes + 255) & ~(size_t)255;
        return pp;
    };
    unsigned* hist  = (unsigned*)alloc((size_t)NTASK * NB1 * 4);
    unsigned* tinfo = (unsigned*)alloc(NTASK * 2 * 4);
    unsigned* cnt   = (unsigned*)alloc(NTASK * 4);
    u64* compb      = (u64*)alloc((size_t)NTASK * CAP * 8);
    float*  cscore  = (float*)alloc((size_t)NTASK * K_TOP * 4);
    float4* cbox    = (float4*)alloc((size_t)NTASK * K_TOP * 16);
    float4* cobox   = (float4*)alloc((size_t)NTASK * K_TOP * 16);
    float*  carea   = (float*)alloc((size_t)NTASK * K_TOP * 4);
    unsigned* cog   = (unsigned*)alloc((size_t)NTASK * K_TOP * 4);
    // NMS scratch
    float*  ssc     = (float*)alloc((size_t)NIMG * NCAND * 4);
    float4* sob     = (float4*)alloc((size_t)NIMG * NCAND * 16);
    float*  sar     = (float*)alloc((size_t)NIMG * NCAND * 4);
    float4* sclip   = (float4*)alloc((size_t)NIMG * NCAND * 16);
    u64*    diagG   = (u64*)alloc((size_t)NIMG * NWORDS * 64 * 8);
    size_t need = off;
    (void)in_sizes; (void)n_in; (void)out_size;

    size_t nhz = (size_t)NTASK * NB1;
    kZero<<<2048, 256, 0, stream>>>(hist, nhz);
    for (int l = 0; l < 5; ++l) {
        int m4 = MS[l] >> 2;
        int gx = (m4 + 8191) / 8192;       // ~32K elements per block
        dim3 g(gx, NIMG);
        kHist<<<g, 1024, 0, stream>>>(P.lg[l], MS[l], l, hist);
    }
    kSelectBin<<<NTASK, 256, 0, stream>>>(hist, tinfo, cnt);
    for (int l = 0; l < 5; ++l) {
        dim3 g((MS[l] + 255) / 256, NIMG);
        kCompact<<<g, 256, 0, stream>>>(P.lg[l], MS[l], l, tinfo, cnt, compb);
    }
    kSortSelect<<<NTASK, 1024, 0, stream>>>(P, cnt, compb, cscore, cbox, cobox, carea, cog);

    if (ws_size >= need) {
        kMerge<<<NIMG, 1024, 0, stream>>>(cscore, cbox, cobox, carea, cog,
                                          ssc, sob, sar, sclip);
        dim3 gd(NWORDS, NIMG);
        kIouDiag<<<gd, 64, 0, stream>>>(sob, sar, diagG);
        kScan<<<NIMG, 1024, 0, stream>>>(ssc, sclip, sob, sar, diagG, (float*)d_out);
    } else {
        kNMS<<<NIMG, 1024, 0, stream>>>(cscore, cbox, cobox, carea, (float*)d_out);
    }
}

// Round 9
// 386.519 us; speedup vs baseline: 1.8659x; 1.6585x over previous
//
#include <hip/hip_runtime.h>
#include <cstdint>
#include <cstddef>

#define NB1      16384      // 2^14 first-level radix bins
#define L1SHIFT  18         // key >> 18 -> 14-bit bin
#define CAP      4096       // compaction buffer per task (power of 2 for bitonic)
#define K_TOP    1000
#define NCAND    5000
#define NIMG     8
#define NLVL     5
#define NTASK    40
#define NPOST    300
#define NEGF     (-1e9f)
#define NWORDS   79         // ceil(5000/64)

typedef unsigned long long u64;

struct Ptrs {
    const float* lg[5];
    const float* dl[5];
};

__device__ __forceinline__ unsigned key_of(float f) {
    unsigned u = __float_as_uint(f);
    return (u & 0x80000000u) ? ~u : (u | 0x80000000u);
}
__device__ __forceinline__ float key_to_float(unsigned k) {
    unsigned u = (k & 0x80000000u) ? (k ^ 0x80000000u) : ~k;
    return __uint_as_float(u);
}

// ---------------- zero scratch ----------------
__global__ void kZero(unsigned* p, size_t n) {
    size_t i = (size_t)blockIdx.x * blockDim.x + threadIdx.x;
    size_t st = (size_t)gridDim.x * blockDim.x;
    for (; i < n; i += st) p[i] = 0u;
}

// ---------------- pass 1: LDS-privatized 14-bit histogram per (img,lvl) ----------------
__global__ __launch_bounds__(1024) void kHist(const float* __restrict__ lg,
                                              int m, int lvl,
                                              unsigned* __restrict__ hist) {
    int img  = blockIdx.y;
    int task = img * NLVL + lvl;
    __shared__ unsigned h[NB1];
    for (int i = threadIdx.x; i < NB1; i += 1024) h[i] = 0u;
    __syncthreads();
    int m4 = m >> 2;                       // all level sizes divisible by 4
    int chunk4 = (m4 + gridDim.x - 1) / (int)gridDim.x;
    int start4 = blockIdx.x * chunk4;
    int end4   = min(start4 + chunk4, m4);
    const float4* src = (const float4*)(lg + (size_t)img * m);
    for (int i = start4 + threadIdx.x; i < end4; i += 1024) {
        float4 v = src[i];
        atomicAdd(&h[key_of(v.x) >> L1SHIFT], 1u);
        atomicAdd(&h[key_of(v.y) >> L1SHIFT], 1u);
        atomicAdd(&h[key_of(v.z) >> L1SHIFT], 1u);
        atomicAdd(&h[key_of(v.w) >> L1SHIFT], 1u);
    }
    __syncthreads();
    unsigned* gh = hist + (size_t)task * NB1;
    for (int i = threadIdx.x; i < NB1; i += 1024) {
        unsigned c = h[i];
        if (c) atomicAdd(&gh[i], c);
    }
}

// ---------------- pass 2: find 14-bit prefix of the K-th largest ----------------
__global__ __launch_bounds__(256) void kSelectBin(const unsigned* __restrict__ hist,
                                                  unsigned* __restrict__ tinfo,
                                                  unsigned* __restrict__ cnt) {
    int task = blockIdx.x;
    const unsigned* h = hist + (size_t)task * NB1;
    __shared__ unsigned sblk[256];
    __shared__ unsigned sbin[64];
    __shared__ int sh_tb;
    __shared__ unsigned sh_rem;
    int t = threadIdx.x;
    unsigned s = 0;
    for (int i = 0; i < 64; ++i) s += h[t * 64 + i];
    sblk[t] = s;
    __syncthreads();
    if (t == 0) {
        unsigned rem = K_TOP; int tb = 0;
        for (int b = 255; b >= 0; --b) {
            if (sblk[b] < rem) rem -= sblk[b];
            else { tb = b; break; }
        }
        sh_tb = tb; sh_rem = rem;
    }
    __syncthreads();
    if (t < 64) sbin[t] = h[sh_tb * 64 + t];
    __syncthreads();
    if (t == 0) {
        unsigned rem = sh_rem; int pfx = sh_tb * 64;
        for (int b = 63; b >= 0; --b) {
            if (sbin[b] < rem) rem -= sbin[b];
            else { pfx = sh_tb * 64 + b; break; }
        }
        tinfo[task * 2]     = (unsigned)pfx;
        tinfo[task * 2 + 1] = rem;
        cnt[task] = 0u;
    }
}

// ---------------- pass 3: compact all keys with bin >= prefix ----------------
__global__ void kCompact(const float* __restrict__ lg, int m, int lvl,
                         const unsigned* __restrict__ tinfo,
                         unsigned* __restrict__ cnt,
                         u64* __restrict__ compbuf) {
    int img = blockIdx.y;
    int task = img * NLVL + lvl;
    unsigned pfx = tinfo[task * 2];
    int j = blockIdx.x * blockDim.x + threadIdx.x;
    if (j < m) {
        unsigned key = key_of(lg[(size_t)img * m + j]);
        if ((key >> L1SHIFT) >= pfx) {
            unsigned pos = atomicAdd(&cnt[task], 1u);
            if (pos < CAP)
                compbuf[(size_t)task * CAP + pos] =
                    ((u64)key << 32) | (unsigned)(~j);
        }
    }
}

// ---------------- pass 4: sort candidates, decode boxes, resort by masked score ----
__global__ __launch_bounds__(1024) void kSortSelect(
        Ptrs p,
        const unsigned* __restrict__ cnt,
        const u64* __restrict__ compbuf,
        float* __restrict__ cscore,
        float4* __restrict__ cbox,
        float4* __restrict__ cobox,
        float* __restrict__ carea,
        unsigned* __restrict__ cog) {
    int task = blockIdx.x;
    int img = task / NLVL, lvl = task % NLVL;
    __shared__ u64 sortbuf[CAP + 1024];   // 40 KB; phase-2 reused as float farr[10240]
    __shared__ u64 buf2[1024];
    u64* buf = sortbuf;
    int n = min((int)cnt[task], CAP);
    for (int i = threadIdx.x; i < CAP; i += 1024)
        buf[i] = (i < n) ? compbuf[(size_t)task * CAP + i] : 0ULL;
    __syncthreads();
    for (int k = 2; k <= CAP; k <<= 1) {
        for (int j2 = k >> 1; j2 > 0; j2 >>= 1) {
            for (int i = threadIdx.x; i < CAP; i += 1024) {
                int pp = i ^ j2;
                if (pp > i) {
                    u64 A = buf[i], B = buf[pp];
                    bool up = ((i & k) == 0);
                    if (up ? (A < B) : (A > B)) { buf[i] = B; buf[pp] = A; }
                }
            }
            __syncthreads();
        }
    }
    const int   MS[5]     = {516096, 129024, 32256, 8064, 2016};
    const int   GW[5]     = {512, 256, 128, 64, 32};
    const float STRIDEF[5]= {4.f, 8.f, 16.f, 32.f, 64.f};
    const int   SIZEI[5]  = {32, 64, 128, 256, 512};
    int r = threadIdx.x;
    float sm = 0.f, x0 = 0.f, y0 = 0.f, x1 = 0.f, y1 = 0.f;
    float b0 = 0.f, b1 = 0.f, b2 = 0.f, b3 = 0.f, area = 0.f;
    if (r < K_TOP) {
        u64 c = buf[r];
        int idx = (int)(~(unsigned)c);
        int m = MS[lvl];
        if ((unsigned)idx >= (unsigned)m) idx = 0;   // safety (never expected)
        const float* lg = p.lg[lvl];
        const float* dl = p.dl[lvl];
        float score = lg[(size_t)img * m + idx];
        int a   = idx % 3;
        int loc = idx / 3;
        int gw  = GW[lvl];
        int x = loc % gw, y = loc / gw;
        double ssz = (double)SIZEI[lvl];
        double arr = (a == 0) ? 0.5 : ((a == 1) ? 1.0 : 2.0);
        double wd = sqrt(ssz * ssz / arr);
        double hd = arr * wd;
        float sx = (float)x * STRIDEF[lvl];
        float sy = (float)y * STRIDEF[lvl];
        float a0 = sx + (float)(-wd * 0.5);
        float a1 = sy + (float)(-hd * 0.5);
        float a2 = sx + (float)( wd * 0.5);
        float a3 = sy + (float)( hd * 0.5);
        float aw = a2 - a0, ah = a3 - a1;
        float acx = a0 + 0.5f * aw, acy = a1 + 0.5f * ah;
        size_t db = ((size_t)img * m + idx) * 4;
        float dx = dl[db], dy = dl[db + 1], dwv = dl[db + 2], dhv = dl[db + 3];
        const float CL = 4.135166556742356f;   // log(1000/16)
        float pw = expf(fminf(dwv, CL)) * aw;
        float ph = expf(fminf(dhv, CL)) * ah;
        float pcx = dx * aw + acx;
        float pcy = dy * ah + acy;
        x0 = pcx - 0.5f * pw; y0 = pcy - 0.5f * ph;
        x1 = pcx + 0.5f * pw; y1 = pcy + 0.5f * ph;
        x0 = fminf(fmaxf(x0, 0.f), 2048.f);
        x1 = fminf(fmaxf(x1, 0.f), 2048.f);
        y0 = fminf(fmaxf(y0, 0.f), 1344.f);
        y1 = fminf(fmaxf(y1, 0.f), 1344.f);
        bool keep = ((x1 - x0) > 0.f) && ((y1 - y0) > 0.f);
        sm = keep ? score : NEGF;
        float off = (float)lvl * 2049.0f;
        b0 = x0 + off; b1 = y0 + off; b2 = x1 + off; b3 = y1 + off;
        area = (b2 - b0) * (b3 - b1);
    }
    __syncthreads();                 // all buf reads done before reuse as farr
    float* farr = (float*)sortbuf;   // [0,1000) score  [1000,2000) area
                                     // [2000,6000) clip box  [6000,10000) offset box
    if (r < K_TOP) {
        farr[r] = sm;
        farr[1000 + r] = area;
        farr[2000 + 4 * r]     = x0;
        farr[2000 + 4 * r + 1] = y0;
        farr[2000 + 4 * r + 2] = x1;
        farr[2000 + 4 * r + 3] = y1;
        farr[6000 + 4 * r]     = b0;
        farr[6000 + 4 * r + 1] = b1;
        farr[6000 + 4 * r + 2] = b2;
        farr[6000 + 4 * r + 3] = b3;
    }
    buf2[r] = (r < K_TOP)
        ? (((u64)key_of(sm) << 32) | (unsigned)(~(unsigned)(lvl * K_TOP + r)))
        : 0ULL;
    __syncthreads();
    for (int k = 2; k <= 1024; k <<= 1) {
        for (int j2 = k >> 1; j2 > 0; j2 >>= 1) {
            int i = r, pp = i ^ j2;
            if (pp > i) {
                u64 A = buf2[i], B = buf2[pp];
                bool up = ((i & k) == 0);
                if (up ? (A < B) : (A > B)) { buf2[i] = B; buf2[pp] = A; }
            }
            __syncthreads();
        }
    }
    if (r < K_TOP) {
        u64 c2 = buf2[r];
        unsigned g2 = ~(unsigned)c2;
        int rsrc = (int)g2 - lvl * K_TOP;    // original within-level rank
        int ci = img * NCAND + lvl * K_TOP + r;
        cscore[ci] = farr[rsrc];
        carea[ci]  = farr[1000 + rsrc];
        cbox[ci]  = make_float4(farr[2000 + 4 * rsrc],     farr[2000 + 4 * rsrc + 1],
                                farr[2000 + 4 * rsrc + 2], farr[2000 + 4 * rsrc + 3]);
        cobox[ci] = make_float4(farr[6000 + 4 * rsrc],     farr[6000 + 4 * rsrc + 1],
                                farr[6000 + 4 * rsrc + 2], farr[6000 + 4 * rsrc + 3]);
        cog[ci] = (unsigned)rsrc;
    }
}

// ---------------- pass 5a: merge 5 sorted lists into global sorted order ----------------
__global__ __launch_bounds__(1024) void kMerge(
        const float* __restrict__ cscore,
        const float4* __restrict__ cbox,
        const float4* __restrict__ cobox,
        const float* __restrict__ carea,
        const unsigned* __restrict__ cog,
        float* __restrict__ ssc,
        float4* __restrict__ sob,
        float* __restrict__ sar,
        float4* __restrict__ sclip) {
    int img = blockIdx.x;
    __shared__ u64 comp[NCAND];
    for (int g = threadIdx.x; g < NCAND; g += 1024) {
        int lv = g / K_TOP;
        unsigned og = (unsigned)(lv * K_TOP) + cog[img * NCAND + g];
        comp[g] = ((u64)key_of(cscore[img * NCAND + g]) << 32) | (unsigned)(~og);
    }
    __syncthreads();
    for (int g = threadIdx.x; g < NCAND; g += 1024) {
        u64 c = comp[g];
        int lv = g / K_TOP;
        int pos = g - lv * K_TOP;    // elements > c within own (desc-sorted) level
        for (int lv2 = 0; lv2 < NLVL; ++lv2) {
            if (lv2 == lv) continue;
            int base = lv2 * K_TOP;
            int lo = 0, hi = K_TOP;
            while (lo < hi) {
                int mid = (lo + hi) >> 1;
                if (comp[base + mid] > c) lo = mid + 1; else hi = mid;
            }
            pos += lo;               // count of elements > c (composites unique)
        }
        int src = img * NCAND + g;
        int dst = img * NCAND + pos;
        ssc[dst]   = cscore[src];
        sob[dst]   = cobox[src];
        sar[dst]   = carea[src];
        sclip[dst] = cbox[src];
    }
}

// ---------------- pass 5: scan with just-in-time per-word suppression ----------------
// Per word w: stage its 64 boxes/scores in LDS; 16 waves compute in parallel
//  (a) suppression of these 64 candidates by ALL previously-emitted boxes
//      (held in LDS, appended at emission time), and (b) the word's own 64x64
//      diagonal IoU block. Then the serial emission walks the word using LDS only.
// IoU work = sum over scanned words of emitted*64  (~100K vs 1.5M before).
__global__ __launch_bounds__(1024) void kScan(
        const float* __restrict__ ssc,
        const float4* __restrict__ sclip,
        const float4* __restrict__ sob,
        const float* __restrict__ sar,
        float* __restrict__ out) {
    int img = blockIdx.x;
    int tid = threadIdx.x;
    int lane = tid & 63;
    int wave = tid >> 6;
    __shared__ float4 wboxS[64];
    __shared__ float  warS[64];
    __shared__ float  wsscS[64];
    __shared__ u64    diagWS[64];
    __shared__ u64    partS[16];
    __shared__ float4 pboxAll[NPOST];
    __shared__ float  parAll[NPOST];
    __shared__ unsigned emS[NPOST];
    const int imgb = img * NCAND;

    int emitted = 0;
    bool done = false;
    for (int w = 0; w < NWORDS && !done; ++w) {
        // ---- stage word w ----
        if (tid < 64) {
            int j = w * 64 + tid;
            if (j < NCAND) {
                wboxS[tid] = sob[imgb + j];
                warS[tid]  = sar[imgb + j];
                wsscS[tid] = ssc[imgb + j];
            } else {
                wboxS[tid] = make_float4(0.f, 0.f, 0.f, 0.f);
                warS[tid]  = 0.f;
                wsscS[tid] = -3.4e38f;     // invalid -> scan stops here
            }
        }
        __syncthreads();
        // ---- parallel: suppression by previously emitted + own diag block ----
        float4 bc = wboxS[lane];
        float  arc = warS[lane];
        bool supp = false;
        for (int t = wave; t < emitted; t += 16) {
            float4 bp = pboxAll[t]; float arp = parAll[t];
            float ltx = fmaxf(bc.x, bp.x), lty = fmaxf(bc.y, bp.y);
            float rbx = fminf(bc.z, bp.z), rby = fminf(bc.w, bp.w);
            float wx = fmaxf(rbx - ltx, 0.f), wy = fmaxf(rby - lty, 0.f);
            float inter = wx * wy;
            float denom = (arc + arp) - inter + 1e-9f;
            supp |= (inter / denom) > 0.7f;
        }
        u64 sb = __ballot(supp);
        if (lane == 0) partS[wave] = sb;
#pragma unroll
        for (int rr = 0; rr < 4; ++rr) {
            int r = wave * 4 + rr;               // diag row r: box vs word's 64
            float4 bp = wboxS[r]; float arp = warS[r];
            float ltx = fmaxf(bc.x, bp.x), lty = fmaxf(bc.y, bp.y);
            float rbx = fminf(bc.z, bp.z), rby = fminf(bc.w, bp.w);
            float wx = fmaxf(rbx - ltx, 0.f), wy = fmaxf(rby - lty, 0.f);
            float inter = wx * wy;
            float denom = (arc + arp) - inter + 1e-9f;
            bool pred = (inter / denom) > 0.7f;
            u64 db = __ballot(pred);
            if (lane == 0) diagWS[r] = db;
        }
        __syncthreads();
        // ---- serial emission within word (redundant on all threads, LDS only) ----
        u64 sm = partS[0];
#pragma unroll
        for (int q = 1; q < 16; ++q) sm |= partS[q];
        u64 cur = ~sm;
        while (cur) {
            int b = __builtin_ctzll(cur);
            float sc = wsscS[b];
            if (sc <= -5.0e8f) { done = true; break; }   // sorted: rest invalid too
            if (tid == 0) {
                emS[emitted]     = (unsigned)(w * 64 + b);
                pboxAll[emitted] = wboxS[b];
                parAll[emitted]  = warS[b];
            }
            ++emitted;                                   // uniform
            if (emitted == NPOST) { done = true; break; }
            cur &= ~diagWS[b];
            cur &= ~(1ULL << b);
        }
        __syncthreads();             // pboxAll/parAll/emS visible for next word
    }
    // ---- parallel output gather ----
    for (int rr = tid; rr < NPOST; rr += 1024) {
        float* o = out + ((size_t)img * NPOST + rr) * 5;
        if (rr < emitted) {
            unsigned i = emS[rr];
            float4 cb = sclip[imgb + i];
            float sc = ssc[imgb + i];
            o[0] = cb.x; o[1] = cb.y; o[2] = cb.z; o[3] = cb.w; o[4] = sc;
        } else {
            o[0] = 0.f; o[1] = 0.f; o[2] = 0.f; o[3] = 0.f; o[4] = NEGF;
        }
    }
}

// ---------------- fallback: round-1 sequential NMS (used only if ws too small) ----------------
__global__ __launch_bounds__(1024) void kNMS(
        const float* __restrict__ cscore,
        const float4* __restrict__ cbox,
        const float4* __restrict__ cobox,
        const float* __restrict__ carea,
        float* __restrict__ out) {
    int img = blockIdx.x;
    int tid = threadIdx.x;
    __shared__ u64 warr[16];
    __shared__ float bb[5];
    float s[5], b0[5], b1[5], b2[5], b3[5], ar[5];
#pragma unroll
    for (int k = 0; k < 5; ++k) {
        int j = tid + k * 1024;
        if (j < NCAND) {
            int ci = img * NCAND + j;
            s[k] = cscore[ci];
            float4 b = cobox[ci];
            b0[k] = b.x; b1[k] = b.y; b2[k] = b.z; b3[k] = b.w;
            ar[k] = carea[ci];
        } else {
            s[k] = -3.4e38f;
            b0[k] = b1[k] = b2[k] = b3[k] = 0.f; ar[k] = 0.f;
        }
    }
    for (int step = 0; step < NPOST; ++step) {
        u64 comp = 0ULL;
#pragma unroll
        for (int k = 0; k < 5; ++k) {
            int j = tid + k * 1024;
            unsigned kk = key_of(s[k]);
            u64 c = ((u64)kk << 32) | (unsigned)(~j);
            comp = (c > comp) ? c : comp;
        }
#pragma unroll
        for (int off2 = 32; off2 >= 1; off2 >>= 1) {
            u64 o = __shfl_xor(comp, off2, 64);
            comp = (o > comp) ? o : comp;
        }
        if ((tid & 63) == 0) warr[tid >> 6] = comp;
        __syncthreads();
        u64 best = warr[0];
#pragma unroll
        for (int w = 1; w < 16; ++w) {
            u64 o = warr[w];
            best = (o > best) ? o : best;
        }
        int bidx = (int)(~(unsigned)best);
        float bscore = key_to_float((unsigned)(best >> 32));
        bool valid = bscore > -5.0e8f;
#pragma unroll
        for (int k = 0; k < 5; ++k) {
            int j = tid + k * 1024;
            if (j == bidx) {
                bb[0] = b0[k]; bb[1] = b1[k]; bb[2] = b2[k]; bb[3] = b3[k]; bb[4] = ar[k];
                float* o = out + ((size_t)img * NPOST + step) * 5;
                if (valid) {
                    float4 gb = cbox[img * NCAND + j];
                    o[0] = gb.x; o[1] = gb.y; o[2] = gb.z; o[3] = gb.w; o[4] = bscore;
                } else {
                    o[0] = 0.f; o[1] = 0.f; o[2] = 0.f; o[3] = 0.f; o[4] = NEGF;
                }
            }
        }
        __syncthreads();
        float ib0 = bb[0], ib1 = bb[1], ib2 = bb[2], ib3 = bb[3], iar = bb[4];
#pragma unroll
        for (int k = 0; k < 5; ++k) {
            int j = tid + k * 1024;
            float ltx = fmaxf(b0[k], ib0), lty = fmaxf(b1[k], ib1);
            float rbx = fminf(b2[k], ib2), rby = fminf(b3[k], ib3);
            float wx = fmaxf(rbx - ltx, 0.f), wy = fmaxf(rby - lty, 0.f);
            float inter = wx * wy;
            float denom = ar[k] + iar;
            denom = denom - inter;
            denom = denom + 1e-9f;
            float iou = inter / denom;
            if (iou > 0.7f) s[k] = NEGF;
            if (j == bidx) s[k] = NEGF;
        }
    }
}

extern "C" void kernel_launch(void* const* d_in, const int* in_sizes, int n_in,
                              void* d_out, int out_size, void* d_ws, size_t ws_size,
                              hipStream_t stream) {
    const int MS[5] = {516096, 129024, 32256, 8064, 2016};
    Ptrs P;
    for (int l = 0; l < 5; ++l) {
        P.lg[l] = (const float*)d_in[2 * l];
        P.dl[l] = (const float*)d_in[2 * l + 1];
    }
    char* w = (char*)d_ws;
    size_t off = 0;
    auto alloc = [&](size_t bytes) -> void* {
        void* pp = (void*)(w + off);
        off = (off + bytes + 255) & ~(size_t)255;
        return pp;
    };
    unsigned* hist  = (unsigned*)alloc((size_t)NTASK * NB1 * 4);
    unsigned* tinfo = (unsigned*)alloc(NTASK * 2 * 4);
    unsigned* cnt   = (unsigned*)alloc(NTASK * 4);
    u64* compb      = (u64*)alloc((size_t)NTASK * CAP * 8);
    float*  cscore  = (float*)alloc((size_t)NTASK * K_TOP * 4);
    float4* cbox    = (float4*)alloc((size_t)NTASK * K_TOP * 16);
    float4* cobox   = (float4*)alloc((size_t)NTASK * K_TOP * 16);
    float*  carea   = (float*)alloc((size_t)NTASK * K_TOP * 4);
    unsigned* cog   = (unsigned*)alloc((size_t)NTASK * K_TOP * 4);
    // NMS scratch
    float*  ssc     = (float*)alloc((size_t)NIMG * NCAND * 4);
    float4* sob     = (float4*)alloc((size_t)NIMG * NCAND * 16);
    float*  sar     = (float*)alloc((size_t)NIMG * NCAND * 4);
    float4* sclip   = (float4*)alloc((size_t)NIMG * NCAND * 16);
    size_t need = off;
    (void)in_sizes; (void)n_in; (void)out_size;

    size_t nhz = (size_t)NTASK * NB1;
    kZero<<<2048, 256, 0, stream>>>(hist, nhz);
    for (int l = 0; l < 5; ++l) {
        int m4 = MS[l] >> 2;
        int gx = (m4 + 8191) / 8192;       // ~32K elements per block
        dim3 g(gx, NIMG);
        kHist<<<g, 1024, 0, stream>>>(P.lg[l], MS[l], l, hist);
    }
    kSelectBin<<<NTASK, 256, 0, stream>>>(hist, tinfo, cnt);
    for (int l = 0; l < 5; ++l) {
        dim3 g((MS[l] + 255) / 256, NIMG);
        kCompact<<<g, 256, 0, stream>>>(P.lg[l], MS[l], l, tinfo, cnt, compb);
    }
    kSortSelect<<<NTASK, 1024, 0, stream>>>(P, cnt, compb, cscore, cbox, cobox, carea, cog);

    if (ws_size >= need) {
        kMerge<<<NIMG, 1024, 0, stream>>>(cscore, cbox, cobox, carea, cog,
                                          ssc, sob, sar, sclip);
        kScan<<<NIMG, 1024, 0, stream>>>(ssc, sclip, sob, sar, (float*)d_out);
    } else {
        kNMS<<<NIMG, 1024, 0, stream>>>(cscore, cbox, cobox, carea, (float*)d_out);
    }
}

// Round 10
// 232.402 us; speedup vs baseline: 3.1032x; 1.6632x over previous
//
#include <hip/hip_runtime.h>
#include <cstdint>
#include <cstddef>

#define NB1      16384      // 2^14 first-level radix bins
#define L1SHIFT  18         // key >> 18 -> 14-bit bin
#define CAP      4096       // compaction buffer per task (power of 2 for bitonic)
#define K_TOP    1000
#define NCAND    5000
#define NIMG     8
#define NLVL     5
#define NTASK    40
#define NPOST    300
#define NEGF     (-1e9f)
#define NWORDS   79         // ceil(5000/64)

typedef unsigned long long u64;

struct Ptrs {
    const float* lg[5];
    const float* dl[5];
};

__device__ __forceinline__ unsigned key_of(float f) {
    unsigned u = __float_as_uint(f);
    return (u & 0x80000000u) ? ~u : (u | 0x80000000u);
}
__device__ __forceinline__ float key_to_float(unsigned k) {
    unsigned u = (k & 0x80000000u) ? (k ^ 0x80000000u) : ~k;
    return __uint_as_float(u);
}

// ---------------- zero scratch ----------------
__global__ void kZero(unsigned* p, size_t n) {
    size_t i = (size_t)blockIdx.x * blockDim.x + threadIdx.x;
    size_t st = (size_t)gridDim.x * blockDim.x;
    for (; i < n; i += st) p[i] = 0u;
}

// ---------------- pass 1: LDS-privatized 14-bit histogram per (img,lvl) ----------------
__global__ __launch_bounds__(1024) void kHist(const float* __restrict__ lg,
                                              int m, int lvl,
                                              unsigned* __restrict__ hist) {
    int img  = blockIdx.y;
    int task = img * NLVL + lvl;
    __shared__ unsigned h[NB1];
    for (int i = threadIdx.x; i < NB1; i += 1024) h[i] = 0u;
    __syncthreads();
    int m4 = m >> 2;                       // all level sizes divisible by 4
    int chunk4 = (m4 + gridDim.x - 1) / (int)gridDim.x;
    int start4 = blockIdx.x * chunk4;
    int end4   = min(start4 + chunk4, m4);
    const float4* src = (const float4*)(lg + (size_t)img * m);
    for (int i = start4 + threadIdx.x; i < end4; i += 1024) {
        float4 v = src[i];
        atomicAdd(&h[key_of(v.x) >> L1SHIFT], 1u);
        atomicAdd(&h[key_of(v.y) >> L1SHIFT], 1u);
        atomicAdd(&h[key_of(v.z) >> L1SHIFT], 1u);
        atomicAdd(&h[key_of(v.w) >> L1SHIFT], 1u);
    }
    __syncthreads();
    unsigned* gh = hist + (size_t)task * NB1;
    for (int i = threadIdx.x; i < NB1; i += 1024) {
        unsigned c = h[i];
        if (c) atomicAdd(&gh[i], c);
    }
}

// ---------------- pass 2: find 14-bit prefix of the K-th largest ----------------
__global__ __launch_bounds__(256) void kSelectBin(const unsigned* __restrict__ hist,
                                                  unsigned* __restrict__ tinfo,
                                                  unsigned* __restrict__ cnt) {
    int task = blockIdx.x;
    const unsigned* h = hist + (size_t)task * NB1;
    __shared__ unsigned sblk[256];
    __shared__ unsigned sbin[64];
    __shared__ int sh_tb;
    __shared__ unsigned sh_rem;
    int t = threadIdx.x;
    unsigned s = 0;
    for (int i = 0; i < 64; ++i) s += h[t * 64 + i];
    sblk[t] = s;
    __syncthreads();
    if (t == 0) {
        unsigned rem = K_TOP; int tb = 0;
        for (int b = 255; b >= 0; --b) {
            if (sblk[b] < rem) rem -= sblk[b];
            else { tb = b; break; }
        }
        sh_tb = tb; sh_rem = rem;
    }
    __syncthreads();
    if (t < 64) sbin[t] = h[sh_tb * 64 + t];
    __syncthreads();
    if (t == 0) {
        unsigned rem = sh_rem; int pfx = sh_tb * 64;
        for (int b = 63; b >= 0; --b) {
            if (sbin[b] < rem) rem -= sbin[b];
            else { pfx = sh_tb * 64 + b; break; }
        }
        tinfo[task * 2]     = (unsigned)pfx;
        tinfo[task * 2 + 1] = rem;
        cnt[task] = 0u;
    }
}

// ---------------- pass 3: compact winners, LDS-staged, one global atomic/block ----
// Fat blocks (1024 thr, float4 strided loop) for deep ILP; winners appended to
// LDS; block reserves a contiguous range in compbuf with a single atomicAdd.
// Order within compbuf is irrelevant (kSortSelect sorts the full buffer).
__global__ __launch_bounds__(1024) void kCompact(const float* __restrict__ lg,
                                                 int m, int lvl,
                                                 const unsigned* __restrict__ tinfo,
                                                 unsigned* __restrict__ cnt,
                                                 u64* __restrict__ compbuf) {
    int img  = blockIdx.y;
    int task = img * NLVL + lvl;
    unsigned pfx = tinfo[task * 2];
    __shared__ u64 stage[CAP];
    __shared__ unsigned lcnt, gbase;
    if (threadIdx.x == 0) lcnt = 0u;
    __syncthreads();
    int m4 = m >> 2;                       // all level sizes divisible by 4
    int chunk4 = (m4 + gridDim.x - 1) / (int)gridDim.x;
    int start4 = blockIdx.x * chunk4;
    int end4   = min(start4 + chunk4, m4);
    const float4* src = (const float4*)(lg + (size_t)img * m);
    for (int i = start4 + threadIdx.x; i < end4; i += 1024) {
        float4 v = src[i];
        int j = i * 4;
        unsigned k0 = key_of(v.x);
        unsigned k1 = key_of(v.y);
        unsigned k2 = key_of(v.z);
        unsigned k3 = key_of(v.w);
        if ((k0 >> L1SHIFT) >= pfx) {
            unsigned p = atomicAdd(&lcnt, 1u);
            if (p < CAP) stage[p] = ((u64)k0 << 32) | (unsigned)(~(unsigned)(j));
        }
        if ((k1 >> L1SHIFT) >= pfx) {
            unsigned p = atomicAdd(&lcnt, 1u);
            if (p < CAP) stage[p] = ((u64)k1 << 32) | (unsigned)(~(unsigned)(j + 1));
        }
        if ((k2 >> L1SHIFT) >= pfx) {
            unsigned p = atomicAdd(&lcnt, 1u);
            if (p < CAP) stage[p] = ((u64)k2 << 32) | (unsigned)(~(unsigned)(j + 2));
        }
        if ((k3 >> L1SHIFT) >= pfx) {
            unsigned p = atomicAdd(&lcnt, 1u);
            if (p < CAP) stage[p] = ((u64)k3 << 32) | (unsigned)(~(unsigned)(j + 3));
        }
    }
    __syncthreads();
    if (threadIdx.x == 0) gbase = atomicAdd(&cnt[task], lcnt);
    __syncthreads();
    unsigned total = min(lcnt, (unsigned)CAP);
    unsigned base  = gbase;
    for (unsigned p = threadIdx.x; p < total; p += 1024) {
        unsigned pos = base + p;
        if (pos < CAP) compbuf[(size_t)task * CAP + pos] = stage[p];
    }
}

// ---------------- pass 4: sort candidates, decode boxes, resort by masked score ----
__global__ __launch_bounds__(1024) void kSortSelect(
        Ptrs p,
        const unsigned* __restrict__ cnt,
        const u64* __restrict__ compbuf,
        float* __restrict__ cscore,
        float4* __restrict__ cbox,
        float4* __restrict__ cobox,
        float* __restrict__ carea,
        unsigned* __restrict__ cog) {
    int task = blockIdx.x;
    int img = task / NLVL, lvl = task % NLVL;
    __shared__ u64 sortbuf[CAP + 1024];   // 40 KB; phase-2 reused as float farr[10240]
    __shared__ u64 buf2[1024];
    u64* buf = sortbuf;
    int n = min((int)cnt[task], CAP);
    for (int i = threadIdx.x; i < CAP; i += 1024)
        buf[i] = (i < n) ? compbuf[(size_t)task * CAP + i] : 0ULL;
    __syncthreads();
    for (int k = 2; k <= CAP; k <<= 1) {
        for (int j2 = k >> 1; j2 > 0; j2 >>= 1) {
            for (int i = threadIdx.x; i < CAP; i += 1024) {
                int pp = i ^ j2;
                if (pp > i) {
                    u64 A = buf[i], B = buf[pp];
                    bool up = ((i & k) == 0);
                    if (up ? (A < B) : (A > B)) { buf[i] = B; buf[pp] = A; }
                }
            }
            __syncthreads();
        }
    }
    const int   MS[5]     = {516096, 129024, 32256, 8064, 2016};
    const int   GW[5]     = {512, 256, 128, 64, 32};
    const float STRIDEF[5]= {4.f, 8.f, 16.f, 32.f, 64.f};
    const int   SIZEI[5]  = {32, 64, 128, 256, 512};
    int r = threadIdx.x;
    float sm = 0.f, x0 = 0.f, y0 = 0.f, x1 = 0.f, y1 = 0.f;
    float b0 = 0.f, b1 = 0.f, b2 = 0.f, b3 = 0.f, area = 0.f;
    if (r < K_TOP) {
        u64 c = buf[r];
        int idx = (int)(~(unsigned)c);
        int m = MS[lvl];
        if ((unsigned)idx >= (unsigned)m) idx = 0;   // safety (never expected)
        const float* lg = p.lg[lvl];
        const float* dl = p.dl[lvl];
        float score = lg[(size_t)img * m + idx];
        int a   = idx % 3;
        int loc = idx / 3;
        int gw  = GW[lvl];
        int x = loc % gw, y = loc / gw;
        double ssz = (double)SIZEI[lvl];
        double arr = (a == 0) ? 0.5 : ((a == 1) ? 1.0 : 2.0);
        double wd = sqrt(ssz * ssz / arr);
        double hd = arr * wd;
        float sx = (float)x * STRIDEF[lvl];
        float sy = (float)y * STRIDEF[lvl];
        float a0 = sx + (float)(-wd * 0.5);
        float a1 = sy + (float)(-hd * 0.5);
        float a2 = sx + (float)( wd * 0.5);
        float a3 = sy + (float)( hd * 0.5);
        float aw = a2 - a0, ah = a3 - a1;
        float acx = a0 + 0.5f * aw, acy = a1 + 0.5f * ah;
        size_t db = ((size_t)img * m + idx) * 4;
        float dx = dl[db], dy = dl[db + 1], dwv = dl[db + 2], dhv = dl[db + 3];
        const float CL = 4.135166556742356f;   // log(1000/16)
        float pw = expf(fminf(dwv, CL)) * aw;
        float ph = expf(fminf(dhv, CL)) * ah;
        float pcx = dx * aw + acx;
        float pcy = dy * ah + acy;
        x0 = pcx - 0.5f * pw; y0 = pcy - 0.5f * ph;
        x1 = pcx + 0.5f * pw; y1 = pcy + 0.5f * ph;
        x0 = fminf(fmaxf(x0, 0.f), 2048.f);
        x1 = fminf(fmaxf(x1, 0.f), 2048.f);
        y0 = fminf(fmaxf(y0, 0.f), 1344.f);
        y1 = fminf(fmaxf(y1, 0.f), 1344.f);
        bool keep = ((x1 - x0) > 0.f) && ((y1 - y0) > 0.f);
        sm = keep ? score : NEGF;
        float off = (float)lvl * 2049.0f;
        b0 = x0 + off; b1 = y0 + off; b2 = x1 + off; b3 = y1 + off;
        area = (b2 - b0) * (b3 - b1);
    }
    __syncthreads();                 // all buf reads done before reuse as farr
    float* farr = (float*)sortbuf;   // [0,1000) score  [1000,2000) area
                                     // [2000,6000) clip box  [6000,10000) offset box
    if (r < K_TOP) {
        farr[r] = sm;
        farr[1000 + r] = area;
        farr[2000 + 4 * r]     = x0;
        farr[2000 + 4 * r + 1] = y0;
        farr[2000 + 4 * r + 2] = x1;
        farr[2000 + 4 * r + 3] = y1;
        farr[6000 + 4 * r]     = b0;
        farr[6000 + 4 * r + 1] = b1;
        farr[6000 + 4 * r + 2] = b2;
        farr[6000 + 4 * r + 3] = b3;
    }
    buf2[r] = (r < K_TOP)
        ? (((u64)key_of(sm) << 32) | (unsigned)(~(unsigned)(lvl * K_TOP + r)))
        : 0ULL;
    __syncthreads();
    for (int k = 2; k <= 1024; k <<= 1) {
        for (int j2 = k >> 1; j2 > 0; j2 >>= 1) {
            int i = r, pp = i ^ j2;
            if (pp > i) {
                u64 A = buf2[i], B = buf2[pp];
                bool up = ((i & k) == 0);
                if (up ? (A < B) : (A > B)) { buf2[i] = B; buf2[pp] = A; }
            }
            __syncthreads();
        }
    }
    if (r < K_TOP) {
        u64 c2 = buf2[r];
        unsigned g2 = ~(unsigned)c2;
        int rsrc = (int)g2 - lvl * K_TOP;    // original within-level rank
        int ci = img * NCAND + lvl * K_TOP + r;
        cscore[ci] = farr[rsrc];
        carea[ci]  = farr[1000 + rsrc];
        cbox[ci]  = make_float4(farr[2000 + 4 * rsrc],     farr[2000 + 4 * rsrc + 1],
                                farr[2000 + 4 * rsrc + 2], farr[2000 + 4 * rsrc + 3]);
        cobox[ci] = make_float4(farr[6000 + 4 * rsrc],     farr[6000 + 4 * rsrc + 1],
                                farr[6000 + 4 * rsrc + 2], farr[6000 + 4 * rsrc + 3]);
        cog[ci] = (unsigned)rsrc;
    }
}

// ---------------- pass 5a: merge 5 sorted lists into global sorted order ----------------
__global__ __launch_bounds__(1024) void kMerge(
        const float* __restrict__ cscore,
        const float4* __restrict__ cbox,
        const float4* __restrict__ cobox,
        const float* __restrict__ carea,
        const unsigned* __restrict__ cog,
        float* __restrict__ ssc,
        float4* __restrict__ sob,
        float* __restrict__ sar,
        float4* __restrict__ sclip) {
    int img = blockIdx.x;
    __shared__ u64 comp[NCAND];
    for (int g = threadIdx.x; g < NCAND; g += 1024) {
        int lv = g / K_TOP;
        unsigned og = (unsigned)(lv * K_TOP) + cog[img * NCAND + g];
        comp[g] = ((u64)key_of(cscore[img * NCAND + g]) << 32) | (unsigned)(~og);
    }
    __syncthreads();
    for (int g = threadIdx.x; g < NCAND; g += 1024) {
        u64 c = comp[g];
        int lv = g / K_TOP;
        int pos = g - lv * K_TOP;    // elements > c within own (desc-sorted) level
        for (int lv2 = 0; lv2 < NLVL; ++lv2) {
            if (lv2 == lv) continue;
            int base = lv2 * K_TOP;
            int lo = 0, hi = K_TOP;
            while (lo < hi) {
                int mid = (lo + hi) >> 1;
                if (comp[base + mid] > c) lo = mid + 1; else hi = mid;
            }
            pos += lo;               // count of elements > c (composites unique)
        }
        int src = img * NCAND + g;
        int dst = img * NCAND + pos;
        ssc[dst]   = cscore[src];
        sob[dst]   = cobox[src];
        sar[dst]   = carea[src];
        sclip[dst] = cbox[src];
    }
}

// ---------------- pass 5: scan with just-in-time per-word suppression ----------------
__global__ __launch_bounds__(1024) void kScan(
        const float* __restrict__ ssc,
        const float4* __restrict__ sclip,
        const float4* __restrict__ sob,
        const float* __restrict__ sar,
        float* __restrict__ out) {
    int img = blockIdx.x;
    int tid = threadIdx.x;
    int lane = tid & 63;
    int wave = tid >> 6;
    __shared__ float4 wboxS[64];
    __shared__ float  warS[64];
    __shared__ float  wsscS[64];
    __shared__ u64    diagWS[64];
    __shared__ u64    partS[16];
    __shared__ float4 pboxAll[NPOST];
    __shared__ float  parAll[NPOST];
    __shared__ unsigned emS[NPOST];
    const int imgb = img * NCAND;

    int emitted = 0;
    bool done = false;
    for (int w = 0; w < NWORDS && !done; ++w) {
        // ---- stage word w ----
        if (tid < 64) {
            int j = w * 64 + tid;
            if (j < NCAND) {
                wboxS[tid] = sob[imgb + j];
                warS[tid]  = sar[imgb + j];
                wsscS[tid] = ssc[imgb + j];
            } else {
                wboxS[tid] = make_float4(0.f, 0.f, 0.f, 0.f);
                warS[tid]  = 0.f;
                wsscS[tid] = -3.4e38f;     // invalid -> scan stops here
            }
        }
        __syncthreads();
        // ---- parallel: suppression by previously emitted + own diag block ----
        float4 bc = wboxS[lane];
        float  arc = warS[lane];
        bool supp = false;
        for (int t = wave; t < emitted; t += 16) {
            float4 bp = pboxAll[t]; float arp = parAll[t];
            float ltx = fmaxf(bc.x, bp.x), lty = fmaxf(bc.y, bp.y);
            float rbx = fminf(bc.z, bp.z), rby = fminf(bc.w, bp.w);
            float wx = fmaxf(rbx - ltx, 0.f), wy = fmaxf(rby - lty, 0.f);
            float inter = wx * wy;
            float denom = (arc + arp) - inter + 1e-9f;
            supp |= (inter / denom) > 0.7f;
        }
        u64 sb = __ballot(supp);
        if (lane == 0) partS[wave] = sb;
#pragma unroll
        for (int rr = 0; rr < 4; ++rr) {
            int r = wave * 4 + rr;               // diag row r: box vs word's 64
            float4 bp = wboxS[r]; float arp = warS[r];
            float ltx = fmaxf(bc.x, bp.x), lty = fmaxf(bc.y, bp.y);
            float rbx = fminf(bc.z, bp.z), rby = fminf(bc.w, bp.w);
            float wx = fmaxf(rbx - ltx, 0.f), wy = fmaxf(rby - lty, 0.f);
            float inter = wx * wy;
            float denom = (arc + arp) - inter + 1e-9f;
            bool pred = (inter / denom) > 0.7f;
            u64 db = __ballot(pred);
            if (lane == 0) diagWS[r] = db;
        }
        __syncthreads();
        // ---- serial emission within word (redundant on all threads, LDS only) ----
        u64 sm = partS[0];
#pragma unroll
        for (int q = 1; q < 16; ++q) sm |= partS[q];
        u64 cur = ~sm;
        while (cur) {
            int b = __builtin_ctzll(cur);
            float sc = wsscS[b];
            if (sc <= -5.0e8f) { done = true; break; }   // sorted: rest invalid too
            if (tid == 0) {
                emS[emitted]     = (unsigned)(w * 64 + b);
                pboxAll[emitted] = wboxS[b];
                parAll[emitted]  = warS[b];
            }
            ++emitted;                                   // uniform
            if (emitted == NPOST) { done = true; break; }
            cur &= ~diagWS[b];
            cur &= ~(1ULL << b);
        }
        __syncthreads();             // pboxAll/parAll/emS visible for next word
    }
    // ---- parallel output gather ----
    for (int rr = tid; rr < NPOST; rr += 1024) {
        float* o = out + ((size_t)img * NPOST + rr) * 5;
        if (rr < emitted) {
            unsigned i = emS[rr];
            float4 cb = sclip[imgb + i];
            float sc = ssc[imgb + i];
            o[0] = cb.x; o[1] = cb.y; o[2] = cb.z; o[3] = cb.w; o[4] = sc;
        } else {
            o[0] = 0.f; o[1] = 0.f; o[2] = 0.f; o[3] = 0.f; o[4] = NEGF;
        }
    }
}

// ---------------- fallback: round-1 sequential NMS (used only if ws too small) ----------------
__global__ __launch_bounds__(1024) void kNMS(
        const float* __restrict__ cscore,
        const float4* __restrict__ cbox,
        const float4* __restrict__ cobox,
        const float* __restrict__ carea,
        float* __restrict__ out) {
    int img = blockIdx.x;
    int tid = threadIdx.x;
    __shared__ u64 warr[16];
    __shared__ float bb[5];
    float s[5], b0[5], b1[5], b2[5], b3[5], ar[5];
#pragma unroll
    for (int k = 0; k < 5; ++k) {
        int j = tid + k * 1024;
        if (j < NCAND) {
            int ci = img * NCAND + j;
            s[k] = cscore[ci];
            float4 b = cobox[ci];
            b0[k] = b.x; b1[k] = b.y; b2[k] = b.z; b3[k] = b.w;
            ar[k] = carea[ci];
        } else {
            s[k] = -3.4e38f;
            b0[k] = b1[k] = b2[k] = b3[k] = 0.f; ar[k] = 0.f;
        }
    }
    for (int step = 0; step < NPOST; ++step) {
        u64 comp = 0ULL;
#pragma unroll
        for (int k = 0; k < 5; ++k) {
            int j = tid + k * 1024;
            unsigned kk = key_of(s[k]);
            u64 c = ((u64)kk << 32) | (unsigned)(~j);
            comp = (c > comp) ? c : comp;
        }
#pragma unroll
        for (int off2 = 32; off2 >= 1; off2 >>= 1) {
            u64 o = __shfl_xor(comp, off2, 64);
            comp = (o > comp) ? o : comp;
        }
        if ((tid & 63) == 0) warr[tid >> 6] = comp;
        __syncthreads();
        u64 best = warr[0];
#pragma unroll
        for (int w = 1; w < 16; ++w) {
            u64 o = warr[w];
            best = (o > best) ? o : best;
        }
        int bidx = (int)(~(unsigned)best);
        float bscore = key_to_float((unsigned)(best >> 32));
        bool valid = bscore > -5.0e8f;
#pragma unroll
        for (int k = 0; k < 5; ++k) {
            int j = tid + k * 1024;
            if (j == bidx) {
                bb[0] = b0[k]; bb[1] = b1[k]; bb[2] = b2[k]; bb[3] = b3[k]; bb[4] = ar[k];
                float* o = out + ((size_t)img * NPOST + step) * 5;
                if (valid) {
                    float4 gb = cbox[img * NCAND + j];
                    o[0] = gb.x; o[1] = gb.y; o[2] = gb.z; o[3] = gb.w; o[4] = bscore;
                } else {
                    o[0] = 0.f; o[1] = 0.f; o[2] = 0.f; o[3] = 0.f; o[4] = NEGF;
                }
            }
        }
        __syncthreads();
        float ib0 = bb[0], ib1 = bb[1], ib2 = bb[2], ib3 = bb[3], iar = bb[4];
#pragma unroll
        for (int k = 0; k < 5; ++k) {
            int j = tid + k * 1024;
            float ltx = fmaxf(b0[k], ib0), lty = fmaxf(b1[k], ib1);
            float rbx = fminf(b2[k], ib2), rby = fminf(b3[k], ib3);
            float wx = fmaxf(rbx - ltx, 0.f), wy = fmaxf(rby - lty, 0.f);
            float inter = wx * wy;
            float denom = ar[k] + iar;
            denom = denom - inter;
            denom = denom + 1e-9f;
            float iou = inter / denom;
            if (iou > 0.7f) s[k] = NEGF;
            if (j == bidx) s[k] = NEGF;
        }
    }
}

extern "C" void kernel_launch(void* const* d_in, const int* in_sizes, int n_in,
                              void* d_out, int out_size, void* d_ws, size_t ws_size,
                              hipStream_t stream) {
    const int MS[5] = {516096, 129024, 32256, 8064, 2016};
    Ptrs P;
    for (int l = 0; l < 5; ++l) {
        P.lg[l] = (const float*)d_in[2 * l];
        P.dl[l] = (const float*)d_in[2 * l + 1];
    }
    char* w = (char*)d_ws;
    size_t off = 0;
    auto alloc = [&](size_t bytes) -> void* {
        void* pp = (void*)(w + off);
        off = (off + bytes + 255) & ~(size_t)255;
        return pp;
    };
    unsigned* hist  = (unsigned*)alloc((size_t)NTASK * NB1 * 4);
    unsigned* tinfo = (unsigned*)alloc(NTASK * 2 * 4);
    unsigned* cnt   = (unsigned*)alloc(NTASK * 4);
    u64* compb      = (u64*)alloc((size_t)NTASK * CAP * 8);
    float*  cscore  = (float*)alloc((size_t)NTASK * K_TOP * 4);
    float4* cbox    = (float4*)alloc((size_t)NTASK * K_TOP * 16);
    float4* cobox   = (float4*)alloc((size_t)NTASK * K_TOP * 16);
    float*  carea   = (float*)alloc((size_t)NTASK * K_TOP * 4);
    unsigned* cog   = (unsigned*)alloc((size_t)NTASK * K_TOP * 4);
    // NMS scratch
    float*  ssc     = (float*)alloc((size_t)NIMG * NCAND * 4);
    float4* sob     = (float4*)alloc((size_t)NIMG * NCAND * 16);
    float*  sar     = (float*)alloc((size_t)NIMG * NCAND * 4);
    float4* sclip   = (float4*)alloc((size_t)NIMG * NCAND * 16);
    size_t need = off;
    (void)in_sizes; (void)n_in; (void)out_size;

    size_t nhz = (size_t)NTASK * NB1;
    kZero<<<2048, 256, 0, stream>>>(hist, nhz);
    for (int l = 0; l < 5; ++l) {
        int m4 = MS[l] >> 2;
        int gx = (m4 + 8191) / 8192;       // ~32K elements per block
        dim3 g(gx, NIMG);
        kHist<<<g, 1024, 0, stream>>>(P.lg[l], MS[l], l, hist);
    }
    kSelectBin<<<NTASK, 256, 0, stream>>>(hist, tinfo, cnt);
    for (int l = 0; l < 5; ++l) {
        int m4 = MS[l] >> 2;
        int gx = (m4 + 4095) / 4096;       // ~16K elements per block
        dim3 g(gx, NIMG);
        kCompact<<<g, 1024, 0, stream>>>(P.lg[l], MS[l], l, tinfo, cnt, compb);
    }
    kSortSelect<<<NTASK, 1024, 0, stream>>>(P, cnt, compb, cscore, cbox, cobox, carea, cog);

    if (ws_size >= need) {
        kMerge<<<NIMG, 1024, 0, stream>>>(cscore, cbox, cobox, carea, cog,
                                          ssc, sob, sar, sclip);
        kScan<<<NIMG, 1024, 0, stream>>>(ssc, sclip, sob, sar, (float*)d_out);
    } else {
        kNMS<<<NIMG, 1024, 0, stream>>>(cscore, cbox, cobox, carea, (float*)d_out);
    }
}

// Round 11
// 179.064 us; speedup vs baseline: 4.0276x; 1.2979x over previous
//
#include <hip/hip_runtime.h>
#include <cstdint>
#include <cstddef>

#define NB1      16384      // 2^14 first-level radix bins
#define L1SHIFT  18         // key >> 18 -> 14-bit bin
#define CAP      4096       // compaction buffer per task
#define K_TOP    1000
#define NCAND    5000
#define NIMG     8
#define NLVL     5
#define NTASK    40
#define NPOST    300
#define NEGF     (-1e9f)
#define NWORDS   79         // ceil(5000/64)

typedef unsigned long long u64;

struct Ptrs {
    const float* lg[5];
    const float* dl[5];
};

__device__ __forceinline__ unsigned key_of(float f) {
    unsigned u = __float_as_uint(f);
    return (u & 0x80000000u) ? ~u : (u | 0x80000000u);
}

// ---------------- zero scratch ----------------
__global__ void kZero(unsigned* p, size_t n) {
    size_t i = (size_t)blockIdx.x * blockDim.x + threadIdx.x;
    size_t st = (size_t)gridDim.x * blockDim.x;
    for (; i < n; i += st) p[i] = 0u;
}

// ---------------- pass 1: LDS-privatized 14-bit histogram per (img,lvl) ----------------
__global__ __launch_bounds__(1024) void kHist(const float* __restrict__ lg,
                                              int m, int lvl,
                                              unsigned* __restrict__ hist) {
    int img  = blockIdx.y;
    int task = img * NLVL + lvl;
    __shared__ unsigned h[NB1];
    for (int i = threadIdx.x; i < NB1; i += 1024) h[i] = 0u;
    __syncthreads();
    int m4 = m >> 2;                       // all level sizes divisible by 4
    int chunk4 = (m4 + gridDim.x - 1) / (int)gridDim.x;
    int start4 = blockIdx.x * chunk4;
    int end4   = min(start4 + chunk4, m4);
    const float4* src = (const float4*)(lg + (size_t)img * m);
    for (int i = start4 + threadIdx.x; i < end4; i += 1024) {
        float4 v = src[i];
        atomicAdd(&h[key_of(v.x) >> L1SHIFT], 1u);
        atomicAdd(&h[key_of(v.y) >> L1SHIFT], 1u);
        atomicAdd(&h[key_of(v.z) >> L1SHIFT], 1u);
        atomicAdd(&h[key_of(v.w) >> L1SHIFT], 1u);
    }
    __syncthreads();
    unsigned* gh = hist + (size_t)task * NB1;
    for (int i = threadIdx.x; i < NB1; i += 1024) {
        unsigned c = h[i];
        if (c) atomicAdd(&gh[i], c);
    }
}

// ---------------- pass 2: find 14-bit prefix of the K-th largest ----------------
__global__ __launch_bounds__(256) void kSelectBin(const unsigned* __restrict__ hist,
                                                  unsigned* __restrict__ tinfo,
                                                  unsigned* __restrict__ cnt) {
    int task = blockIdx.x;
    const unsigned* h = hist + (size_t)task * NB1;
    __shared__ unsigned sblk[256];
    __shared__ unsigned sbin[64];
    __shared__ int sh_tb;
    __shared__ unsigned sh_rem;
    int t = threadIdx.x;
    unsigned s = 0;
    for (int i = 0; i < 64; ++i) s += h[t * 64 + i];
    sblk[t] = s;
    __syncthreads();
    if (t == 0) {
        unsigned rem = K_TOP; int tb = 0;
        for (int b = 255; b >= 0; --b) {
            if (sblk[b] < rem) rem -= sblk[b];
            else { tb = b; break; }
        }
        sh_tb = tb; sh_rem = rem;
    }
    __syncthreads();
    if (t < 64) sbin[t] = h[sh_tb * 64 + t];
    __syncthreads();
    if (t == 0) {
        unsigned rem = sh_rem; int pfx = sh_tb * 64;
        for (int b = 63; b >= 0; --b) {
            if (sbin[b] < rem) rem -= sbin[b];
            else { pfx = sh_tb * 64 + b; break; }
        }
        tinfo[task * 2]     = (unsigned)pfx;
        tinfo[task * 2 + 1] = rem;
        cnt[task] = 0u;
    }
}

// ---------------- pass 3: compact winners, LDS-staged, one global atomic/block ----
__global__ __launch_bounds__(1024) void kCompact(const float* __restrict__ lg,
                                                 int m, int lvl,
                                                 const unsigned* __restrict__ tinfo,
                                                 unsigned* __restrict__ cnt,
                                                 u64* __restrict__ compbuf) {
    int img  = blockIdx.y;
    int task = img * NLVL + lvl;
    unsigned pfx = tinfo[task * 2];
    __shared__ u64 stage[CAP];
    __shared__ unsigned lcnt, gbase;
    if (threadIdx.x == 0) lcnt = 0u;
    __syncthreads();
    int m4 = m >> 2;
    int chunk4 = (m4 + gridDim.x - 1) / (int)gridDim.x;
    int start4 = blockIdx.x * chunk4;
    int end4   = min(start4 + chunk4, m4);
    const float4* src = (const float4*)(lg + (size_t)img * m);
    for (int i = start4 + threadIdx.x; i < end4; i += 1024) {
        float4 v = src[i];
        int j = i * 4;
        unsigned k0 = key_of(v.x);
        unsigned k1 = key_of(v.y);
        unsigned k2 = key_of(v.z);
        unsigned k3 = key_of(v.w);
        if ((k0 >> L1SHIFT) >= pfx) {
            unsigned p = atomicAdd(&lcnt, 1u);
            if (p < CAP) stage[p] = ((u64)k0 << 32) | (unsigned)(~(unsigned)(j));
        }
        if ((k1 >> L1SHIFT) >= pfx) {
            unsigned p = atomicAdd(&lcnt, 1u);
            if (p < CAP) stage[p] = ((u64)k1 << 32) | (unsigned)(~(unsigned)(j + 1));
        }
        if ((k2 >> L1SHIFT) >= pfx) {
            unsigned p = atomicAdd(&lcnt, 1u);
            if (p < CAP) stage[p] = ((u64)k2 << 32) | (unsigned)(~(unsigned)(j + 2));
        }
        if ((k3 >> L1SHIFT) >= pfx) {
            unsigned p = atomicAdd(&lcnt, 1u);
            if (p < CAP) stage[p] = ((u64)k3 << 32) | (unsigned)(~(unsigned)(j + 3));
        }
    }
    __syncthreads();
    if (threadIdx.x == 0) gbase = atomicAdd(&cnt[task], lcnt);
    __syncthreads();
    unsigned total = min(lcnt, (unsigned)CAP);
    unsigned base  = gbase;
    for (unsigned p = threadIdx.x; p < total; p += 1024) {
        unsigned pos = base + p;
        if (pos < CAP) compbuf[(size_t)task * CAP + pos] = stage[p];
    }
}

// ---------------- pass 4: split-sort (sure/boundary), decode, valid-compact ----
// sure (bin > pfx, count S <= 999) and boundary (bin == pfx) sorted concurrently
// with one unified 1024-bitonic schedule; final order = sure ++ bnd. Masked
// (empty-box) candidates are dropped via block prefix-scan; per-level valid
// counts go to vcnt. Output lists: valid candidates, desc score, orig-rank in cog.
__global__ __launch_bounds__(1024) void kSortSelect(
        Ptrs p,
        const unsigned* __restrict__ cnt,
        const unsigned* __restrict__ tinfo,
        const u64* __restrict__ compbuf,
        float* __restrict__ cscore,
        float4* __restrict__ cbox,
        float4* __restrict__ cobox,
        float* __restrict__ carea,
        unsigned* __restrict__ cog,
        unsigned* __restrict__ vcnt) {
    int task = blockIdx.x;
    int img = task / NLVL, lvl = task % NLVL;
    int tid = threadIdx.x;
    __shared__ u64 sure[1024];
    __shared__ u64 bnd[2048];
    __shared__ unsigned cS, cB;
    if (tid == 0) { cS = 0u; cB = 0u; }
    sure[tid] = 0ULL;
    bnd[tid] = 0ULL; bnd[tid + 1024] = 0ULL;
    __syncthreads();
    int n = min((int)cnt[task], CAP);
    unsigned pfx = tinfo[task * 2];
    for (int i = tid; i < n; i += 1024) {
        u64 c = compbuf[(size_t)task * CAP + i];
        unsigned bin = (unsigned)(c >> (32 + L1SHIFT));
        if (bin > pfx) {
            unsigned q = atomicAdd(&cS, 1u);
            if (q < 1024) sure[q] = c;
        } else {
            unsigned q = atomicAdd(&cB, 1u);
            if (q < 2048) bnd[q] = c;
        }
    }
    __syncthreads();
    unsigned S = cS;
    unsigned B = cB;
    // unified descending bitonic: threads 0-511 sort sure[1024], 512-1023 bnd[0:1024]
    {
        u64* arr = (tid < 512) ? sure : bnd;
        int q = tid & 511;
        for (int k = 2; k <= 1024; k <<= 1) {
            for (int j = k >> 1; j > 0; j >>= 1) {
                int i = ((q & ~(j - 1)) << 1) | (q & (j - 1));
                int pp = i | j;
                u64 A = arr[i], Bv = arr[pp];
                bool up = ((i & k) == 0);
                if (up ? (A < Bv) : (A > Bv)) { arr[i] = Bv; arr[pp] = A; }
                __syncthreads();
            }
        }
    }
    if (B > 1024) {    // statistically never; full 2048 network re-sorts bnd
        for (int k = 2; k <= 2048; k <<= 1)
            for (int j = k >> 1; j > 0; j >>= 1) {
                int i = ((tid & ~(j - 1)) << 1) | (tid & (j - 1));
                int pp = i | j;
                u64 A = bnd[i], Bv = bnd[pp];
                bool up = ((i & k) == 0);
                if (up ? (A < Bv) : (A > Bv)) { bnd[i] = Bv; bnd[pp] = A; }
                __syncthreads();
            }
    }
    // rank r composite
    int r = tid;
    u64 c = 0ULL;
    if (r < K_TOP) c = (r < (int)S) ? sure[r] : ((r - (int)S < (int)B) ? bnd[r - (int)S] : 0ULL);
    __syncthreads();                 // all sure/bnd reads done (bnd reused for scan)

    const int   MS[5]     = {516096, 129024, 32256, 8064, 2016};
    const int   GW[5]     = {512, 256, 128, 64, 32};
    const float STRIDEF[5]= {4.f, 8.f, 16.f, 32.f, 64.f};
    const int   SIZEI[5]  = {32, 64, 128, 256, 512};
    float sm = NEGF, x0 = 0.f, y0 = 0.f, x1 = 0.f, y1 = 0.f;
    float b0 = 0.f, b1 = 0.f, b2 = 0.f, b3 = 0.f, area = 0.f;
    bool valid = false;
    if (r < K_TOP) {
        int idx = (int)(~(unsigned)c);
        int m = MS[lvl];
        if ((unsigned)idx >= (unsigned)m) idx = 0;   // safety (never expected)
        const float* lg = p.lg[lvl];
        const float* dl = p.dl[lvl];
        float score = lg[(size_t)img * m + idx];
        int a   = idx % 3;
        int loc = idx / 3;
        int gw  = GW[lvl];
        int x = loc % gw, y = loc / gw;
        double ssz = (double)SIZEI[lvl];
        double arr = (a == 0) ? 0.5 : ((a == 1) ? 1.0 : 2.0);
        double wd = sqrt(ssz * ssz / arr);
        double hd = arr * wd;
        float sx = (float)x * STRIDEF[lvl];
        float sy = (float)y * STRIDEF[lvl];
        float a0 = sx + (float)(-wd * 0.5);
        float a1 = sy + (float)(-hd * 0.5);
        float a2 = sx + (float)( wd * 0.5);
        float a3 = sy + (float)( hd * 0.5);
        float aw = a2 - a0, ah = a3 - a1;
        float acx = a0 + 0.5f * aw, acy = a1 + 0.5f * ah;
        size_t db = ((size_t)img * m + idx) * 4;
        float dx = dl[db], dy = dl[db + 1], dwv = dl[db + 2], dhv = dl[db + 3];
        const float CL = 4.135166556742356f;   // log(1000/16)
        float pw = expf(fminf(dwv, CL)) * aw;
        float ph = expf(fminf(dhv, CL)) * ah;
        float pcx = dx * aw + acx;
        float pcy = dy * ah + acy;
        x0 = pcx - 0.5f * pw; y0 = pcy - 0.5f * ph;
        x1 = pcx + 0.5f * pw; y1 = pcy + 0.5f * ph;
        x0 = fminf(fmaxf(x0, 0.f), 2048.f);
        x1 = fminf(fmaxf(x1, 0.f), 2048.f);
        y0 = fminf(fmaxf(y0, 0.f), 1344.f);
        y1 = fminf(fmaxf(y1, 0.f), 1344.f);
        bool keep = ((x1 - x0) > 0.f) && ((y1 - y0) > 0.f);
        valid = keep;
        sm = score;
        float off = (float)lvl * 2049.0f;
        b0 = x0 + off; b1 = y0 + off; b2 = x1 + off; b3 = y1 + off;
        area = (b2 - b0) * (b3 - b1);
    }
    // block prefix scan over valid flags (Hillis-Steele, ping-pong in bnd region)
    int* sc1 = (int*)bnd;
    int* sc2 = sc1 + 1024;
    sc1[tid] = valid ? 1 : 0;
    __syncthreads();
    int* sA = sc1; int* sB = sc2;
    for (int dd = 1; dd < 1024; dd <<= 1) {
        int v = sA[tid];
        if (tid >= dd) v += sA[tid - dd];
        sB[tid] = v;
        __syncthreads();
        int* t2 = sA; sA = sB; sB = t2;
    }
    int incl  = sA[tid];
    int total = sA[1023];
    int pos   = incl - (valid ? 1 : 0);
    if (valid) {
        int ci = img * NCAND + lvl * K_TOP + pos;
        cscore[ci] = sm;
        carea[ci]  = area;
        cbox[ci]   = make_float4(x0, y0, x1, y1);
        cobox[ci]  = make_float4(b0, b1, b2, b3);
        cog[ci]    = (unsigned)r;
    }
    if (tid == 0) vcnt[task] = (unsigned)total;
}

// ---------------- pass 5a: merge 5 variable-length sorted lists ----------------
__global__ __launch_bounds__(1024) void kMerge(
        const float* __restrict__ cscore,
        const float4* __restrict__ cbox,
        const float4* __restrict__ cobox,
        const float* __restrict__ carea,
        const unsigned* __restrict__ cog,
        const unsigned* __restrict__ vcnt,
        float* __restrict__ ssc,
        float4* __restrict__ sob,
        float* __restrict__ sar,
        float4* __restrict__ sclip) {
    int img = blockIdx.x;
    int tid = threadIdx.x;
    __shared__ u64 comp[NCAND];
    __shared__ int LS[NLVL];
    if (tid < NLVL) LS[tid] = (int)vcnt[img * NLVL + tid];
    __syncthreads();
    for (int g = tid; g < NCAND; g += 1024) {
        int lv = g / K_TOP, gl = g - lv * K_TOP;
        u64 c = 0ULL;
        if (gl < LS[lv]) {
            int src = img * NCAND + g;
            unsigned og = (unsigned)(lv * K_TOP) + cog[src];
            c = ((u64)key_of(cscore[src]) << 32) | (unsigned)(~og);
        }
        comp[g] = c;
    }
    __syncthreads();
    int V = LS[0] + LS[1] + LS[2] + LS[3] + LS[4];
    for (int g = tid; g < NCAND; g += 1024) {
        int lv = g / K_TOP, gl = g - lv * K_TOP;
        if (gl < LS[lv]) {
            u64 c = comp[g];
            int pos = gl;
            for (int lv2 = 0; lv2 < NLVL; ++lv2) {
                if (lv2 == lv) continue;
                int base = lv2 * K_TOP;
                int lo = 0, hi = LS[lv2];
                while (lo < hi) {
                    int mid = (lo + hi) >> 1;
                    if (comp[base + mid] > c) lo = mid + 1; else hi = mid;
                }
                pos += lo;
            }
            int src = img * NCAND + g;
            int dst = img * NCAND + pos;
            ssc[dst]   = cscore[src];
            sob[dst]   = cobox[src];
            sar[dst]   = carea[src];
            sclip[dst] = cbox[src];
        }
    }
    for (int t = V + tid; t < NCAND; t += 1024) {
        int dst = img * NCAND + t;
        ssc[dst]   = NEGF;
        sob[dst]   = make_float4(0.f, 0.f, 0.f, 0.f);
        sar[dst]   = 0.f;
        sclip[dst] = make_float4(0.f, 0.f, 0.f, 0.f);
    }
}

// ---------------- pass 5b: scan with just-in-time per-word suppression ----------------
__global__ __launch_bounds__(1024) void kScan(
        const float* __restrict__ ssc,
        const float4* __restrict__ sclip,
        const float4* __restrict__ sob,
        const float* __restrict__ sar,
        float* __restrict__ out) {
    int img = blockIdx.x;
    int tid = threadIdx.x;
    int lane = tid & 63;
    int wave = tid >> 6;
    __shared__ float4 wboxS[64];
    __shared__ float  warS[64];
    __shared__ float  wsscS[64];
    __shared__ u64    diagWS[64];
    __shared__ u64    partS[16];
    __shared__ float4 pboxAll[NPOST];
    __shared__ float  parAll[NPOST];
    __shared__ unsigned emS[NPOST];
    const int imgb = img * NCAND;

    int emitted = 0;
    bool done = false;
    for (int w = 0; w < NWORDS && !done; ++w) {
        if (tid < 64) {
            int j = w * 64 + tid;
            if (j < NCAND) {
                wboxS[tid] = sob[imgb + j];
                warS[tid]  = sar[imgb + j];
                wsscS[tid] = ssc[imgb + j];
            } else {
                wboxS[tid] = make_float4(0.f, 0.f, 0.f, 0.f);
                warS[tid]  = 0.f;
                wsscS[tid] = -3.4e38f;
            }
        }
        __syncthreads();
        float4 bc = wboxS[lane];
        float  arc = warS[lane];
        bool supp = false;
        for (int t = wave; t < emitted; t += 16) {
            float4 bp = pboxAll[t]; float arp = parAll[t];
            float ltx = fmaxf(bc.x, bp.x), lty = fmaxf(bc.y, bp.y);
            float rbx = fminf(bc.z, bp.z), rby = fminf(bc.w, bp.w);
            float wx = fmaxf(rbx - ltx, 0.f), wy = fmaxf(rby - lty, 0.f);
            float inter = wx * wy;
            float denom = (arc + arp) - inter + 1e-9f;
            supp |= (inter / denom) > 0.7f;
        }
        u64 sb = __ballot(supp);
        if (lane == 0) partS[wave] = sb;
#pragma unroll
        for (int rr = 0; rr < 4; ++rr) {
            int r = wave * 4 + rr;
            float4 bp = wboxS[r]; float arp = warS[r];
            float ltx = fmaxf(bc.x, bp.x), lty = fmaxf(bc.y, bp.y);
            float rbx = fminf(bc.z, bp.z), rby = fminf(bc.w, bp.w);
            float wx = fmaxf(rbx - ltx, 0.f), wy = fmaxf(rby - lty, 0.f);
            float inter = wx * wy;
            float denom = (arc + arp) - inter + 1e-9f;
            bool pred = (inter / denom) > 0.7f;
            u64 db = __ballot(pred);
            if (lane == 0) diagWS[r] = db;
        }
        __syncthreads();
        u64 sm = partS[0];
#pragma unroll
        for (int q = 1; q < 16; ++q) sm |= partS[q];
        u64 cur = ~sm;
        while (cur) {
            int b = __builtin_ctzll(cur);
            float sc = wsscS[b];
            if (sc <= -5.0e8f) { done = true; break; }
            if (tid == 0) {
                emS[emitted]     = (unsigned)(w * 64 + b);
                pboxAll[emitted] = wboxS[b];
                parAll[emitted]  = warS[b];
            }
            ++emitted;
            if (emitted == NPOST) { done = true; break; }
            cur &= ~diagWS[b];
            cur &= ~(1ULL << b);
        }
        __syncthreads();
    }
    for (int rr = tid; rr < NPOST; rr += 1024) {
        float* o = out + ((size_t)img * NPOST + rr) * 5;
        if (rr < emitted) {
            unsigned i = emS[rr];
            float4 cb = sclip[imgb + i];
            float sc = ssc[imgb + i];
            o[0] = cb.x; o[1] = cb.y; o[2] = cb.z; o[3] = cb.w; o[4] = sc;
        } else {
            o[0] = 0.f; o[1] = 0.f; o[2] = 0.f; o[3] = 0.f; o[4] = NEGF;
        }
    }
}

extern "C" void kernel_launch(void* const* d_in, const int* in_sizes, int n_in,
                              void* d_out, int out_size, void* d_ws, size_t ws_size,
                              hipStream_t stream) {
    const int MS[5] = {516096, 129024, 32256, 8064, 2016};
    Ptrs P;
    for (int l = 0; l < 5; ++l) {
        P.lg[l] = (const float*)d_in[2 * l];
        P.dl[l] = (const float*)d_in[2 * l + 1];
    }
    char* w = (char*)d_ws;
    size_t off = 0;
    auto alloc = [&](size_t bytes) -> void* {
        void* pp = (void*)(w + off);
        off = (off + bytes + 255) & ~(size_t)255;
        return pp;
    };
    unsigned* hist  = (unsigned*)alloc((size_t)NTASK * NB1 * 4);
    unsigned* tinfo = (unsigned*)alloc(NTASK * 2 * 4);
    unsigned* cnt   = (unsigned*)alloc(NTASK * 4);
    u64* compb      = (u64*)alloc((size_t)NTASK * CAP * 8);
    float*  cscore  = (float*)alloc((size_t)NTASK * K_TOP * 4);
    float4* cbox    = (float4*)alloc((size_t)NTASK * K_TOP * 16);
    float4* cobox   = (float4*)alloc((size_t)NTASK * K_TOP * 16);
    float*  carea   = (float*)alloc((size_t)NTASK * K_TOP * 4);
    unsigned* cog   = (unsigned*)alloc((size_t)NTASK * K_TOP * 4);
    unsigned* vcnt  = (unsigned*)alloc(NTASK * 4);
    float*  ssc     = (float*)alloc((size_t)NIMG * NCAND * 4);
    float4* sob     = (float4*)alloc((size_t)NIMG * NCAND * 16);
    float*  sar     = (float*)alloc((size_t)NIMG * NCAND * 4);
    float4* sclip   = (float4*)alloc((size_t)NIMG * NCAND * 16);
    (void)in_sizes; (void)n_in; (void)out_size; (void)ws_size;

    size_t nhz = (size_t)NTASK * NB1;
    kZero<<<2048, 256, 0, stream>>>(hist, nhz);
    for (int l = 0; l < 5; ++l) {
        int m4 = MS[l] >> 2;
        int gx = (m4 + 8191) / 8192;       // ~32K elements per block
        dim3 g(gx, NIMG);
        kHist<<<g, 1024, 0, stream>>>(P.lg[l], MS[l], l, hist);
    }
    kSelectBin<<<NTASK, 256, 0, stream>>>(hist, tinfo, cnt);
    for (int l = 0; l < 5; ++l) {
        int m4 = MS[l] >> 2;
        int gx = (m4 + 4095) / 4096;       // ~16K elements per block
        dim3 g(gx, NIMG);
        kCompact<<<g, 1024, 0, stream>>>(P.lg[l], MS[l], l, tinfo, cnt, compb);
    }
    kSortSelect<<<NTASK, 1024, 0, stream>>>(P, cnt, tinfo, compb,
                                            cscore, cbox, cobox, carea, cog, vcnt);
    kMerge<<<NIMG, 1024, 0, stream>>>(cscore, cbox, cobox, carea, cog, vcnt,
                                      ssc, sob, sar, sclip);
    kScan<<<NIMG, 1024, 0, stream>>>(ssc, sclip, sob, sar, (float*)d_out);
}

// Round 12
// 175.266 us; speedup vs baseline: 4.1148x; 1.0217x over previous
//
#include <hip/hip_runtime.h>
#include <cstdint>
#include <cstddef>

#define NB1      16384      // 2^14 first-level radix bins
#define L1SHIFT  18         // key >> 18 -> 14-bit bin
#define CAP      4096       // compaction buffer per task
#define K_TOP    1000
#define NCAND    5000
#define NIMG     8
#define NLVL     5
#define NTASK    40
#define NPOST    300
#define NEGF     (-1e9f)
#define NWORDS   79         // ceil(5000/64)
#define NPAD     (NWORDS * 64)   // 5056, padded candidate count

typedef unsigned long long u64;

struct Ptrs {
    const float* lg[5];
    const float* dl[5];
};

__device__ __forceinline__ unsigned key_of(float f) {
    unsigned u = __float_as_uint(f);
    return (u & 0x80000000u) ? ~u : (u | 0x80000000u);
}

// ---------------- zero scratch ----------------
__global__ void kZero(unsigned* p, size_t n) {
    size_t i = (size_t)blockIdx.x * blockDim.x + threadIdx.x;
    size_t st = (size_t)gridDim.x * blockDim.x;
    for (; i < n; i += st) p[i] = 0u;
}

// ---------------- pass 1: LDS-privatized 14-bit histogram per (img,lvl) ----------------
__global__ __launch_bounds__(1024) void kHist(const float* __restrict__ lg,
                                              int m, int lvl,
                                              unsigned* __restrict__ hist) {
    int img  = blockIdx.y;
    int task = img * NLVL + lvl;
    __shared__ unsigned h[NB1];
    for (int i = threadIdx.x; i < NB1; i += 1024) h[i] = 0u;
    __syncthreads();
    int m4 = m >> 2;                       // all level sizes divisible by 4
    int chunk4 = (m4 + gridDim.x - 1) / (int)gridDim.x;
    int start4 = blockIdx.x * chunk4;
    int end4   = min(start4 + chunk4, m4);
    const float4* src = (const float4*)(lg + (size_t)img * m);
    for (int i = start4 + threadIdx.x; i < end4; i += 1024) {
        float4 v = src[i];
        atomicAdd(&h[key_of(v.x) >> L1SHIFT], 1u);
        atomicAdd(&h[key_of(v.y) >> L1SHIFT], 1u);
        atomicAdd(&h[key_of(v.z) >> L1SHIFT], 1u);
        atomicAdd(&h[key_of(v.w) >> L1SHIFT], 1u);
    }
    __syncthreads();
    unsigned* gh = hist + (size_t)task * NB1;
    for (int i = threadIdx.x; i < NB1; i += 1024) {
        unsigned c = h[i];
        if (c) atomicAdd(&gh[i], c);
    }
}

// ---------------- pass 2: find 14-bit prefix of the K-th largest ----------------
__global__ __launch_bounds__(256) void kSelectBin(const unsigned* __restrict__ hist,
                                                  unsigned* __restrict__ tinfo,
                                                  unsigned* __restrict__ cnt) {
    int task = blockIdx.x;
    const unsigned* h = hist + (size_t)task * NB1;
    __shared__ unsigned sblk[256];
    __shared__ unsigned sbin[64];
    __shared__ int sh_tb;
    __shared__ unsigned sh_rem;
    int t = threadIdx.x;
    unsigned s = 0;
    for (int i = 0; i < 64; ++i) s += h[t * 64 + i];
    sblk[t] = s;
    __syncthreads();
    if (t == 0) {
        unsigned rem = K_TOP; int tb = 0;
        for (int b = 255; b >= 0; --b) {
            if (sblk[b] < rem) rem -= sblk[b];
            else { tb = b; break; }
        }
        sh_tb = tb; sh_rem = rem;
    }
    __syncthreads();
    if (t < 64) sbin[t] = h[sh_tb * 64 + t];
    __syncthreads();
    if (t == 0) {
        unsigned rem = sh_rem; int pfx = sh_tb * 64;
        for (int b = 63; b >= 0; --b) {
            if (sbin[b] < rem) rem -= sbin[b];
            else { pfx = sh_tb * 64 + b; break; }
        }
        tinfo[task * 2]     = (unsigned)pfx;
        tinfo[task * 2 + 1] = rem;
        cnt[task] = 0u;
    }
}

// ---------------- pass 3: compact winners, LDS-staged, one global atomic/block ----
__global__ __launch_bounds__(1024) void kCompact(const float* __restrict__ lg,
                                                 int m, int lvl,
                                                 const unsigned* __restrict__ tinfo,
                                                 unsigned* __restrict__ cnt,
                                                 u64* __restrict__ compbuf) {
    int img  = blockIdx.y;
    int task = img * NLVL + lvl;
    unsigned pfx = tinfo[task * 2];
    __shared__ u64 stage[CAP];
    __shared__ unsigned lcnt, gbase;
    if (threadIdx.x == 0) lcnt = 0u;
    __syncthreads();
    int m4 = m >> 2;
    int chunk4 = (m4 + gridDim.x - 1) / (int)gridDim.x;
    int start4 = blockIdx.x * chunk4;
    int end4   = min(start4 + chunk4, m4);
    const float4* src = (const float4*)(lg + (size_t)img * m);
    for (int i = start4 + threadIdx.x; i < end4; i += 1024) {
        float4 v = src[i];
        int j = i * 4;
        unsigned k0 = key_of(v.x);
        unsigned k1 = key_of(v.y);
        unsigned k2 = key_of(v.z);
        unsigned k3 = key_of(v.w);
        if ((k0 >> L1SHIFT) >= pfx) {
            unsigned p = atomicAdd(&lcnt, 1u);
            if (p < CAP) stage[p] = ((u64)k0 << 32) | (unsigned)(~(unsigned)(j));
        }
        if ((k1 >> L1SHIFT) >= pfx) {
            unsigned p = atomicAdd(&lcnt, 1u);
            if (p < CAP) stage[p] = ((u64)k1 << 32) | (unsigned)(~(unsigned)(j + 1));
        }
        if ((k2 >> L1SHIFT) >= pfx) {
            unsigned p = atomicAdd(&lcnt, 1u);
            if (p < CAP) stage[p] = ((u64)k2 << 32) | (unsigned)(~(unsigned)(j + 2));
        }
        if ((k3 >> L1SHIFT) >= pfx) {
            unsigned p = atomicAdd(&lcnt, 1u);
            if (p < CAP) stage[p] = ((u64)k3 << 32) | (unsigned)(~(unsigned)(j + 3));
        }
    }
    __syncthreads();
    if (threadIdx.x == 0) gbase = atomicAdd(&cnt[task], lcnt);
    __syncthreads();
    unsigned total = min(lcnt, (unsigned)CAP);
    unsigned base  = gbase;
    for (unsigned p = threadIdx.x; p < total; p += 1024) {
        unsigned pos = base + p;
        if (pos < CAP) compbuf[(size_t)task * CAP + pos] = stage[p];
    }
}

// ---------------- pass 4: split-sort (sure/boundary), decode, valid-compact ----
__global__ __launch_bounds__(1024) void kSortSelect(
        Ptrs p,
        const unsigned* __restrict__ cnt,
        const unsigned* __restrict__ tinfo,
        const u64* __restrict__ compbuf,
        float* __restrict__ cscore,
        float4* __restrict__ cbox,
        float4* __restrict__ cobox,
        unsigned* __restrict__ cog,
        unsigned* __restrict__ vcnt) {
    int task = blockIdx.x;
    int img = task / NLVL, lvl = task % NLVL;
    int tid = threadIdx.x;
    __shared__ u64 sure[1024];
    __shared__ u64 bnd[2048];
    __shared__ unsigned cS, cB;
    if (tid == 0) { cS = 0u; cB = 0u; }
    sure[tid] = 0ULL;
    bnd[tid] = 0ULL; bnd[tid + 1024] = 0ULL;
    __syncthreads();
    int n = min((int)cnt[task], CAP);
    unsigned pfx = tinfo[task * 2];
    for (int i = tid; i < n; i += 1024) {
        u64 c = compbuf[(size_t)task * CAP + i];
        unsigned bin = (unsigned)(c >> (32 + L1SHIFT));
        if (bin > pfx) {
            unsigned q = atomicAdd(&cS, 1u);
            if (q < 1024) sure[q] = c;
        } else {
            unsigned q = atomicAdd(&cB, 1u);
            if (q < 2048) bnd[q] = c;
        }
    }
    __syncthreads();
    unsigned S = cS;
    unsigned B = cB;
    // unified descending bitonic: threads 0-511 sort sure[1024], 512-1023 bnd[0:1024]
    {
        u64* arr = (tid < 512) ? sure : bnd;
        int q = tid & 511;
        for (int k = 2; k <= 1024; k <<= 1) {
            for (int j = k >> 1; j > 0; j >>= 1) {
                int i = ((q & ~(j - 1)) << 1) | (q & (j - 1));
                int pp = i | j;
                u64 A = arr[i], Bv = arr[pp];
                bool up = ((i & k) == 0);
                if (up ? (A < Bv) : (A > Bv)) { arr[i] = Bv; arr[pp] = A; }
                __syncthreads();
            }
        }
    }
    if (B > 1024) {    // statistically never; full 2048 network re-sorts bnd
        for (int k = 2; k <= 2048; k <<= 1)
            for (int j = k >> 1; j > 0; j >>= 1) {
                int i = ((tid & ~(j - 1)) << 1) | (tid & (j - 1));
                int pp = i | j;
                u64 A = bnd[i], Bv = bnd[pp];
                bool up = ((i & k) == 0);
                if (up ? (A < Bv) : (A > Bv)) { bnd[i] = Bv; bnd[pp] = A; }
                __syncthreads();
            }
    }
    int r = tid;
    u64 c = 0ULL;
    if (r < K_TOP) c = (r < (int)S) ? sure[r] : ((r - (int)S < (int)B) ? bnd[r - (int)S] : 0ULL);
    __syncthreads();                 // all sure/bnd reads done (bnd reused for scan)

    const int   MS[5]     = {516096, 129024, 32256, 8064, 2016};
    const int   GW[5]     = {512, 256, 128, 64, 32};
    const float STRIDEF[5]= {4.f, 8.f, 16.f, 32.f, 64.f};
    const int   SIZEI[5]  = {32, 64, 128, 256, 512};
    float sm = NEGF, x0 = 0.f, y0 = 0.f, x1 = 0.f, y1 = 0.f;
    float b0 = 0.f, b1 = 0.f, b2 = 0.f, b3 = 0.f;
    bool valid = false;
    if (r < K_TOP) {
        int idx = (int)(~(unsigned)c);
        int m = MS[lvl];
        if ((unsigned)idx >= (unsigned)m) idx = 0;   // safety (never expected)
        const float* lg = p.lg[lvl];
        const float* dl = p.dl[lvl];
        float score = lg[(size_t)img * m + idx];
        int a   = idx % 3;
        int loc = idx / 3;
        int gw  = GW[lvl];
        int x = loc % gw, y = loc / gw;
        double ssz = (double)SIZEI[lvl];
        double arr = (a == 0) ? 0.5 : ((a == 1) ? 1.0 : 2.0);
        double wd = sqrt(ssz * ssz / arr);
        double hd = arr * wd;
        float sx = (float)x * STRIDEF[lvl];
        float sy = (float)y * STRIDEF[lvl];
        float a0 = sx + (float)(-wd * 0.5);
        float a1 = sy + (float)(-hd * 0.5);
        float a2 = sx + (float)( wd * 0.5);
        float a3 = sy + (float)( hd * 0.5);
        float aw = a2 - a0, ah = a3 - a1;
        float acx = a0 + 0.5f * aw, acy = a1 + 0.5f * ah;
        size_t db = ((size_t)img * m + idx) * 4;
        float dx = dl[db], dy = dl[db + 1], dwv = dl[db + 2], dhv = dl[db + 3];
        const float CL = 4.135166556742356f;   // log(1000/16)
        float pw = expf(fminf(dwv, CL)) * aw;
        float ph = expf(fminf(dhv, CL)) * ah;
        float pcx = dx * aw + acx;
        float pcy = dy * ah + acy;
        x0 = pcx - 0.5f * pw; y0 = pcy - 0.5f * ph;
        x1 = pcx + 0.5f * pw; y1 = pcy + 0.5f * ph;
        x0 = fminf(fmaxf(x0, 0.f), 2048.f);
        x1 = fminf(fmaxf(x1, 0.f), 2048.f);
        y0 = fminf(fmaxf(y0, 0.f), 1344.f);
        y1 = fminf(fmaxf(y1, 0.f), 1344.f);
        bool keep = ((x1 - x0) > 0.f) && ((y1 - y0) > 0.f);
        valid = keep;
        sm = score;
        float off = (float)lvl * 2049.0f;
        b0 = x0 + off; b1 = y0 + off; b2 = x1 + off; b3 = y1 + off;
    }
    // block prefix scan over valid flags (Hillis-Steele, ping-pong in bnd region)
    int* sc1 = (int*)bnd;
    int* sc2 = sc1 + 1024;
    sc1[tid] = valid ? 1 : 0;
    __syncthreads();
    int* sA = sc1; int* sB = sc2;
    for (int dd = 1; dd < 1024; dd <<= 1) {
        int v = sA[tid];
        if (tid >= dd) v += sA[tid - dd];
        sB[tid] = v;
        __syncthreads();
        int* t2 = sA; sA = sB; sB = t2;
    }
    int incl  = sA[tid];
    int total = sA[1023];
    int pos   = incl - (valid ? 1 : 0);
    if (valid) {
        int ci = img * NCAND + lvl * K_TOP + pos;
        cscore[ci] = sm;
        cbox[ci]   = make_float4(x0, y0, x1, y1);
        cobox[ci]  = make_float4(b0, b1, b2, b3);
        cog[ci]    = (unsigned)r;
    }
    if (tid == 0) vcnt[task] = (unsigned)total;
}

// ---------------- pass 5: fused merge + scan, fully LDS-resident ----------------
// Per image: rank-merge the 5 valid lists into LDS (mobS/midxS), then run the
// word-tiled greedy scan. Stop condition is i >= V (register); areas are
// recomputed from boxes ((z-x)*(w-y), bit-exact vs the old carea). No global
// traffic inside the scan loop.
__global__ __launch_bounds__(1024) void kMergeScan(
        const float* __restrict__ cscore,
        const float4* __restrict__ cbox,
        const float4* __restrict__ cobox,
        const unsigned* __restrict__ cog,
        const unsigned* __restrict__ vcnt,
        float* __restrict__ out) {
    int img = blockIdx.x;
    int tid = threadIdx.x;
    int lane = tid & 63;
    int wave = tid >> 6;
    __shared__ u64    comp[NCAND];      // 40000 B
    __shared__ float4 mobS[NPAD];       // 80896 B (padded to word multiple)
    __shared__ unsigned midxS[NCAND];   // 20000 B
    __shared__ u64    diagWS[64];
    __shared__ u64    partS[16];
    __shared__ float4 pboxAll[NPOST];
    __shared__ unsigned emS[NPOST];
    __shared__ int LSs[NLVL];
    const int imgb = img * NCAND;

    if (tid < NLVL) LSs[tid] = (int)vcnt[img * NLVL + tid];
    __syncthreads();
    int V = LSs[0] + LSs[1] + LSs[2] + LSs[3] + LSs[4];
    // build composites
    for (int g = tid; g < NCAND; g += 1024) {
        int lv = g / K_TOP, gl = g - lv * K_TOP;
        u64 c = 0ULL;
        if (gl < LSs[lv]) {
            unsigned og = (unsigned)(lv * K_TOP) + cog[imgb + g];
            c = ((u64)key_of(cscore[imgb + g]) << 32) | (unsigned)(~og);
        }
        comp[g] = c;
    }
    __syncthreads();
    // rank by binary search, scatter offset-boxes + source index into LDS
    for (int g = tid; g < NCAND; g += 1024) {
        int lv = g / K_TOP, gl = g - lv * K_TOP;
        if (gl < LSs[lv]) {
            u64 c = comp[g];
            int pos = gl;
            for (int lv2 = 0; lv2 < NLVL; ++lv2) {
                if (lv2 == lv) continue;
                int base = lv2 * K_TOP;
                int lo = 0, hi = LSs[lv2];
                while (lo < hi) {
                    int mid = (lo + hi) >> 1;
                    if (comp[base + mid] > c) lo = mid + 1; else hi = mid;
                }
                pos += lo;
            }
            mobS[pos]  = cobox[imgb + g];
            midxS[pos] = (unsigned)g;
        }
    }
    for (int pos = V + tid; pos < NPAD; pos += 1024)
        mobS[pos] = make_float4(0.f, 0.f, 0.f, 0.f);
    __syncthreads();

    // ---- word-tiled greedy scan ----
    int emitted = 0;
    bool done = (V == 0);
    for (int w = 0; w < NWORDS && !done; ++w) {
        int base = w * 64;
        if (base >= V) break;
        // parallel phase: suppression-by-emitted + own diag block
        float4 bc = mobS[base + lane];
        float  arc = (bc.z - bc.x) * (bc.w - bc.y);
        bool supp = false;
        for (int t = wave; t < emitted; t += 16) {
            float4 bp = pboxAll[t];
            float arp = (bp.z - bp.x) * (bp.w - bp.y);
            float ltx = fmaxf(bc.x, bp.x), lty = fmaxf(bc.y, bp.y);
            float rbx = fminf(bc.z, bp.z), rby = fminf(bc.w, bp.w);
            float wx = fmaxf(rbx - ltx, 0.f), wy = fmaxf(rby - lty, 0.f);
            float inter = wx * wy;
            float denom = (arc + arp) - inter + 1e-9f;
            supp |= (inter / denom) > 0.7f;
        }
        u64 sb = __ballot(supp);
        if (lane == 0) partS[wave] = sb;
#pragma unroll
        for (int rr = 0; rr < 4; ++rr) {
            int r = wave * 4 + rr;
            float4 bp = mobS[base + r];
            float arp = (bp.z - bp.x) * (bp.w - bp.y);
            float ltx = fmaxf(bc.x, bp.x), lty = fmaxf(bc.y, bp.y);
            float rbx = fminf(bc.z, bp.z), rby = fminf(bc.w, bp.w);
            float wx = fmaxf(rbx - ltx, 0.f), wy = fmaxf(rby - lty, 0.f);
            float inter = wx * wy;
            float denom = (arc + arp) - inter + 1e-9f;
            bool pred = (inter / denom) > 0.7f;
            u64 db = __ballot(pred);
            if (lane == 0) diagWS[r] = db;
        }
        __syncthreads();
        // serial emission within word (redundant on all threads, LDS only)
        u64 sm = partS[0];
#pragma unroll
        for (int q = 1; q < 16; ++q) sm |= partS[q];
        int rem = V - base;
        u64 vmask = (rem >= 64) ? ~0ULL : ((1ULL << rem) - 1ULL);
        u64 cur = (~sm) & vmask;
        while (cur) {
            int b = __builtin_ctzll(cur);
            int i = base + b;
            if (tid == 0) {
                emS[emitted]     = (unsigned)i;
                pboxAll[emitted] = mobS[i];
            }
            ++emitted;                                   // uniform
            if (emitted == NPOST) { done = true; break; }
            cur &= ~diagWS[b];                           // one dependent LDS read
            cur &= ~(1ULL << b);
        }
        __syncthreads();             // pboxAll/emS visible for next word
    }
    __syncthreads();
    // ---- parallel output gather ----
    for (int rr = tid; rr < NPOST; rr += 1024) {
        float* o = out + ((size_t)img * NPOST + rr) * 5;
        if (rr < emitted) {
            unsigned i = emS[rr];
            unsigned g = midxS[i];
            float4 cb = cbox[imgb + g];
            float sc = cscore[imgb + g];
            o[0] = cb.x; o[1] = cb.y; o[2] = cb.z; o[3] = cb.w; o[4] = sc;
        } else {
            o[0] = 0.f; o[1] = 0.f; o[2] = 0.f; o[3] = 0.f; o[4] = NEGF;
        }
    }
}

extern "C" void kernel_launch(void* const* d_in, const int* in_sizes, int n_in,
                              void* d_out, int out_size, void* d_ws, size_t ws_size,
                              hipStream_t stream) {
    const int MS[5] = {516096, 129024, 32256, 8064, 2016};
    Ptrs P;
    for (int l = 0; l < 5; ++l) {
        P.lg[l] = (const float*)d_in[2 * l];
        P.dl[l] = (const float*)d_in[2 * l + 1];
    }
    char* w = (char*)d_ws;
    size_t off = 0;
    auto alloc = [&](size_t bytes) -> void* {
        void* pp = (void*)(w + off);
        off = (off + bytes + 255) & ~(size_t)255;
        return pp;
    };
    unsigned* hist  = (unsigned*)alloc((size_t)NTASK * NB1 * 4);
    unsigned* tinfo = (unsigned*)alloc(NTASK * 2 * 4);
    unsigned* cnt   = (unsigned*)alloc(NTASK * 4);
    u64* compb      = (u64*)alloc((size_t)NTASK * CAP * 8);
    float*  cscore  = (float*)alloc((size_t)NTASK * K_TOP * 4);
    float4* cbox    = (float4*)alloc((size_t)NTASK * K_TOP * 16);
    float4* cobox   = (float4*)alloc((size_t)NTASK * K_TOP * 16);
    unsigned* cog   = (unsigned*)alloc((size_t)NTASK * K_TOP * 4);
    unsigned* vcnt  = (unsigned*)alloc(NTASK * 4);
    (void)in_sizes; (void)n_in; (void)out_size; (void)ws_size;

    size_t nhz = (size_t)NTASK * NB1;
    kZero<<<2048, 256, 0, stream>>>(hist, nhz);
    for (int l = 0; l < 5; ++l) {
        int m4 = MS[l] >> 2;
        int gx = (m4 + 8191) / 8192;       // ~32K elements per block
        dim3 g(gx, NIMG);
        kHist<<<g, 1024, 0, stream>>>(P.lg[l], MS[l], l, hist);
    }
    kSelectBin<<<NTASK, 256, 0, stream>>>(hist, tinfo, cnt);
    for (int l = 0; l < 5; ++l) {
        int m4 = MS[l] >> 2;
        int gx = (m4 + 4095) / 4096;       // ~16K elements per block
        dim3 g(gx, NIMG);
        kCompact<<<g, 1024, 0, stream>>>(P.lg[l], MS[l], l, tinfo, cnt, compb);
    }
    kSortSelect<<<NTASK, 1024, 0, stream>>>(P, cnt, tinfo, compb,
                                            cscore, cbox, cobox, cog, vcnt);
    kMergeScan<<<NIMG, 1024, 0, stream>>>(cscore, cbox, cobox, cog, vcnt,
                                          (float*)d_out);
}

// Round 13
// 158.316 us; speedup vs baseline: 4.5554x; 1.1071x over previous
//
#include <hip/hip_runtime.h>
#include <cstdint>
#include <cstddef>

#define NB1      16384      // 2^14 first-level radix bins
#define L1SHIFT  18         // key >> 18 -> 14-bit bin
#define CAP      4096       // compaction buffer per task
#define K_TOP    1000
#define NCAND    5000
#define NIMG     8
#define NLVL     5
#define NTASK    40
#define NPOST    300
#define NEGF     (-1e9f)
#define NWORDS   79         // ceil(5000/64)
#define NPAD     (NWORDS * 64)   // 5056, padded candidate count

typedef unsigned long long u64;

struct Ptrs {
    const float* lg[5];
    const float* dl[5];
};

__device__ __forceinline__ unsigned key_of(float f) {
    unsigned u = __float_as_uint(f);
    return (u & 0x80000000u) ? ~u : (u | 0x80000000u);
}

// ---------------- zero scratch ----------------
__global__ void kZero(unsigned* p, size_t n) {
    size_t i = (size_t)blockIdx.x * blockDim.x + threadIdx.x;
    size_t st = (size_t)gridDim.x * blockDim.x;
    for (; i < n; i += st) p[i] = 0u;
}

// ---------------- pass 1: all-level LDS-privatized histogram (1 dispatch) ----------------
// blockIdx.x partitioned over levels: {16,4,1,1,1} blocks -> 23 per image.
__global__ __launch_bounds__(1024) void kHistAll(Ptrs p, unsigned* __restrict__ hist) {
    int bx = blockIdx.x;
    int lvl = (bx < 16) ? 0 : (bx < 20) ? 1 : (bx < 21) ? 2 : (bx < 22) ? 3 : 4;
    int lb  = bx - ((lvl == 0) ? 0 : (lvl == 1) ? 16 : (lvl == 2) ? 20 : (lvl == 3) ? 21 : 22);
    int gx  = (lvl == 0) ? 16 : (lvl == 1) ? 4 : 1;
    int m   = (lvl == 0) ? 516096 : (lvl == 1) ? 129024 : (lvl == 2) ? 32256
              : (lvl == 3) ? 8064 : 2016;
    int img  = blockIdx.y;
    int task = img * NLVL + lvl;
    const float* lg = p.lg[lvl];
    __shared__ unsigned h[NB1];
    for (int i = threadIdx.x; i < NB1; i += 1024) h[i] = 0u;
    __syncthreads();
    int m4 = m >> 2;
    int chunk4 = (m4 + gx - 1) / gx;
    int start4 = lb * chunk4;
    int end4   = min(start4 + chunk4, m4);
    const float4* src = (const float4*)(lg + (size_t)img * m);
    for (int i = start4 + threadIdx.x; i < end4; i += 1024) {
        float4 v = src[i];
        atomicAdd(&h[key_of(v.x) >> L1SHIFT], 1u);
        atomicAdd(&h[key_of(v.y) >> L1SHIFT], 1u);
        atomicAdd(&h[key_of(v.z) >> L1SHIFT], 1u);
        atomicAdd(&h[key_of(v.w) >> L1SHIFT], 1u);
    }
    __syncthreads();
    unsigned* gh = hist + (size_t)task * NB1;
    for (int i = threadIdx.x; i < NB1; i += 1024) {
        unsigned c = h[i];
        if (c) atomicAdd(&gh[i], c);
    }
}

// ---------------- pass 2: find 14-bit prefix of the K-th largest ----------------
__global__ __launch_bounds__(256) void kSelectBin(const unsigned* __restrict__ hist,
                                                  unsigned* __restrict__ tinfo,
                                                  unsigned* __restrict__ cnt) {
    int task = blockIdx.x;
    const unsigned* h = hist + (size_t)task * NB1;
    __shared__ unsigned sblk[256];
    __shared__ unsigned sbin[64];
    __shared__ int sh_tb;
    __shared__ unsigned sh_rem;
    int t = threadIdx.x;
    unsigned s = 0;
    for (int i = 0; i < 64; ++i) s += h[t * 64 + i];
    sblk[t] = s;
    __syncthreads();
    if (t == 0) {
        unsigned rem = K_TOP; int tb = 0;
        for (int b = 255; b >= 0; --b) {
            if (sblk[b] < rem) rem -= sblk[b];
            else { tb = b; break; }
        }
        sh_tb = tb; sh_rem = rem;
    }
    __syncthreads();
    if (t < 64) sbin[t] = h[sh_tb * 64 + t];
    __syncthreads();
    if (t == 0) {
        unsigned rem = sh_rem; int pfx = sh_tb * 64;
        for (int b = 63; b >= 0; --b) {
            if (sbin[b] < rem) rem -= sbin[b];
            else { pfx = sh_tb * 64 + b; break; }
        }
        tinfo[task * 2]     = (unsigned)pfx;
        tinfo[task * 2 + 1] = rem;
        cnt[task] = 0u;
    }
}

// ---------------- pass 3: all-level compact (1 dispatch) ----------------
// blockIdx.x partitioned over levels: {32,8,2,1,1} -> 44 per image.
__global__ __launch_bounds__(1024) void kCompactAll(Ptrs p,
                                                    const unsigned* __restrict__ tinfo,
                                                    unsigned* __restrict__ cnt,
                                                    u64* __restrict__ compbuf) {
    int bx = blockIdx.x;
    int lvl = (bx < 32) ? 0 : (bx < 40) ? 1 : (bx < 42) ? 2 : (bx < 43) ? 3 : 4;
    int lb  = bx - ((lvl == 0) ? 0 : (lvl == 1) ? 32 : (lvl == 2) ? 40 : (lvl == 3) ? 42 : 43);
    int gx  = (lvl == 0) ? 32 : (lvl == 1) ? 8 : (lvl == 2) ? 2 : 1;
    int m   = (lvl == 0) ? 516096 : (lvl == 1) ? 129024 : (lvl == 2) ? 32256
              : (lvl == 3) ? 8064 : 2016;
    int img  = blockIdx.y;
    int task = img * NLVL + lvl;
    const float* lg = p.lg[lvl];
    unsigned pfx = tinfo[task * 2];
    __shared__ u64 stage[CAP];
    __shared__ unsigned lcnt, gbase;
    if (threadIdx.x == 0) lcnt = 0u;
    __syncthreads();
    int m4 = m >> 2;
    int chunk4 = (m4 + gx - 1) / gx;
    int start4 = lb * chunk4;
    int end4   = min(start4 + chunk4, m4);
    const float4* src = (const float4*)(lg + (size_t)img * m);
    for (int i = start4 + threadIdx.x; i < end4; i += 1024) {
        float4 v = src[i];
        int j = i * 4;
        unsigned k0 = key_of(v.x);
        unsigned k1 = key_of(v.y);
        unsigned k2 = key_of(v.z);
        unsigned k3 = key_of(v.w);
        if ((k0 >> L1SHIFT) >= pfx) {
            unsigned q = atomicAdd(&lcnt, 1u);
            if (q < CAP) stage[q] = ((u64)k0 << 32) | (unsigned)(~(unsigned)(j));
        }
        if ((k1 >> L1SHIFT) >= pfx) {
            unsigned q = atomicAdd(&lcnt, 1u);
            if (q < CAP) stage[q] = ((u64)k1 << 32) | (unsigned)(~(unsigned)(j + 1));
        }
        if ((k2 >> L1SHIFT) >= pfx) {
            unsigned q = atomicAdd(&lcnt, 1u);
            if (q < CAP) stage[q] = ((u64)k2 << 32) | (unsigned)(~(unsigned)(j + 2));
        }
        if ((k3 >> L1SHIFT) >= pfx) {
            unsigned q = atomicAdd(&lcnt, 1u);
            if (q < CAP) stage[q] = ((u64)k3 << 32) | (unsigned)(~(unsigned)(j + 3));
        }
    }
    __syncthreads();
    if (threadIdx.x == 0) gbase = atomicAdd(&cnt[task], lcnt);
    __syncthreads();
    unsigned total = min(lcnt, (unsigned)CAP);
    unsigned base  = gbase;
    for (unsigned q = threadIdx.x; q < total; q += 1024) {
        unsigned pos = base + q;
        if (pos < CAP) compbuf[(size_t)task * CAP + pos] = stage[q];
    }
}

// ---------------- pass 4: split-sort (sure/boundary), decode, valid-compact ----
__global__ __launch_bounds__(1024) void kSortSelect(
        Ptrs p,
        const unsigned* __restrict__ cnt,
        const unsigned* __restrict__ tinfo,
        const u64* __restrict__ compbuf,
        float* __restrict__ cscore,
        float4* __restrict__ cbox,
        float4* __restrict__ cobox,
        unsigned* __restrict__ cog,
        unsigned* __restrict__ vcnt) {
    int task = blockIdx.x;
    int img = task / NLVL, lvl = task % NLVL;
    int tid = threadIdx.x;
    __shared__ u64 sure[1024];
    __shared__ u64 bnd[2048];
    __shared__ unsigned cS, cB;
    if (tid == 0) { cS = 0u; cB = 0u; }
    sure[tid] = 0ULL;
    bnd[tid] = 0ULL; bnd[tid + 1024] = 0ULL;
    __syncthreads();
    int n = min((int)cnt[task], CAP);
    unsigned pfx = tinfo[task * 2];
    for (int i = tid; i < n; i += 1024) {
        u64 c = compbuf[(size_t)task * CAP + i];
        unsigned bin = (unsigned)(c >> (32 + L1SHIFT));
        if (bin > pfx) {
            unsigned q = atomicAdd(&cS, 1u);
            if (q < 1024) sure[q] = c;
        } else {
            unsigned q = atomicAdd(&cB, 1u);
            if (q < 2048) bnd[q] = c;
        }
    }
    __syncthreads();
    unsigned S = cS;
    unsigned B = cB;
    // unified descending bitonic: threads 0-511 sort sure[1024], 512-1023 bnd[0:1024]
    {
        u64* arr = (tid < 512) ? sure : bnd;
        int q = tid & 511;
        for (int k = 2; k <= 1024; k <<= 1) {
            for (int j = k >> 1; j > 0; j >>= 1) {
                int i = ((q & ~(j - 1)) << 1) | (q & (j - 1));
                int pp = i | j;
                u64 A = arr[i], Bv = arr[pp];
                bool up = ((i & k) == 0);
                if (up ? (A < Bv) : (A > Bv)) { arr[i] = Bv; arr[pp] = A; }
                __syncthreads();
            }
        }
    }
    if (B > 1024) {    // statistically never; full 2048 network re-sorts bnd
        for (int k = 2; k <= 2048; k <<= 1)
            for (int j = k >> 1; j > 0; j >>= 1) {
                int i = ((tid & ~(j - 1)) << 1) | (tid & (j - 1));
                int pp = i | j;
                u64 A = bnd[i], Bv = bnd[pp];
                bool up = ((i & k) == 0);
                if (up ? (A < Bv) : (A > Bv)) { bnd[i] = Bv; bnd[pp] = A; }
                __syncthreads();
            }
    }
    int r = tid;
    u64 c = 0ULL;
    if (r < K_TOP) c = (r < (int)S) ? sure[r] : ((r - (int)S < (int)B) ? bnd[r - (int)S] : 0ULL);
    __syncthreads();                 // all sure/bnd reads done (bnd reused for scan)

    const int   MS[5]     = {516096, 129024, 32256, 8064, 2016};
    const int   GW[5]     = {512, 256, 128, 64, 32};
    const float STRIDEF[5]= {4.f, 8.f, 16.f, 32.f, 64.f};
    const int   SIZEI[5]  = {32, 64, 128, 256, 512};
    float sm = NEGF, x0 = 0.f, y0 = 0.f, x1 = 0.f, y1 = 0.f;
    float b0 = 0.f, b1 = 0.f, b2 = 0.f, b3 = 0.f;
    bool valid = false;
    if (r < K_TOP) {
        int idx = (int)(~(unsigned)c);
        int m = MS[lvl];
        if ((unsigned)idx >= (unsigned)m) idx = 0;   // safety (never expected)
        const float* lg = p.lg[lvl];
        const float* dl = p.dl[lvl];
        float score = lg[(size_t)img * m + idx];
        int a   = idx % 3;
        int loc = idx / 3;
        int gw  = GW[lvl];
        int x = loc % gw, y = loc / gw;
        double ssz = (double)SIZEI[lvl];
        double arr = (a == 0) ? 0.5 : ((a == 1) ? 1.0 : 2.0);
        double wd = sqrt(ssz * ssz / arr);
        double hd = arr * wd;
        float sx = (float)x * STRIDEF[lvl];
        float sy = (float)y * STRIDEF[lvl];
        float a0 = sx + (float)(-wd * 0.5);
        float a1 = sy + (float)(-hd * 0.5);
        float a2 = sx + (float)( wd * 0.5);
        float a3 = sy + (float)( hd * 0.5);
        float aw = a2 - a0, ah = a3 - a1;
        float acx = a0 + 0.5f * aw, acy = a1 + 0.5f * ah;
        size_t db = ((size_t)img * m + idx) * 4;
        float dx = dl[db], dy = dl[db + 1], dwv = dl[db + 2], dhv = dl[db + 3];
        const float CL = 4.135166556742356f;   // log(1000/16)
        float pw = expf(fminf(dwv, CL)) * aw;
        float ph = expf(fminf(dhv, CL)) * ah;
        float pcx = dx * aw + acx;
        float pcy = dy * ah + acy;
        x0 = pcx - 0.5f * pw; y0 = pcy - 0.5f * ph;
        x1 = pcx + 0.5f * pw; y1 = pcy + 0.5f * ph;
        x0 = fminf(fmaxf(x0, 0.f), 2048.f);
        x1 = fminf(fmaxf(x1, 0.f), 2048.f);
        y0 = fminf(fmaxf(y0, 0.f), 1344.f);
        y1 = fminf(fmaxf(y1, 0.f), 1344.f);
        bool keep = ((x1 - x0) > 0.f) && ((y1 - y0) > 0.f);
        valid = keep;
        sm = score;
        float off = (float)lvl * 2049.0f;
        b0 = x0 + off; b1 = y0 + off; b2 = x1 + off; b3 = y1 + off;
    }
    // block prefix scan over valid flags (Hillis-Steele, ping-pong in bnd region)
    int* sc1 = (int*)bnd;
    int* sc2 = sc1 + 1024;
    sc1[tid] = valid ? 1 : 0;
    __syncthreads();
    int* sA = sc1; int* sB = sc2;
    for (int dd = 1; dd < 1024; dd <<= 1) {
        int v = sA[tid];
        if (tid >= dd) v += sA[tid - dd];
        sB[tid] = v;
        __syncthreads();
        int* t2 = sA; sA = sB; sB = t2;
    }
    int incl  = sA[tid];
    int total = sA[1023];
    int pos   = incl - (valid ? 1 : 0);
    if (valid) {
        int ci = img * NCAND + lvl * K_TOP + pos;
        cscore[ci] = sm;
        cbox[ci]   = make_float4(x0, y0, x1, y1);
        cobox[ci]  = make_float4(b0, b1, b2, b3);
        cog[ci]    = (unsigned)r;
    }
    if (tid == 0) vcnt[task] = (unsigned)total;
}

// ---------------- pass 5: fused merge + scan, fully LDS-resident ----------------
__global__ __launch_bounds__(1024) void kMergeScan(
        const float* __restrict__ cscore,
        const float4* __restrict__ cbox,
        const float4* __restrict__ cobox,
        const unsigned* __restrict__ cog,
        const unsigned* __restrict__ vcnt,
        float* __restrict__ out) {
    int img = blockIdx.x;
    int tid = threadIdx.x;
    int lane = tid & 63;
    int wave = tid >> 6;
    __shared__ u64    comp[NCAND];      // 40000 B
    __shared__ float4 mobS[NPAD];       // 80896 B
    __shared__ unsigned midxS[NCAND];   // 20000 B
    __shared__ u64    diagWS[64];
    __shared__ u64    partS[16];
    __shared__ float4 pboxAll[NPOST];
    __shared__ unsigned emS[NPOST];
    __shared__ int LSs[NLVL];
    const int imgb = img * NCAND;

    if (tid < NLVL) LSs[tid] = (int)vcnt[img * NLVL + tid];
    __syncthreads();
    int V = LSs[0] + LSs[1] + LSs[2] + LSs[3] + LSs[4];
    for (int g = tid; g < NCAND; g += 1024) {
        int lv = g / K_TOP, gl = g - lv * K_TOP;
        u64 c = 0ULL;
        if (gl < LSs[lv]) {
            unsigned og = (unsigned)(lv * K_TOP) + cog[imgb + g];
            c = ((u64)key_of(cscore[imgb + g]) << 32) | (unsigned)(~og);
        }
        comp[g] = c;
    }
    __syncthreads();
    // rank by 4-way interleaved binary search, scatter into LDS
    for (int g = tid; g < NCAND; g += 1024) {
        int lv = g / K_TOP, gl = g - lv * K_TOP;
        if (gl < LSs[lv]) {
            u64 c = comp[g];
            int o0 = (lv == 0) ? 1 : 0;
            int o1 = (lv <= 1) ? 2 : 1;
            int o2 = (lv <= 2) ? 3 : 2;
            int o3 = (lv <= 3) ? 4 : 3;
            int B0 = o0 * K_TOP, B1 = o1 * K_TOP, B2 = o2 * K_TOP, B3 = o3 * K_TOP;
            int l0 = 0, h0 = LSs[o0];
            int l1 = 0, h1 = LSs[o1];
            int l2 = 0, h2 = LSs[o2];
            int l3 = 0, h3 = LSs[o3];
#pragma unroll
            for (int step = 0; step < 11; ++step) {
                if (l0 < h0) { int m0 = (l0 + h0) >> 1; u64 v0 = comp[B0 + m0]; if (v0 > c) l0 = m0 + 1; else h0 = m0; }
                if (l1 < h1) { int m1 = (l1 + h1) >> 1; u64 v1 = comp[B1 + m1]; if (v1 > c) l1 = m1 + 1; else h1 = m1; }
                if (l2 < h2) { int m2 = (l2 + h2) >> 1; u64 v2 = comp[B2 + m2]; if (v2 > c) l2 = m2 + 1; else h2 = m2; }
                if (l3 < h3) { int m3 = (l3 + h3) >> 1; u64 v3 = comp[B3 + m3]; if (v3 > c) l3 = m3 + 1; else h3 = m3; }
            }
            int pos = gl + l0 + l1 + l2 + l3;
            mobS[pos]  = cobox[imgb + g];
            midxS[pos] = (unsigned)g;
        }
    }
    for (int pos = V + tid; pos < NPAD; pos += 1024)
        mobS[pos] = make_float4(0.f, 0.f, 0.f, 0.f);
    __syncthreads();

    // ---- word-tiled greedy scan with batch-4 speculative pops ----
    int emitted = 0;
    bool done = (V == 0);
    for (int w = 0; w < NWORDS && !done; ++w) {
        int base = w * 64;
        if (base >= V) break;
        float4 bc = mobS[base + lane];
        float  arc = (bc.z - bc.x) * (bc.w - bc.y);
        bool supp = false;
        for (int t = wave; t < emitted; t += 16) {
            float4 bp = pboxAll[t];
            float arp = (bp.z - bp.x) * (bp.w - bp.y);
            float ltx = fmaxf(bc.x, bp.x), lty = fmaxf(bc.y, bp.y);
            float rbx = fminf(bc.z, bp.z), rby = fminf(bc.w, bp.w);
            float wx = fmaxf(rbx - ltx, 0.f), wy = fmaxf(rby - lty, 0.f);
            float inter = wx * wy;
            float denom = (arc + arp) - inter + 1e-9f;
            supp |= (inter / denom) > 0.7f;
        }
        u64 sb = __ballot(supp);
        if (lane == 0) partS[wave] = sb;
#pragma unroll
        for (int rr = 0; rr < 4; ++rr) {
            int r = wave * 4 + rr;
            float4 bp = mobS[base + r];
            float arp = (bp.z - bp.x) * (bp.w - bp.y);
            float ltx = fmaxf(bc.x, bp.x), lty = fmaxf(bc.y, bp.y);
            float rbx = fminf(bc.z, bp.z), rby = fminf(bc.w, bp.w);
            float wx = fmaxf(rbx - ltx, 0.f), wy = fmaxf(rby - lty, 0.f);
            float inter = wx * wy;
            float denom = (arc + arp) - inter + 1e-9f;
            bool pred = (inter / denom) > 0.7f;
            u64 db = __ballot(pred);
            if (lane == 0) diagWS[r] = db;
        }
        __syncthreads();
        u64 sm = partS[0];
#pragma unroll
        for (int q = 1; q < 16; ++q) sm |= partS[q];
        int rem = V - base;
        u64 vmask = (rem >= 64) ? ~0ULL : ((1ULL << rem) - 1ULL);
        u64 cur = (~sm) & vmask;
        while (cur) {
            // gather next up-to-4 set bits; load their diag rows in one latency
            u64 tmp = cur;
            int b0 = __builtin_ctzll(tmp); tmp &= tmp - 1;
            int b1 = tmp ? __builtin_ctzll(tmp) : 64; if (tmp) tmp &= tmp - 1;
            int b2 = tmp ? __builtin_ctzll(tmp) : 64; if (tmp) tmp &= tmp - 1;
            int b3 = tmp ? __builtin_ctzll(tmp) : 64;
            u64 r0 = diagWS[b0];
            u64 r1 = (b1 < 64) ? diagWS[b1] : 0ULL;
            u64 r2 = (b2 < 64) ? diagWS[b2] : 0ULL;
            u64 r3 = (b3 < 64) ? diagWS[b3] : 0ULL;
            // commit with exact greedy fixup (register-only)
            u64 sup = r0;
            u64 embits = 1ULL << b0;
            if (tid == 0) { emS[emitted] = (unsigned)(base + b0); pboxAll[emitted] = mobS[base + b0]; }
            ++emitted;
            if (emitted == NPOST) { done = true; break; }
            if (b1 < 64 && !((sup >> b1) & 1ULL)) {
                if (tid == 0) { emS[emitted] = (unsigned)(base + b1); pboxAll[emitted] = mobS[base + b1]; }
                ++emitted; embits |= 1ULL << b1; sup |= r1;
                if (emitted == NPOST) { done = true; break; }
            }
            if (b2 < 64 && !((sup >> b2) & 1ULL)) {
                if (tid == 0) { emS[emitted] = (unsigned)(base + b2); pboxAll[emitted] = mobS[base + b2]; }
                ++emitted; embits |= 1ULL << b2; sup |= r2;
                if (emitted == NPOST) { done = true; break; }
            }
            if (b3 < 64 && !((sup >> b3) & 1ULL)) {
                if (tid == 0) { emS[emitted] = (unsigned)(base + b3); pboxAll[emitted] = mobS[base + b3]; }
                ++emitted; embits |= 1ULL << b3; sup |= r3;
                if (emitted == NPOST) { done = true; break; }
            }
            // clear all examined-and-resolved bits: emitted ones + everything
            // suppressed by the emitted set (incl. examined-but-suppressed bits)
            cur &= ~(sup | embits);
            // bits b1..b3 that were skipped because suppressed are inside sup. bits
            // beyond b3 suppressed by sup are also cleared (correct: they'd be
            // skipped by the serial scan too).
        }
        __syncthreads();             // pboxAll/emS visible for next word
    }
    __syncthreads();
    // ---- parallel output gather ----
    for (int rr = tid; rr < NPOST; rr += 1024) {
        float* o = out + ((size_t)img * NPOST + rr) * 5;
        if (rr < emitted) {
            unsigned i = emS[rr];
            unsigned g = midxS[i];
            float4 cb = cbox[imgb + g];
            float sc = cscore[imgb + g];
            o[0] = cb.x; o[1] = cb.y; o[2] = cb.z; o[3] = cb.w; o[4] = sc;
        } else {
            o[0] = 0.f; o[1] = 0.f; o[2] = 0.f; o[3] = 0.f; o[4] = NEGF;
        }
    }
}

extern "C" void kernel_launch(void* const* d_in, const int* in_sizes, int n_in,
                              void* d_out, int out_size, void* d_ws, size_t ws_size,
                              hipStream_t stream) {
    Ptrs P;
    for (int l = 0; l < 5; ++l) {
        P.lg[l] = (const float*)d_in[2 * l];
        P.dl[l] = (const float*)d_in[2 * l + 1];
    }
    char* w = (char*)d_ws;
    size_t off = 0;
    auto alloc = [&](size_t bytes) -> void* {
        void* pp = (void*)(w + off);
        off = (off + bytes + 255) & ~(size_t)255;
        return pp;
    };
    unsigned* hist  = (unsigned*)alloc((size_t)NTASK * NB1 * 4);
    unsigned* tinfo = (unsigned*)alloc(NTASK * 2 * 4);
    unsigned* cnt   = (unsigned*)alloc(NTASK * 4);
    u64* compb      = (u64*)alloc((size_t)NTASK * CAP * 8);
    float*  cscore  = (float*)alloc((size_t)NTASK * K_TOP * 4);
    float4* cbox    = (float4*)alloc((size_t)NTASK * K_TOP * 16);
    float4* cobox   = (float4*)alloc((size_t)NTASK * K_TOP * 16);
    unsigned* cog   = (unsigned*)alloc((size_t)NTASK * K_TOP * 4);
    unsigned* vcnt  = (unsigned*)alloc(NTASK * 4);
    (void)in_sizes; (void)n_in; (void)out_size; (void)ws_size;

    size_t nhz = (size_t)NTASK * NB1;
    kZero<<<2048, 256, 0, stream>>>(hist, nhz);
    kHistAll<<<dim3(23, NIMG), 1024, 0, stream>>>(P, hist);
    kSelectBin<<<NTASK, 256, 0, stream>>>(hist, tinfo, cnt);
    kCompactAll<<<dim3(44, NIMG), 1024, 0, stream>>>(P, tinfo, cnt, compb);
    kSortSelect<<<NTASK, 1024, 0, stream>>>(P, cnt, tinfo, compb,
                                            cscore, cbox, cobox, cog, vcnt);
    kMergeScan<<<NIMG, 1024, 0, stream>>>(cscore, cbox, cobox, cog, vcnt,
                                          (float*)d_out);
}

// Round 14
// 134.564 us; speedup vs baseline: 5.3595x; 1.1765x over previous
//
#include <hip/hip_runtime.h>
#include <cstdint>
#include <cstddef>

#define NB1      16384      // 2^14 first-level radix bins
#define L1SHIFT  18         // key >> 18 -> 14-bit bin
#define CAP      4096       // compaction buffer per task
#define K_TOP    1000
#define NCAND    5000
#define NIMG     8
#define NLVL     5
#define NTASK    40
#define NPOST    300
#define NEGF     (-1e9f)
#define NWORDS   79         // ceil(5000/64)
#define NPAD     (NWORDS * 64)   // 5056, padded candidate count

typedef unsigned long long u64;

struct Ptrs {
    const float* lg[5];
    const float* dl[5];
};

__device__ __forceinline__ unsigned key_of(float f) {
    unsigned u = __float_as_uint(f);
    return (u & 0x80000000u) ? ~u : (u | 0x80000000u);
}

// ---------------- zero scratch ----------------
__global__ void kZero(unsigned* p, size_t n) {
    size_t i = (size_t)blockIdx.x * blockDim.x + threadIdx.x;
    size_t st = (size_t)gridDim.x * blockDim.x;
    for (; i < n; i += st) p[i] = 0u;
}

// ---------------- pass 1: all-level LDS-privatized histogram (1 dispatch) ----------------
__global__ __launch_bounds__(1024) void kHistAll(Ptrs p, unsigned* __restrict__ hist) {
    int bx = blockIdx.x;
    int lvl = (bx < 16) ? 0 : (bx < 20) ? 1 : (bx < 21) ? 2 : (bx < 22) ? 3 : 4;
    int lb  = bx - ((lvl == 0) ? 0 : (lvl == 1) ? 16 : (lvl == 2) ? 20 : (lvl == 3) ? 21 : 22);
    int gx  = (lvl == 0) ? 16 : (lvl == 1) ? 4 : 1;
    int m   = (lvl == 0) ? 516096 : (lvl == 1) ? 129024 : (lvl == 2) ? 32256
              : (lvl == 3) ? 8064 : 2016;
    int img  = blockIdx.y;
    int task = img * NLVL + lvl;
    const float* lg = p.lg[lvl];
    __shared__ unsigned h[NB1];
    for (int i = threadIdx.x; i < NB1; i += 1024) h[i] = 0u;
    __syncthreads();
    int m4 = m >> 2;
    int chunk4 = (m4 + gx - 1) / gx;
    int start4 = lb * chunk4;
    int end4   = min(start4 + chunk4, m4);
    const float4* src = (const float4*)(lg + (size_t)img * m);
    for (int i = start4 + threadIdx.x; i < end4; i += 1024) {
        float4 v = src[i];
        atomicAdd(&h[key_of(v.x) >> L1SHIFT], 1u);
        atomicAdd(&h[key_of(v.y) >> L1SHIFT], 1u);
        atomicAdd(&h[key_of(v.z) >> L1SHIFT], 1u);
        atomicAdd(&h[key_of(v.w) >> L1SHIFT], 1u);
    }
    __syncthreads();
    unsigned* gh = hist + (size_t)task * NB1;
    for (int i = threadIdx.x; i < NB1; i += 1024) {
        unsigned c = h[i];
        if (c) atomicAdd(&gh[i], c);
    }
}

// ---------------- pass 2: find 14-bit prefix of the K-th largest ----------------
__global__ __launch_bounds__(256) void kSelectBin(const unsigned* __restrict__ hist,
                                                  unsigned* __restrict__ tinfo,
                                                  unsigned* __restrict__ cnt) {
    int task = blockIdx.x;
    const unsigned* h = hist + (size_t)task * NB1;
    __shared__ unsigned sblk[256];
    __shared__ unsigned sbin[64];
    __shared__ int sh_tb;
    __shared__ unsigned sh_rem;
    int t = threadIdx.x;
    unsigned s = 0;
    for (int i = 0; i < 64; ++i) s += h[t * 64 + i];
    sblk[t] = s;
    __syncthreads();
    if (t == 0) {
        unsigned rem = K_TOP; int tb = 0;
        for (int b = 255; b >= 0; --b) {
            if (sblk[b] < rem) rem -= sblk[b];
            else { tb = b; break; }
        }
        sh_tb = tb; sh_rem = rem;
    }
    __syncthreads();
    if (t < 64) sbin[t] = h[sh_tb * 64 + t];
    __syncthreads();
    if (t == 0) {
        unsigned rem = sh_rem; int pfx = sh_tb * 64;
        for (int b = 63; b >= 0; --b) {
            if (sbin[b] < rem) rem -= sbin[b];
            else { pfx = sh_tb * 64 + b; break; }
        }
        tinfo[task * 2]     = (unsigned)pfx;
        tinfo[task * 2 + 1] = rem;
        cnt[task] = 0u;
    }
}

// ---------------- pass 3: all-level compact (1 dispatch) ----------------
__global__ __launch_bounds__(1024) void kCompactAll(Ptrs p,
                                                    const unsigned* __restrict__ tinfo,
                                                    unsigned* __restrict__ cnt,
                                                    u64* __restrict__ compbuf) {
    int bx = blockIdx.x;
    int lvl = (bx < 32) ? 0 : (bx < 40) ? 1 : (bx < 42) ? 2 : (bx < 43) ? 3 : 4;
    int lb  = bx - ((lvl == 0) ? 0 : (lvl == 1) ? 32 : (lvl == 2) ? 40 : (lvl == 3) ? 42 : 43);
    int gx  = (lvl == 0) ? 32 : (lvl == 1) ? 8 : (lvl == 2) ? 2 : 1;
    int m   = (lvl == 0) ? 516096 : (lvl == 1) ? 129024 : (lvl == 2) ? 32256
              : (lvl == 3) ? 8064 : 2016;
    int img  = blockIdx.y;
    int task = img * NLVL + lvl;
    const float* lg = p.lg[lvl];
    unsigned pfx = tinfo[task * 2];
    __shared__ u64 stage[CAP];
    __shared__ unsigned lcnt, gbase;
    if (threadIdx.x == 0) lcnt = 0u;
    __syncthreads();
    int m4 = m >> 2;
    int chunk4 = (m4 + gx - 1) / gx;
    int start4 = lb * chunk4;
    int end4   = min(start4 + chunk4, m4);
    const float4* src = (const float4*)(lg + (size_t)img * m);
    for (int i = start4 + threadIdx.x; i < end4; i += 1024) {
        float4 v = src[i];
        int j = i * 4;
        unsigned k0 = key_of(v.x);
        unsigned k1 = key_of(v.y);
        unsigned k2 = key_of(v.z);
        unsigned k3 = key_of(v.w);
        if ((k0 >> L1SHIFT) >= pfx) {
            unsigned q = atomicAdd(&lcnt, 1u);
            if (q < CAP) stage[q] = ((u64)k0 << 32) | (unsigned)(~(unsigned)(j));
        }
        if ((k1 >> L1SHIFT) >= pfx) {
            unsigned q = atomicAdd(&lcnt, 1u);
            if (q < CAP) stage[q] = ((u64)k1 << 32) | (unsigned)(~(unsigned)(j + 1));
        }
        if ((k2 >> L1SHIFT) >= pfx) {
            unsigned q = atomicAdd(&lcnt, 1u);
            if (q < CAP) stage[q] = ((u64)k2 << 32) | (unsigned)(~(unsigned)(j + 2));
        }
        if ((k3 >> L1SHIFT) >= pfx) {
            unsigned q = atomicAdd(&lcnt, 1u);
            if (q < CAP) stage[q] = ((u64)k3 << 32) | (unsigned)(~(unsigned)(j + 3));
        }
    }
    __syncthreads();
    if (threadIdx.x == 0) gbase = atomicAdd(&cnt[task], lcnt);
    __syncthreads();
    unsigned total = min(lcnt, (unsigned)CAP);
    unsigned base  = gbase;
    for (unsigned q = threadIdx.x; q < total; q += 1024) {
        unsigned pos = base + q;
        if (pos < CAP) compbuf[(size_t)task * CAP + pos] = stage[q];
    }
}

// ---------------- pass 4: split-sort (sure/boundary), decode, valid-compact ----
__global__ __launch_bounds__(1024) void kSortSelect(
        Ptrs p,
        const unsigned* __restrict__ cnt,
        const unsigned* __restrict__ tinfo,
        const u64* __restrict__ compbuf,
        float* __restrict__ cscore,
        float4* __restrict__ cbox,
        float4* __restrict__ cobox,
        unsigned* __restrict__ cog,
        unsigned* __restrict__ vcnt) {
    int task = blockIdx.x;
    int img = task / NLVL, lvl = task % NLVL;
    int tid = threadIdx.x;
    __shared__ u64 sure[1024];
    __shared__ u64 bnd[2048];
    __shared__ unsigned cS, cB;
    if (tid == 0) { cS = 0u; cB = 0u; }
    sure[tid] = 0ULL;
    bnd[tid] = 0ULL; bnd[tid + 1024] = 0ULL;
    __syncthreads();
    int n = min((int)cnt[task], CAP);
    unsigned pfx = tinfo[task * 2];
    for (int i = tid; i < n; i += 1024) {
        u64 c = compbuf[(size_t)task * CAP + i];
        unsigned bin = (unsigned)(c >> (32 + L1SHIFT));
        if (bin > pfx) {
            unsigned q = atomicAdd(&cS, 1u);
            if (q < 1024) sure[q] = c;
        } else {
            unsigned q = atomicAdd(&cB, 1u);
            if (q < 2048) bnd[q] = c;
        }
    }
    __syncthreads();
    unsigned S = cS;
    unsigned B = cB;
    {
        u64* arr = (tid < 512) ? sure : bnd;
        int q = tid & 511;
        for (int k = 2; k <= 1024; k <<= 1) {
            for (int j = k >> 1; j > 0; j >>= 1) {
                int i = ((q & ~(j - 1)) << 1) | (q & (j - 1));
                int pp = i | j;
                u64 A = arr[i], Bv = arr[pp];
                bool up = ((i & k) == 0);
                if (up ? (A < Bv) : (A > Bv)) { arr[i] = Bv; arr[pp] = A; }
                __syncthreads();
            }
        }
    }
    if (B > 1024) {    // statistically never; full 2048 network re-sorts bnd
        for (int k = 2; k <= 2048; k <<= 1)
            for (int j = k >> 1; j > 0; j >>= 1) {
                int i = ((tid & ~(j - 1)) << 1) | (tid & (j - 1));
                int pp = i | j;
                u64 A = bnd[i], Bv = bnd[pp];
                bool up = ((i & k) == 0);
                if (up ? (A < Bv) : (A > Bv)) { bnd[i] = Bv; bnd[pp] = A; }
                __syncthreads();
            }
    }
    int r = tid;
    u64 c = 0ULL;
    if (r < K_TOP) c = (r < (int)S) ? sure[r] : ((r - (int)S < (int)B) ? bnd[r - (int)S] : 0ULL);
    __syncthreads();                 // all sure/bnd reads done (bnd reused for scan)

    const int   MS[5]     = {516096, 129024, 32256, 8064, 2016};
    const int   GW[5]     = {512, 256, 128, 64, 32};
    const float STRIDEF[5]= {4.f, 8.f, 16.f, 32.f, 64.f};
    const int   SIZEI[5]  = {32, 64, 128, 256, 512};
    float sm = NEGF, x0 = 0.f, y0 = 0.f, x1 = 0.f, y1 = 0.f;
    float b0 = 0.f, b1 = 0.f, b2 = 0.f, b3 = 0.f;
    bool valid = false;
    if (r < K_TOP) {
        int idx = (int)(~(unsigned)c);
        int m = MS[lvl];
        if ((unsigned)idx >= (unsigned)m) idx = 0;   // safety (never expected)
        const float* lg = p.lg[lvl];
        const float* dl = p.dl[lvl];
        float score = lg[(size_t)img * m + idx];
        int a   = idx % 3;
        int loc = idx / 3;
        int gw  = GW[lvl];
        int x = loc % gw, y = loc / gw;
        double ssz = (double)SIZEI[lvl];
        double arr = (a == 0) ? 0.5 : ((a == 1) ? 1.0 : 2.0);
        double wd = sqrt(ssz * ssz / arr);
        double hd = arr * wd;
        float sx = (float)x * STRIDEF[lvl];
        float sy = (float)y * STRIDEF[lvl];
        float a0 = sx + (float)(-wd * 0.5);
        float a1 = sy + (float)(-hd * 0.5);
        float a2 = sx + (float)( wd * 0.5);
        float a3 = sy + (float)( hd * 0.5);
        float aw = a2 - a0, ah = a3 - a1;
        float acx = a0 + 0.5f * aw, acy = a1 + 0.5f * ah;
        size_t db = ((size_t)img * m + idx) * 4;
        float dx = dl[db], dy = dl[db + 1], dwv = dl[db + 2], dhv = dl[db + 3];
        const float CL = 4.135166556742356f;   // log(1000/16)
        float pw = expf(fminf(dwv, CL)) * aw;
        float ph = expf(fminf(dhv, CL)) * ah;
        float pcx = dx * aw + acx;
        float pcy = dy * ah + acy;
        x0 = pcx - 0.5f * pw; y0 = pcy - 0.5f * ph;
        x1 = pcx + 0.5f * pw; y1 = pcy + 0.5f * ph;
        x0 = fminf(fmaxf(x0, 0.f), 2048.f);
        x1 = fminf(fmaxf(x1, 0.f), 2048.f);
        y0 = fminf(fmaxf(y0, 0.f), 1344.f);
        y1 = fminf(fmaxf(y1, 0.f), 1344.f);
        bool keep = ((x1 - x0) > 0.f) && ((y1 - y0) > 0.f);
        valid = keep;
        sm = score;
        float off = (float)lvl * 2049.0f;
        b0 = x0 + off; b1 = y0 + off; b2 = x1 + off; b3 = y1 + off;
    }
    // block prefix scan over valid flags (Hillis-Steele, ping-pong in bnd region)
    int* sc1 = (int*)bnd;
    int* sc2 = sc1 + 1024;
    sc1[tid] = valid ? 1 : 0;
    __syncthreads();
    int* sA = sc1; int* sB = sc2;
    for (int dd = 1; dd < 1024; dd <<= 1) {
        int v = sA[tid];
        if (tid >= dd) v += sA[tid - dd];
        sB[tid] = v;
        __syncthreads();
        int* t2 = sA; sA = sB; sB = t2;
    }
    int incl  = sA[tid];
    int total = sA[1023];
    int pos   = incl - (valid ? 1 : 0);
    if (valid) {
        int ci = img * NCAND + lvl * K_TOP + pos;
        cscore[ci] = sm;
        cbox[ci]   = make_float4(x0, y0, x1, y1);
        cobox[ci]  = make_float4(b0, b1, b2, b3);
        cog[ci]    = (unsigned)r;
    }
    if (tid == 0) vcnt[task] = (unsigned)total;
}

// ---------------- pass 5: fused merge + scan, serial phase on wave 0 only ----------------
__global__ __launch_bounds__(1024) void kMergeScan(
        const float* __restrict__ cscore,
        const float4* __restrict__ cbox,
        const float4* __restrict__ cobox,
        const unsigned* __restrict__ cog,
        const unsigned* __restrict__ vcnt,
        float* __restrict__ out) {
    int img = blockIdx.x;
    int tid = threadIdx.x;
    int lane = tid & 63;
    int wave = tid >> 6;
    __shared__ u64    comp[NCAND];      // 40000 B
    __shared__ float4 mobS[NPAD];       // 80896 B
    __shared__ unsigned midxS[NCAND];   // 20000 B
    __shared__ u64    diagWS[64];
    __shared__ u64    partS[16];
    __shared__ float4 pboxAll[NPOST];
    __shared__ unsigned emS[NPOST];
    __shared__ int LSs[NLVL];
    __shared__ int stateS[2];           // {emitted, done}
    const int imgb = img * NCAND;

    if (tid < NLVL) LSs[tid] = (int)vcnt[img * NLVL + tid];
    __syncthreads();
    int V = LSs[0] + LSs[1] + LSs[2] + LSs[3] + LSs[4];
    for (int g = tid; g < NCAND; g += 1024) {
        int lv = g / K_TOP, gl = g - lv * K_TOP;
        u64 c = 0ULL;
        if (gl < LSs[lv]) {
            unsigned og = (unsigned)(lv * K_TOP) + cog[imgb + g];
            c = ((u64)key_of(cscore[imgb + g]) << 32) | (unsigned)(~og);
        }
        comp[g] = c;
    }
    __syncthreads();
    // rank by 4-way interleaved binary search, scatter into LDS
    for (int g = tid; g < NCAND; g += 1024) {
        int lv = g / K_TOP, gl = g - lv * K_TOP;
        if (gl < LSs[lv]) {
            u64 c = comp[g];
            int o0 = (lv == 0) ? 1 : 0;
            int o1 = (lv <= 1) ? 2 : 1;
            int o2 = (lv <= 2) ? 3 : 2;
            int o3 = (lv <= 3) ? 4 : 3;
            int B0 = o0 * K_TOP, B1 = o1 * K_TOP, B2 = o2 * K_TOP, B3 = o3 * K_TOP;
            int l0 = 0, h0 = LSs[o0];
            int l1 = 0, h1 = LSs[o1];
            int l2 = 0, h2 = LSs[o2];
            int l3 = 0, h3 = LSs[o3];
#pragma unroll
            for (int step = 0; step < 11; ++step) {
                if (l0 < h0) { int m0 = (l0 + h0) >> 1; u64 v0 = comp[B0 + m0]; if (v0 > c) l0 = m0 + 1; else h0 = m0; }
                if (l1 < h1) { int m1 = (l1 + h1) >> 1; u64 v1 = comp[B1 + m1]; if (v1 > c) l1 = m1 + 1; else h1 = m1; }
                if (l2 < h2) { int m2 = (l2 + h2) >> 1; u64 v2 = comp[B2 + m2]; if (v2 > c) l2 = m2 + 1; else h2 = m2; }
                if (l3 < h3) { int m3 = (l3 + h3) >> 1; u64 v3 = comp[B3 + m3]; if (v3 > c) l3 = m3 + 1; else h3 = m3; }
            }
            int pos = gl + l0 + l1 + l2 + l3;
            mobS[pos]  = cobox[imgb + g];
            midxS[pos] = (unsigned)g;
        }
    }
    for (int pos = V + tid; pos < NPAD; pos += 1024)
        mobS[pos] = make_float4(0.f, 0.f, 0.f, 0.f);
    __syncthreads();

    // ---- word-tiled greedy scan; serial pops on wave 0 with shuffle-resident diag ----
    int emitted = 0;
    bool done = (V == 0);
    for (int w = 0; w < NWORDS && !done; ++w) {
        int base = w * 64;
        if (base >= V) break;
        // parallel phase (all 16 waves): suppression-by-emitted + own diag block
        float4 bc = mobS[base + lane];
        float  arc = (bc.z - bc.x) * (bc.w - bc.y);
        bool supp = false;
        for (int t = wave; t < emitted; t += 16) {
            float4 bp = pboxAll[t];
            float arp = (bp.z - bp.x) * (bp.w - bp.y);
            float ltx = fmaxf(bc.x, bp.x), lty = fmaxf(bc.y, bp.y);
            float rbx = fminf(bc.z, bp.z), rby = fminf(bc.w, bp.w);
            float wx = fmaxf(rbx - ltx, 0.f), wy = fmaxf(rby - lty, 0.f);
            float inter = wx * wy;
            float denom = (arc + arp) - inter + 1e-9f;
            supp |= (inter / denom) > 0.7f;
        }
        u64 sb = __ballot(supp);
        if (lane == 0) partS[wave] = sb;
#pragma unroll
        for (int rr = 0; rr < 4; ++rr) {
            int r = wave * 4 + rr;
            float4 bp = mobS[base + r];
            float arp = (bp.z - bp.x) * (bp.w - bp.y);
            float ltx = fmaxf(bc.x, bp.x), lty = fmaxf(bc.y, bp.y);
            float rbx = fminf(bc.z, bp.z), rby = fminf(bc.w, bp.w);
            float wx = fmaxf(rbx - ltx, 0.f), wy = fmaxf(rby - lty, 0.f);
            float inter = wx * wy;
            float denom = (arc + arp) - inter + 1e-9f;
            bool pred = (inter / denom) > 0.7f;
            u64 db = __ballot(pred);
            if (lane == 0) diagWS[r] = db;
        }
        __syncthreads();
        // serial phase: wave 0 only; diag rows live in lane registers
        if (wave == 0) {
            u64 dreg = diagWS[lane];
            u64 sm = partS[0];
#pragma unroll
            for (int q = 1; q < 16; ++q) sm |= partS[q];
            int rem = V - base;
            u64 vmask = (rem >= 64) ? ~0ULL : ((1ULL << rem) - 1ULL);
            u64 cur = (~sm) & vmask;
            int em = emitted;
            int dn = 0;
            while (cur) {
                int b = __builtin_ctzll(cur);
                u64 row = __shfl(dreg, b, 64);       // suppression row from registers
                if (lane == 0) {
                    emS[em]     = (unsigned)(base + b);
                    pboxAll[em] = mobS[base + b];
                }
                ++em;
                if (em == NPOST) { dn = 1; break; }
                cur &= ~row;
                cur &= ~(1ULL << b);
            }
            if (lane == 0) { stateS[0] = em; stateS[1] = dn; }
        }
        __syncthreads();
        emitted = stateS[0];
        done = (stateS[1] != 0);
        __syncthreads();
    }
    __syncthreads();
    // ---- parallel output gather ----
    for (int rr = tid; rr < NPOST; rr += 1024) {
        float* o = out + ((size_t)img * NPOST + rr) * 5;
        if (rr < emitted) {
            unsigned i = emS[rr];
            unsigned g = midxS[i];
            float4 cb = cbox[imgb + g];
            float sc = cscore[imgb + g];
            o[0] = cb.x; o[1] = cb.y; o[2] = cb.z; o[3] = cb.w; o[4] = sc;
        } else {
            o[0] = 0.f; o[1] = 0.f; o[2] = 0.f; o[3] = 0.f; o[4] = NEGF;
        }
    }
}

extern "C" void kernel_launch(void* const* d_in, const int* in_sizes, int n_in,
                              void* d_out, int out_size, void* d_ws, size_t ws_size,
                              hipStream_t stream) {
    Ptrs P;
    for (int l = 0; l < 5; ++l) {
        P.lg[l] = (const float*)d_in[2 * l];
        P.dl[l] = (const float*)d_in[2 * l + 1];
    }
    char* w = (char*)d_ws;
    size_t off = 0;
    auto alloc = [&](size_t bytes) -> void* {
        void* pp = (void*)(w + off);
        off = (off + bytes + 255) & ~(size_t)255;
        return pp;
    };
    unsigned* hist  = (unsigned*)alloc((size_t)NTASK * NB1 * 4);
    unsigned* tinfo = (unsigned*)alloc(NTASK * 2 * 4);
    unsigned* cnt   = (unsigned*)alloc(NTASK * 4);
    u64* compb      = (u64*)alloc((size_t)NTASK * CAP * 8);
    float*  cscore  = (float*)alloc((size_t)NTASK * K_TOP * 4);
    float4* cbox    = (float4*)alloc((size_t)NTASK * K_TOP * 16);
    float4* cobox   = (float4*)alloc((size_t)NTASK * K_TOP * 16);
    unsigned* cog   = (unsigned*)alloc((size_t)NTASK * K_TOP * 4);
    unsigned* vcnt  = (unsigned*)alloc(NTASK * 4);
    (void)in_sizes; (void)n_in; (void)out_size; (void)ws_size;

    size_t nhz = (size_t)NTASK * NB1;
    kZero<<<2048, 256, 0, stream>>>(hist, nhz);
    kHistAll<<<dim3(23, NIMG), 1024, 0, stream>>>(P, hist);
    kSelectBin<<<NTASK, 256, 0, stream>>>(hist, tinfo, cnt);
    kCompactAll<<<dim3(44, NIMG), 1024, 0, stream>>>(P, tinfo, cnt, compb);
    kSortSelect<<<NTASK, 1024, 0, stream>>>(P, cnt, tinfo, compb,
                                            cscore, cbox, cobox, cog, vcnt);
    kMergeScan<<<NIMG, 1024, 0, stream>>>(cscore, cbox, cobox, cog, vcnt,
                                          (float*)d_out);
}

// Round 15
// 115.159 us; speedup vs baseline: 6.2625x; 1.1685x over previous
//
#include <hip/hip_runtime.h>
#include <cstdint>
#include <cstddef>

#define NB1      16384      // 2^14 first-level radix bins
#define L1SHIFT  18         // key >> 18 -> 14-bit bin
#define CAP      4096       // compaction buffer per task
#define K_TOP    1000
#define NCAND    5000
#define NIMG     8
#define NLVL     5
#define NTASK    40
#define NPOST    300
#define NEGF     (-1e9f)
#define NWORDS   79         // ceil(5000/64)
#define NPAD     (NWORDS * 64)   // 5056, padded candidate count

typedef unsigned long long u64;

struct Ptrs {
    const float* lg[5];
    const float* dl[5];
};

__device__ __forceinline__ unsigned key_of(float f) {
    unsigned u = __float_as_uint(f);
    return (u & 0x80000000u) ? ~u : (u | 0x80000000u);
}

// ---------------- zero scratch ----------------
__global__ void kZero(unsigned* p, size_t n) {
    size_t i = (size_t)blockIdx.x * blockDim.x + threadIdx.x;
    size_t st = (size_t)gridDim.x * blockDim.x;
    for (; i < n; i += st) p[i] = 0u;
}

// ---------------- pass 1: all-level LDS-privatized histogram (1 dispatch) ----------------
__global__ __launch_bounds__(1024) void kHistAll(Ptrs p, unsigned* __restrict__ hist) {
    int bx = blockIdx.x;
    int lvl = (bx < 16) ? 0 : (bx < 20) ? 1 : (bx < 21) ? 2 : (bx < 22) ? 3 : 4;
    int lb  = bx - ((lvl == 0) ? 0 : (lvl == 1) ? 16 : (lvl == 2) ? 20 : (lvl == 3) ? 21 : 22);
    int gx  = (lvl == 0) ? 16 : (lvl == 1) ? 4 : 1;
    int m   = (lvl == 0) ? 516096 : (lvl == 1) ? 129024 : (lvl == 2) ? 32256
              : (lvl == 3) ? 8064 : 2016;
    int img  = blockIdx.y;
    int task = img * NLVL + lvl;
    const float* lg = p.lg[lvl];
    __shared__ unsigned h[NB1];
    for (int i = threadIdx.x; i < NB1; i += 1024) h[i] = 0u;
    __syncthreads();
    int m4 = m >> 2;
    int chunk4 = (m4 + gx - 1) / gx;
    int start4 = lb * chunk4;
    int end4   = min(start4 + chunk4, m4);
    const float4* src = (const float4*)(lg + (size_t)img * m);
    for (int i = start4 + threadIdx.x; i < end4; i += 1024) {
        float4 v = src[i];
        atomicAdd(&h[key_of(v.x) >> L1SHIFT], 1u);
        atomicAdd(&h[key_of(v.y) >> L1SHIFT], 1u);
        atomicAdd(&h[key_of(v.z) >> L1SHIFT], 1u);
        atomicAdd(&h[key_of(v.w) >> L1SHIFT], 1u);
    }
    __syncthreads();
    unsigned* gh = hist + (size_t)task * NB1;
    for (int i = threadIdx.x; i < NB1; i += 1024) {
        unsigned c = h[i];
        if (c) atomicAdd(&gh[i], c);
    }
}

// ---------------- pass 2: find 14-bit prefix of the K-th largest ----------------
__global__ __launch_bounds__(256) void kSelectBin(const unsigned* __restrict__ hist,
                                                  unsigned* __restrict__ tinfo,
                                                  unsigned* __restrict__ cnt) {
    int task = blockIdx.x;
    const unsigned* h = hist + (size_t)task * NB1;
    __shared__ unsigned sblk[256];
    __shared__ unsigned sbin[64];
    __shared__ int sh_tb;
    __shared__ unsigned sh_rem;
    int t = threadIdx.x;
    unsigned s = 0;
    for (int i = 0; i < 64; ++i) s += h[t * 64 + i];
    sblk[t] = s;
    __syncthreads();
    if (t == 0) {
        unsigned rem = K_TOP; int tb = 0;
        for (int b = 255; b >= 0; --b) {
            if (sblk[b] < rem) rem -= sblk[b];
            else { tb = b; break; }
        }
        sh_tb = tb; sh_rem = rem;
    }
    __syncthreads();
    if (t < 64) sbin[t] = h[sh_tb * 64 + t];
    __syncthreads();
    if (t == 0) {
        unsigned rem = sh_rem; int pfx = sh_tb * 64;
        for (int b = 63; b >= 0; --b) {
            if (sbin[b] < rem) rem -= sbin[b];
            else { pfx = sh_tb * 64 + b; break; }
        }
        tinfo[task * 2]     = (unsigned)pfx;
        tinfo[task * 2 + 1] = rem;
        cnt[task] = 0u;
    }
}

// ---------------- pass 3: all-level compact (1 dispatch) ----------------
__global__ __launch_bounds__(1024) void kCompactAll(Ptrs p,
                                                    const unsigned* __restrict__ tinfo,
                                                    unsigned* __restrict__ cnt,
                                                    u64* __restrict__ compbuf) {
    int bx = blockIdx.x;
    int lvl = (bx < 32) ? 0 : (bx < 40) ? 1 : (bx < 42) ? 2 : (bx < 43) ? 3 : 4;
    int lb  = bx - ((lvl == 0) ? 0 : (lvl == 1) ? 32 : (lvl == 2) ? 40 : (lvl == 3) ? 42 : 43);
    int gx  = (lvl == 0) ? 32 : (lvl == 1) ? 8 : (lvl == 2) ? 2 : 1;
    int m   = (lvl == 0) ? 516096 : (lvl == 1) ? 129024 : (lvl == 2) ? 32256
              : (lvl == 3) ? 8064 : 2016;
    int img  = blockIdx.y;
    int task = img * NLVL + lvl;
    const float* lg = p.lg[lvl];
    unsigned pfx = tinfo[task * 2];
    __shared__ u64 stage[CAP];
    __shared__ unsigned lcnt, gbase;
    if (threadIdx.x == 0) lcnt = 0u;
    __syncthreads();
    int m4 = m >> 2;
    int chunk4 = (m4 + gx - 1) / gx;
    int start4 = lb * chunk4;
    int end4   = min(start4 + chunk4, m4);
    const float4* src = (const float4*)(lg + (size_t)img * m);
    for (int i = start4 + threadIdx.x; i < end4; i += 1024) {
        float4 v = src[i];
        int j = i * 4;
        unsigned k0 = key_of(v.x);
        unsigned k1 = key_of(v.y);
        unsigned k2 = key_of(v.z);
        unsigned k3 = key_of(v.w);
        if ((k0 >> L1SHIFT) >= pfx) {
            unsigned q = atomicAdd(&lcnt, 1u);
            if (q < CAP) stage[q] = ((u64)k0 << 32) | (unsigned)(~(unsigned)(j));
        }
        if ((k1 >> L1SHIFT) >= pfx) {
            unsigned q = atomicAdd(&lcnt, 1u);
            if (q < CAP) stage[q] = ((u64)k1 << 32) | (unsigned)(~(unsigned)(j + 1));
        }
        if ((k2 >> L1SHIFT) >= pfx) {
            unsigned q = atomicAdd(&lcnt, 1u);
            if (q < CAP) stage[q] = ((u64)k2 << 32) | (unsigned)(~(unsigned)(j + 2));
        }
        if ((k3 >> L1SHIFT) >= pfx) {
            unsigned q = atomicAdd(&lcnt, 1u);
            if (q < CAP) stage[q] = ((u64)k3 << 32) | (unsigned)(~(unsigned)(j + 3));
        }
    }
    __syncthreads();
    if (threadIdx.x == 0) gbase = atomicAdd(&cnt[task], lcnt);
    __syncthreads();
    unsigned total = min(lcnt, (unsigned)CAP);
    unsigned base  = gbase;
    for (unsigned q = threadIdx.x; q < total; q += 1024) {
        unsigned pos = base + q;
        if (pos < CAP) compbuf[(size_t)task * CAP + pos] = stage[q];
    }
}

// ---------------- pass 4: split-sort (sure/boundary), decode, valid-compact ----
__global__ __launch_bounds__(1024) void kSortSelect(
        Ptrs p,
        const unsigned* __restrict__ cnt,
        const unsigned* __restrict__ tinfo,
        const u64* __restrict__ compbuf,
        float* __restrict__ cscore,
        float4* __restrict__ cbox,
        float4* __restrict__ cobox,
        unsigned* __restrict__ cog,
        unsigned* __restrict__ vcnt) {
    int task = blockIdx.x;
    int img = task / NLVL, lvl = task % NLVL;
    int tid = threadIdx.x;
    __shared__ u64 sure[1024];
    __shared__ u64 bnd[2048];
    __shared__ unsigned cS, cB;
    if (tid == 0) { cS = 0u; cB = 0u; }
    sure[tid] = 0ULL;
    bnd[tid] = 0ULL; bnd[tid + 1024] = 0ULL;
    __syncthreads();
    int n = min((int)cnt[task], CAP);
    unsigned pfx = tinfo[task * 2];
    for (int i = tid; i < n; i += 1024) {
        u64 c = compbuf[(size_t)task * CAP + i];
        unsigned bin = (unsigned)(c >> (32 + L1SHIFT));
        if (bin > pfx) {
            unsigned q = atomicAdd(&cS, 1u);
            if (q < 1024) sure[q] = c;
        } else {
            unsigned q = atomicAdd(&cB, 1u);
            if (q < 2048) bnd[q] = c;
        }
    }
    __syncthreads();
    unsigned S = cS;
    unsigned B = cB;
    {
        u64* arr = (tid < 512) ? sure : bnd;
        int q = tid & 511;
        for (int k = 2; k <= 1024; k <<= 1) {
            for (int j = k >> 1; j > 0; j >>= 1) {
                int i = ((q & ~(j - 1)) << 1) | (q & (j - 1));
                int pp = i | j;
                u64 A = arr[i], Bv = arr[pp];
                bool up = ((i & k) == 0);
                if (up ? (A < Bv) : (A > Bv)) { arr[i] = Bv; arr[pp] = A; }
                __syncthreads();
            }
        }
    }
    if (B > 1024) {    // statistically never; full 2048 network re-sorts bnd
        for (int k = 2; k <= 2048; k <<= 1)
            for (int j = k >> 1; j > 0; j >>= 1) {
                int i = ((tid & ~(j - 1)) << 1) | (tid & (j - 1));
                int pp = i | j;
                u64 A = bnd[i], Bv = bnd[pp];
                bool up = ((i & k) == 0);
                if (up ? (A < Bv) : (A > Bv)) { bnd[i] = Bv; bnd[pp] = A; }
                __syncthreads();
            }
    }
    int r = tid;
    u64 c = 0ULL;
    if (r < K_TOP) c = (r < (int)S) ? sure[r] : ((r - (int)S < (int)B) ? bnd[r - (int)S] : 0ULL);
    __syncthreads();                 // all sure/bnd reads done (bnd reused for scan)

    const int   MS[5]     = {516096, 129024, 32256, 8064, 2016};
    const int   GW[5]     = {512, 256, 128, 64, 32};
    const float STRIDEF[5]= {4.f, 8.f, 16.f, 32.f, 64.f};
    const int   SIZEI[5]  = {32, 64, 128, 256, 512};
    float sm = NEGF, x0 = 0.f, y0 = 0.f, x1 = 0.f, y1 = 0.f;
    float b0 = 0.f, b1 = 0.f, b2 = 0.f, b3 = 0.f;
    bool valid = false;
    if (r < K_TOP) {
        int idx = (int)(~(unsigned)c);
        int m = MS[lvl];
        if ((unsigned)idx >= (unsigned)m) idx = 0;   // safety (never expected)
        const float* lg = p.lg[lvl];
        const float* dl = p.dl[lvl];
        float score = lg[(size_t)img * m + idx];
        int a   = idx % 3;
        int loc = idx / 3;
        int gw  = GW[lvl];
        int x = loc % gw, y = loc / gw;
        double ssz = (double)SIZEI[lvl];
        double arr = (a == 0) ? 0.5 : ((a == 1) ? 1.0 : 2.0);
        double wd = sqrt(ssz * ssz / arr);
        double hd = arr * wd;
        float sx = (float)x * STRIDEF[lvl];
        float sy = (float)y * STRIDEF[lvl];
        float a0 = sx + (float)(-wd * 0.5);
        float a1 = sy + (float)(-hd * 0.5);
        float a2 = sx + (float)( wd * 0.5);
        float a3 = sy + (float)( hd * 0.5);
        float aw = a2 - a0, ah = a3 - a1;
        float acx = a0 + 0.5f * aw, acy = a1 + 0.5f * ah;
        size_t db = ((size_t)img * m + idx) * 4;
        float dx = dl[db], dy = dl[db + 1], dwv = dl[db + 2], dhv = dl[db + 3];
        const float CL = 4.135166556742356f;   // log(1000/16)
        float pw = expf(fminf(dwv, CL)) * aw;
        float ph = expf(fminf(dhv, CL)) * ah;
        float pcx = dx * aw + acx;
        float pcy = dy * ah + acy;
        x0 = pcx - 0.5f * pw; y0 = pcy - 0.5f * ph;
        x1 = pcx + 0.5f * pw; y1 = pcy + 0.5f * ph;
        x0 = fminf(fmaxf(x0, 0.f), 2048.f);
        x1 = fminf(fmaxf(x1, 0.f), 2048.f);
        y0 = fminf(fmaxf(y0, 0.f), 1344.f);
        y1 = fminf(fmaxf(y1, 0.f), 1344.f);
        bool keep = ((x1 - x0) > 0.f) && ((y1 - y0) > 0.f);
        valid = keep;
        sm = score;
        float off = (float)lvl * 2049.0f;
        b0 = x0 + off; b1 = y0 + off; b2 = x1 + off; b3 = y1 + off;
    }
    // block prefix scan over valid flags (Hillis-Steele, ping-pong in bnd region)
    int* sc1 = (int*)bnd;
    int* sc2 = sc1 + 1024;
    sc1[tid] = valid ? 1 : 0;
    __syncthreads();
    int* sA = sc1; int* sB = sc2;
    for (int dd = 1; dd < 1024; dd <<= 1) {
        int v = sA[tid];
        if (tid >= dd) v += sA[tid - dd];
        sB[tid] = v;
        __syncthreads();
        int* t2 = sA; sA = sB; sB = t2;
    }
    int incl  = sA[tid];
    int total = sA[1023];
    int pos   = incl - (valid ? 1 : 0);
    if (valid) {
        int ci = img * NCAND + lvl * K_TOP + pos;
        cscore[ci] = sm;
        cbox[ci]   = make_float4(x0, y0, x1, y1);
        cobox[ci]  = make_float4(b0, b1, b2, b3);
        cog[ci]    = (unsigned)r;
    }
    if (tid == 0) vcnt[task] = (unsigned)total;
}

// ---------------- pass 5: fused merge + scan; pop loop is pure register/ballot ----------------
__global__ __launch_bounds__(1024) void kMergeScan(
        const float* __restrict__ cscore,
        const float4* __restrict__ cbox,
        const float4* __restrict__ cobox,
        const unsigned* __restrict__ cog,
        const unsigned* __restrict__ vcnt,
        float* __restrict__ out) {
    int img = blockIdx.x;
    int tid = threadIdx.x;
    int lane = tid & 63;
    int wave = tid >> 6;
    __shared__ u64    comp[NCAND];      // 40000 B
    __shared__ float4 mobS[NPAD];       // 80896 B
    __shared__ unsigned midxS[NCAND];   // 20000 B
    __shared__ u64    diagWS[64];
    __shared__ u64    partS[16];
    __shared__ float4 pboxAll[NPOST];
    __shared__ unsigned emS[NPOST];
    __shared__ int LSs[NLVL];
    __shared__ int stateS[2];           // {emitted, done}
    const int imgb = img * NCAND;

    if (tid < NLVL) LSs[tid] = (int)vcnt[img * NLVL + tid];
    __syncthreads();
    int V = LSs[0] + LSs[1] + LSs[2] + LSs[3] + LSs[4];
    for (int g = tid; g < NCAND; g += 1024) {
        int lv = g / K_TOP, gl = g - lv * K_TOP;
        u64 c = 0ULL;
        if (gl < LSs[lv]) {
            unsigned og = (unsigned)(lv * K_TOP) + cog[imgb + g];
            c = ((u64)key_of(cscore[imgb + g]) << 32) | (unsigned)(~og);
        }
        comp[g] = c;
    }
    __syncthreads();
    // rank by 4-way interleaved binary search; cobox prefetched to overlap HBM latency
    for (int g = tid; g < NCAND; g += 1024) {
        int lv = g / K_TOP, gl = g - lv * K_TOP;
        if (gl < LSs[lv]) {
            float4 pref = cobox[imgb + g];     // issue early, consumed after search
            u64 c = comp[g];
            int o0 = (lv == 0) ? 1 : 0;
            int o1 = (lv <= 1) ? 2 : 1;
            int o2 = (lv <= 2) ? 3 : 2;
            int o3 = (lv <= 3) ? 4 : 3;
            int B0 = o0 * K_TOP, B1 = o1 * K_TOP, B2 = o2 * K_TOP, B3 = o3 * K_TOP;
            int l0 = 0, h0 = LSs[o0];
            int l1 = 0, h1 = LSs[o1];
            int l2 = 0, h2 = LSs[o2];
            int l3 = 0, h3 = LSs[o3];
#pragma unroll
            for (int step = 0; step < 11; ++step) {
                if (l0 < h0) { int m0 = (l0 + h0) >> 1; u64 v0 = comp[B0 + m0]; if (v0 > c) l0 = m0 + 1; else h0 = m0; }
                if (l1 < h1) { int m1 = (l1 + h1) >> 1; u64 v1 = comp[B1 + m1]; if (v1 > c) l1 = m1 + 1; else h1 = m1; }
                if (l2 < h2) { int m2 = (l2 + h2) >> 1; u64 v2 = comp[B2 + m2]; if (v2 > c) l2 = m2 + 1; else h2 = m2; }
                if (l3 < h3) { int m3 = (l3 + h3) >> 1; u64 v3 = comp[B3 + m3]; if (v3 > c) l3 = m3 + 1; else h3 = m3; }
            }
            int pos = gl + l0 + l1 + l2 + l3;
            mobS[pos]  = pref;
            midxS[pos] = (unsigned)g;
        }
    }
    for (int pos = V + tid; pos < NPAD; pos += 1024)
        mobS[pos] = make_float4(0.f, 0.f, 0.f, 0.f);
    __syncthreads();

    // ---- word-tiled greedy scan; pop loop = ctz + ballot + masks only ----
    int emitted = 0;
    bool done = (V == 0);
    for (int w = 0; w < NWORDS && !done; ++w) {
        int base = w * 64;
        if (base >= V) break;
        // parallel phase (all 16 waves): suppression-by-emitted + own diag block
        float4 bc = mobS[base + lane];
        float  arc = (bc.z - bc.x) * (bc.w - bc.y);
        bool supp = false;
        for (int t = wave; t < emitted; t += 16) {
            float4 bp = pboxAll[t];
            float arp = (bp.z - bp.x) * (bp.w - bp.y);
            float ltx = fmaxf(bc.x, bp.x), lty = fmaxf(bc.y, bp.y);
            float rbx = fminf(bc.z, bp.z), rby = fminf(bc.w, bp.w);
            float wx = fmaxf(rbx - ltx, 0.f), wy = fmaxf(rby - lty, 0.f);
            float inter = wx * wy;
            float denom = (arc + arp) - inter + 1e-9f;
            supp |= (inter / denom) > 0.7f;
        }
        u64 sb = __ballot(supp);
        if (lane == 0) partS[wave] = sb;
#pragma unroll
        for (int rr = 0; rr < 4; ++rr) {
            int r = wave * 4 + rr;
            float4 bp = mobS[base + r];
            float arp = (bp.z - bp.x) * (bp.w - bp.y);
            float ltx = fmaxf(bc.x, bp.x), lty = fmaxf(bc.y, bp.y);
            float rbx = fminf(bc.z, bp.z), rby = fminf(bc.w, bp.w);
            float wx = fmaxf(rbx - ltx, 0.f), wy = fmaxf(rby - lty, 0.f);
            float inter = wx * wy;
            float denom = (arc + arp) - inter + 1e-9f;
            bool pred = (inter / denom) > 0.7f;
            u64 db = __ballot(pred);
            if (lane == 0) diagWS[r] = db;
        }
        __syncthreads();
        // serial phase: wave 0; diag row b reconstructed by symmetry via ballot
        if (wave == 0) {
            u64 dreg = diagWS[lane];           // lane's own row (symmetric matrix)
            u64 smv = partS[0];
#pragma unroll
            for (int q = 1; q < 16; ++q) smv |= partS[q];
            int rem = V - base;
            u64 vmask = (rem >= 64) ? ~0ULL : ((1ULL << rem) - 1ULL);
            u64 cur = (~smv) & vmask;
            int em = emitted;
            int dn = 0;
            u64 embits = 0ULL;
            while (cur) {
                int b = __builtin_ctzll(cur);
                embits |= 1ULL << b;
                ++em;
                if (em == NPOST) { dn = 1; break; }
                u64 row = __ballot((dreg >> b) & 1ULL);   // row[b] via symmetry
                cur &= ~row;
                cur &= ~(1ULL << b);
            }
            // parallel write-back: pops were in ascending bit order
            if ((embits >> lane) & 1ULL) {
                int rank = __popcll(embits & ((1ULL << lane) - 1ULL));
                emS[emitted + rank]     = (unsigned)(base + lane);
                pboxAll[emitted + rank] = mobS[base + lane];
            }
            if (lane == 0) { stateS[0] = em; stateS[1] = dn; }
        }
        __syncthreads();
        emitted = stateS[0];
        done = (stateS[1] != 0);
        // no extra barrier: next write to stateS/partS/diagWS is separated by
        // the post-parallel-phase barrier of the next iteration
    }
    __syncthreads();
    // ---- parallel output gather ----
    for (int rr = tid; rr < NPOST; rr += 1024) {
        float* o = out + ((size_t)img * NPOST + rr) * 5;
        if (rr < emitted) {
            unsigned i = emS[rr];
            unsigned g = midxS[i];
            float4 cb = cbox[imgb + g];
            float sc = cscore[imgb + g];
            o[0] = cb.x; o[1] = cb.y; o[2] = cb.z; o[3] = cb.w; o[4] = sc;
        } else {
            o[0] = 0.f; o[1] = 0.f; o[2] = 0.f; o[3] = 0.f; o[4] = NEGF;
        }
    }
}

extern "C" void kernel_launch(void* const* d_in, const int* in_sizes, int n_in,
                              void* d_out, int out_size, void* d_ws, size_t ws_size,
                              hipStream_t stream) {
    Ptrs P;
    for (int l = 0; l < 5; ++l) {
        P.lg[l] = (const float*)d_in[2 * l];
        P.dl[l] = (const float*)d_in[2 * l + 1];
    }
    char* w = (char*)d_ws;
    size_t off = 0;
    auto alloc = [&](size_t bytes) -> void* {
        void* pp = (void*)(w + off);
        off = (off + bytes + 255) & ~(size_t)255;
        return pp;
    };
    unsigned* hist  = (unsigned*)alloc((size_t)NTASK * NB1 * 4);
    unsigned* tinfo = (unsigned*)alloc(NTASK * 2 * 4);
    unsigned* cnt   = (unsigned*)alloc(NTASK * 4);
    u64* compb      = (u64*)alloc((size_t)NTASK * CAP * 8);
    float*  cscore  = (float*)alloc((size_t)NTASK * K_TOP * 4);
    float4* cbox    = (float4*)alloc((size_t)NTASK * K_TOP * 16);
    float4* cobox   = (float4*)alloc((size_t)NTASK * K_TOP * 16);
    unsigned* cog   = (unsigned*)alloc((size_t)NTASK * K_TOP * 4);
    unsigned* vcnt  = (unsigned*)alloc(NTASK * 4);
    (void)in_sizes; (void)n_in; (void)out_size; (void)ws_size;

    size_t nhz = (size_t)NTASK * NB1;
    kZero<<<2048, 256, 0, stream>>>(hist, nhz);
    kHistAll<<<dim3(23, NIMG), 1024, 0, stream>>>(P, hist);
    kSelectBin<<<NTASK, 256, 0, stream>>>(hist, tinfo, cnt);
    kCompactAll<<<dim3(44, NIMG), 1024, 0, stream>>>(P, tinfo, cnt, compb);
    kSortSelect<<<NTASK, 1024, 0, stream>>>(P, cnt, tinfo, compb,
                                            cscore, cbox, cobox, cog, vcnt);
    kMergeScan<<<NIMG, 1024, 0, stream>>>(cscore, cbox, cobox, cog, vcnt,
                                          (float*)d_out);
}

// Round 16
// 110.852 us; speedup vs baseline: 6.5059x; 1.0389x over previous
//
#include <hip/hip_runtime.h>
#include <cstdint>
#include <cstddef>

#define NB1      16384      // 2^14 first-level radix bins
#define L1SHIFT  18         // key >> 18 -> 14-bit bin
#define CAP      4096       // compaction buffer per task
#define K_TOP    1000
#define NCAND    5000
#define NIMG     8
#define NLVL     5
#define NTASK    40
#define NPOST    300
#define NEGF     (-1e9f)
#define NWORDS   79         // ceil(5000/64)
#define NPAD     (NWORDS * 64)   // 5056, padded candidate count

typedef unsigned long long u64;

struct Ptrs {
    const float* lg[5];
    const float* dl[5];
};

__device__ __forceinline__ unsigned key_of(float f) {
    unsigned u = __float_as_uint(f);
    return (u & 0x80000000u) ? ~u : (u | 0x80000000u);
}

// ---------------- pass 1: all-level LDS-privatized histogram (1 dispatch) ----------------
__global__ __launch_bounds__(1024) void kHistAll(Ptrs p, unsigned* __restrict__ hist) {
    int bx = blockIdx.x;
    int lvl = (bx < 16) ? 0 : (bx < 20) ? 1 : (bx < 21) ? 2 : (bx < 22) ? 3 : 4;
    int lb  = bx - ((lvl == 0) ? 0 : (lvl == 1) ? 16 : (lvl == 2) ? 20 : (lvl == 3) ? 21 : 22);
    int gx  = (lvl == 0) ? 16 : (lvl == 1) ? 4 : 1;
    int m   = (lvl == 0) ? 516096 : (lvl == 1) ? 129024 : (lvl == 2) ? 32256
              : (lvl == 3) ? 8064 : 2016;
    int img  = blockIdx.y;
    int task = img * NLVL + lvl;
    const float* lg = p.lg[lvl];
    __shared__ unsigned h[NB1];
    for (int i = threadIdx.x; i < NB1; i += 1024) h[i] = 0u;
    __syncthreads();
    int m4 = m >> 2;
    int chunk4 = (m4 + gx - 1) / gx;
    int start4 = lb * chunk4;
    int end4   = min(start4 + chunk4, m4);
    const float4* src = (const float4*)(lg + (size_t)img * m);
    for (int i = start4 + threadIdx.x; i < end4; i += 1024) {
        float4 v = src[i];
        atomicAdd(&h[key_of(v.x) >> L1SHIFT], 1u);
        atomicAdd(&h[key_of(v.y) >> L1SHIFT], 1u);
        atomicAdd(&h[key_of(v.z) >> L1SHIFT], 1u);
        atomicAdd(&h[key_of(v.w) >> L1SHIFT], 1u);
    }
    __syncthreads();
    unsigned* gh = hist + (size_t)task * NB1;
    for (int i = threadIdx.x; i < NB1; i += 1024) {
        unsigned c = h[i];
        if (c) atomicAdd(&gh[i], c);
    }
}

// ---------------- pass 2: find 14-bit prefix of the K-th largest ----------------
__global__ __launch_bounds__(256) void kSelectBin(const unsigned* __restrict__ hist,
                                                  unsigned* __restrict__ tinfo,
                                                  unsigned* __restrict__ cnt) {
    int task = blockIdx.x;
    const unsigned* h = hist + (size_t)task * NB1;
    __shared__ unsigned sblk[256];
    __shared__ unsigned sbin[64];
    __shared__ int sh_tb;
    __shared__ unsigned sh_rem;
    int t = threadIdx.x;
    unsigned s = 0;
    for (int i = 0; i < 64; ++i) s += h[t * 64 + i];
    sblk[t] = s;
    __syncthreads();
    if (t == 0) {
        unsigned rem = K_TOP; int tb = 0;
        for (int b = 255; b >= 0; --b) {
            if (sblk[b] < rem) rem -= sblk[b];
            else { tb = b; break; }
        }
        sh_tb = tb; sh_rem = rem;
    }
    __syncthreads();
    if (t < 64) sbin[t] = h[sh_tb * 64 + t];
    __syncthreads();
    if (t == 0) {
        unsigned rem = sh_rem; int pfx = sh_tb * 64;
        for (int b = 63; b >= 0; --b) {
            if (sbin[b] < rem) rem -= sbin[b];
            else { pfx = sh_tb * 64 + b; break; }
        }
        tinfo[task * 2]     = (unsigned)pfx;
        tinfo[task * 2 + 1] = rem;
        cnt[task] = 0u;
    }
}

// ---------------- pass 3: all-level compact (1 dispatch) ----------------
__global__ __launch_bounds__(1024) void kCompactAll(Ptrs p,
                                                    const unsigned* __restrict__ tinfo,
                                                    unsigned* __restrict__ cnt,
                                                    u64* __restrict__ compbuf) {
    int bx = blockIdx.x;
    int lvl = (bx < 32) ? 0 : (bx < 40) ? 1 : (bx < 42) ? 2 : (bx < 43) ? 3 : 4;
    int lb  = bx - ((lvl == 0) ? 0 : (lvl == 1) ? 32 : (lvl == 2) ? 40 : (lvl == 3) ? 42 : 43);
    int gx  = (lvl == 0) ? 32 : (lvl == 1) ? 8 : (lvl == 2) ? 2 : 1;
    int m   = (lvl == 0) ? 516096 : (lvl == 1) ? 129024 : (lvl == 2) ? 32256
              : (lvl == 3) ? 8064 : 2016;
    int img  = blockIdx.y;
    int task = img * NLVL + lvl;
    const float* lg = p.lg[lvl];
    unsigned pfx = tinfo[task * 2];
    __shared__ u64 stage[CAP];
    __shared__ unsigned lcnt, gbase;
    if (threadIdx.x == 0) lcnt = 0u;
    __syncthreads();
    int m4 = m >> 2;
    int chunk4 = (m4 + gx - 1) / gx;
    int start4 = lb * chunk4;
    int end4   = min(start4 + chunk4, m4);
    const float4* src = (const float4*)(lg + (size_t)img * m);
    for (int i = start4 + threadIdx.x; i < end4; i += 1024) {
        float4 v = src[i];
        int j = i * 4;
        unsigned k0 = key_of(v.x);
        unsigned k1 = key_of(v.y);
        unsigned k2 = key_of(v.z);
        unsigned k3 = key_of(v.w);
        if ((k0 >> L1SHIFT) >= pfx) {
            unsigned q = atomicAdd(&lcnt, 1u);
            if (q < CAP) stage[q] = ((u64)k0 << 32) | (unsigned)(~(unsigned)(j));
        }
        if ((k1 >> L1SHIFT) >= pfx) {
            unsigned q = atomicAdd(&lcnt, 1u);
            if (q < CAP) stage[q] = ((u64)k1 << 32) | (unsigned)(~(unsigned)(j + 1));
        }
        if ((k2 >> L1SHIFT) >= pfx) {
            unsigned q = atomicAdd(&lcnt, 1u);
            if (q < CAP) stage[q] = ((u64)k2 << 32) | (unsigned)(~(unsigned)(j + 2));
        }
        if ((k3 >> L1SHIFT) >= pfx) {
            unsigned q = atomicAdd(&lcnt, 1u);
            if (q < CAP) stage[q] = ((u64)k3 << 32) | (unsigned)(~(unsigned)(j + 3));
        }
    }
    __syncthreads();
    if (threadIdx.x == 0) gbase = atomicAdd(&cnt[task], lcnt);
    __syncthreads();
    unsigned total = min(lcnt, (unsigned)CAP);
    unsigned base  = gbase;
    for (unsigned q = threadIdx.x; q < total; q += 1024) {
        unsigned pos = base + q;
        if (pos < CAP) compbuf[(size_t)task * CAP + pos] = stage[q];
    }
}

// ---------------- pass 4: split-sort (sure/boundary), decode, valid-compact ----
__global__ __launch_bounds__(1024) void kSortSelect(
        Ptrs p,
        const unsigned* __restrict__ cnt,
        const unsigned* __restrict__ tinfo,
        const u64* __restrict__ compbuf,
        float* __restrict__ cscore,
        float4* __restrict__ cbox,
        float4* __restrict__ cobox,
        unsigned* __restrict__ cog,
        unsigned* __restrict__ vcnt) {
    int task = blockIdx.x;
    int img = task / NLVL, lvl = task % NLVL;
    int tid = threadIdx.x;
    __shared__ u64 sure[1024];
    __shared__ u64 bnd[2048];
    __shared__ unsigned cS, cB;
    if (tid == 0) { cS = 0u; cB = 0u; }
    sure[tid] = 0ULL;
    bnd[tid] = 0ULL; bnd[tid + 1024] = 0ULL;
    __syncthreads();
    int n = min((int)cnt[task], CAP);
    unsigned pfx = tinfo[task * 2];
    for (int i = tid; i < n; i += 1024) {
        u64 c = compbuf[(size_t)task * CAP + i];
        unsigned bin = (unsigned)(c >> (32 + L1SHIFT));
        if (bin > pfx) {
            unsigned q = atomicAdd(&cS, 1u);
            if (q < 1024) sure[q] = c;
        } else {
            unsigned q = atomicAdd(&cB, 1u);
            if (q < 2048) bnd[q] = c;
        }
    }
    __syncthreads();
    unsigned S = cS;
    unsigned B = cB;
    {
        u64* arr = (tid < 512) ? sure : bnd;
        int q = tid & 511;
        for (int k = 2; k <= 1024; k <<= 1) {
            for (int j = k >> 1; j > 0; j >>= 1) {
                int i = ((q & ~(j - 1)) << 1) | (q & (j - 1));
                int pp = i | j;
                u64 A = arr[i], Bv = arr[pp];
                bool up = ((i & k) == 0);
                if (up ? (A < Bv) : (A > Bv)) { arr[i] = Bv; arr[pp] = A; }
                __syncthreads();
            }
        }
    }
    if (B > 1024) {    // statistically never; full 2048 network re-sorts bnd
        for (int k = 2; k <= 2048; k <<= 1)
            for (int j = k >> 1; j > 0; j >>= 1) {
                int i = ((tid & ~(j - 1)) << 1) | (tid & (j - 1));
                int pp = i | j;
                u64 A = bnd[i], Bv = bnd[pp];
                bool up = ((i & k) == 0);
                if (up ? (A < Bv) : (A > Bv)) { bnd[i] = Bv; bnd[pp] = A; }
                __syncthreads();
            }
    }
    int r = tid;
    u64 c = 0ULL;
    if (r < K_TOP) c = (r < (int)S) ? sure[r] : ((r - (int)S < (int)B) ? bnd[r - (int)S] : 0ULL);
    __syncthreads();                 // all sure/bnd reads done (bnd reused for scan)

    const int   MS[5]     = {516096, 129024, 32256, 8064, 2016};
    const int   GW[5]     = {512, 256, 128, 64, 32};
    const float STRIDEF[5]= {4.f, 8.f, 16.f, 32.f, 64.f};
    const int   SIZEI[5]  = {32, 64, 128, 256, 512};
    float sm = NEGF, x0 = 0.f, y0 = 0.f, x1 = 0.f, y1 = 0.f;
    float b0 = 0.f, b1 = 0.f, b2 = 0.f, b3 = 0.f;
    bool valid = false;
    if (r < K_TOP) {
        int idx = (int)(~(unsigned)c);
        int m = MS[lvl];
        if ((unsigned)idx >= (unsigned)m) idx = 0;   // safety (never expected)
        const float* lg = p.lg[lvl];
        const float* dl = p.dl[lvl];
        float score = lg[(size_t)img * m + idx];
        int a   = idx % 3;
        int loc = idx / 3;
        int gw  = GW[lvl];
        int x = loc % gw, y = loc / gw;
        double ssz = (double)SIZEI[lvl];
        double arr = (a == 0) ? 0.5 : ((a == 1) ? 1.0 : 2.0);
        double wd = sqrt(ssz * ssz / arr);
        double hd = arr * wd;
        float sx = (float)x * STRIDEF[lvl];
        float sy = (float)y * STRIDEF[lvl];
        float a0 = sx + (float)(-wd * 0.5);
        float a1 = sy + (float)(-hd * 0.5);
        float a2 = sx + (float)( wd * 0.5);
        float a3 = sy + (float)( hd * 0.5);
        float aw = a2 - a0, ah = a3 - a1;
        float acx = a0 + 0.5f * aw, acy = a1 + 0.5f * ah;
        size_t db = ((size_t)img * m + idx) * 4;
        float dx = dl[db], dy = dl[db + 1], dwv = dl[db + 2], dhv = dl[db + 3];
        const float CL = 4.135166556742356f;   // log(1000/16)
        float pw = expf(fminf(dwv, CL)) * aw;
        float ph = expf(fminf(dhv, CL)) * ah;
        float pcx = dx * aw + acx;
        float pcy = dy * ah + acy;
        x0 = pcx - 0.5f * pw; y0 = pcy - 0.5f * ph;
        x1 = pcx + 0.5f * pw; y1 = pcy + 0.5f * ph;
        x0 = fminf(fmaxf(x0, 0.f), 2048.f);
        x1 = fminf(fmaxf(x1, 0.f), 2048.f);
        y0 = fminf(fmaxf(y0, 0.f), 1344.f);
        y1 = fminf(fmaxf(y1, 0.f), 1344.f);
        bool keep = ((x1 - x0) > 0.f) && ((y1 - y0) > 0.f);
        valid = keep;
        sm = score;
        float off = (float)lvl * 2049.0f;
        b0 = x0 + off; b1 = y0 + off; b2 = x1 + off; b3 = y1 + off;
    }
    // block prefix scan over valid flags (Hillis-Steele, ping-pong in bnd region)
    int* sc1 = (int*)bnd;
    int* sc2 = sc1 + 1024;
    sc1[tid] = valid ? 1 : 0;
    __syncthreads();
    int* sA = sc1; int* sB = sc2;
    for (int dd = 1; dd < 1024; dd <<= 1) {
        int v = sA[tid];
        if (tid >= dd) v += sA[tid - dd];
        sB[tid] = v;
        __syncthreads();
        int* t2 = sA; sA = sB; sB = t2;
    }
    int incl  = sA[tid];
    int total = sA[1023];
    int pos   = incl - (valid ? 1 : 0);
    if (valid) {
        int ci = img * NCAND + lvl * K_TOP + pos;
        cscore[ci] = sm;
        cbox[ci]   = make_float4(x0, y0, x1, y1);
        cobox[ci]  = make_float4(b0, b1, b2, b3);
        cog[ci]    = (unsigned)r;
    }
    if (tid == 0) vcnt[task] = (unsigned)total;
}

// ---------------- pass 5a: rank-merge, 1 block per (img,lvl), scatter to global ----
__global__ __launch_bounds__(1024) void kMergeRank(
        const float* __restrict__ cscore,
        const float4* __restrict__ cobox,
        const unsigned* __restrict__ cog,
        const unsigned* __restrict__ vcnt,
        float4* __restrict__ mobG,
        unsigned* __restrict__ midxG) {
    int task = blockIdx.x;
    int img = task / NLVL, lvl = task % NLVL;
    int tid = threadIdx.x;
    const int imgb = img * NCAND;
    __shared__ u64 compO[4 * K_TOP];    // other 4 levels' composites (32 KB)
    __shared__ int LSs[NLVL];
    if (tid < NLVL) LSs[tid] = (int)vcnt[img * NLVL + tid];
    __syncthreads();
    for (int idx = tid; idx < 4 * K_TOP; idx += 1024) {
        int q = idx / K_TOP, gl2 = idx - q * K_TOP;
        int l2 = q + (q >= lvl ? 1 : 0);
        u64 c = 0ULL;
        if (gl2 < LSs[l2]) {
            int g2 = l2 * K_TOP + gl2;
            unsigned og = (unsigned)(l2 * K_TOP) + cog[imgb + g2];
            c = ((u64)key_of(cscore[imgb + g2]) << 32) | (unsigned)(~og);
        }
        compO[idx] = c;
    }
    __syncthreads();
    int gl = tid;
    if (gl < LSs[lvl]) {
        int g = lvl * K_TOP + gl;
        float4 pref = cobox[imgb + g];             // overlap HBM with LDS searches
        unsigned og = (unsigned)(lvl * K_TOP) + cog[imgb + g];
        u64 c = ((u64)key_of(cscore[imgb + g]) << 32) | (unsigned)(~og);
        int h0v = LSs[0 + (0 >= lvl ? 1 : 0)];
        int h1v = LSs[1 + (1 >= lvl ? 1 : 0)];
        int h2v = LSs[2 + (2 >= lvl ? 1 : 0)];
        int h3v = LSs[3 + (3 >= lvl ? 1 : 0)];
        int l0 = 0, h0 = h0v;
        int l1 = 0, h1 = h1v;
        int l2 = 0, h2 = h2v;
        int l3 = 0, h3 = h3v;
#pragma unroll
        for (int step = 0; step < 10; ++step) {    // lists <= 1000 -> 10 steps
            if (l0 < h0) { int m0 = (l0 + h0) >> 1; if (compO[0 * K_TOP + m0] > c) l0 = m0 + 1; else h0 = m0; }
            if (l1 < h1) { int m1 = (l1 + h1) >> 1; if (compO[1 * K_TOP + m1] > c) l1 = m1 + 1; else h1 = m1; }
            if (l2 < h2) { int m2 = (l2 + h2) >> 1; if (compO[2 * K_TOP + m2] > c) l2 = m2 + 1; else h2 = m2; }
            if (l3 < h3) { int m3 = (l3 + h3) >> 1; if (compO[3 * K_TOP + m3] > c) l3 = m3 + 1; else h3 = m3; }
        }
        int pos = gl + l0 + l1 + l2 + l3;
        mobG[(size_t)img * NPAD + pos] = pref;
        midxG[imgb + pos] = (unsigned)g;
    }
}

// ---------------- pass 5b: greedy scan, words staged on demand, ballot serial ----
__global__ __launch_bounds__(1024) void kScan(
        const float4* __restrict__ mobG,
        const unsigned* __restrict__ midxG,
        const float* __restrict__ cscore,
        const float4* __restrict__ cbox,
        const unsigned* __restrict__ vcnt,
        float* __restrict__ out) {
    int img = blockIdx.x;
    int tid = threadIdx.x;
    int lane = tid & 63;
    int wave = tid >> 6;
    __shared__ float4 wboxS[64];
    __shared__ u64    diagWS[64];
    __shared__ u64    partS[16];
    __shared__ float4 pboxAll[NPOST];
    __shared__ unsigned emS[NPOST];
    __shared__ int stateS[2];           // {emitted, done}
    const int imgb = img * NCAND;

    int V = 0;
    for (int l = 0; l < NLVL; ++l) V += (int)vcnt[img * NLVL + l];

    int emitted = 0;
    bool done = (V == 0);
    for (int w = 0; w < NWORDS && !done; ++w) {
        int base = w * 64;
        if (base >= V) break;
        if (tid < 64) wboxS[tid] = mobG[(size_t)img * NPAD + base + tid];
        __syncthreads();
        // parallel phase (all 16 waves): suppression-by-emitted + own diag block
        float4 bc = wboxS[lane];
        float  arc = (bc.z - bc.x) * (bc.w - bc.y);
        bool supp = false;
        for (int t = wave; t < emitted; t += 16) {
            float4 bp = pboxAll[t];
            float arp = (bp.z - bp.x) * (bp.w - bp.y);
            float ltx = fmaxf(bc.x, bp.x), lty = fmaxf(bc.y, bp.y);
            float rbx = fminf(bc.z, bp.z), rby = fminf(bc.w, bp.w);
            float wx = fmaxf(rbx - ltx, 0.f), wy = fmaxf(rby - lty, 0.f);
            float inter = wx * wy;
            float denom = (arc + arp) - inter + 1e-9f;
            supp |= (inter / denom) > 0.7f;
        }
        u64 sb = __ballot(supp);
        if (lane == 0) partS[wave] = sb;
#pragma unroll
        for (int rr = 0; rr < 4; ++rr) {
            int r = wave * 4 + rr;
            float4 bp = wboxS[r];
            float arp = (bp.z - bp.x) * (bp.w - bp.y);
            float ltx = fmaxf(bc.x, bp.x), lty = fmaxf(bc.y, bp.y);
            float rbx = fminf(bc.z, bp.z), rby = fminf(bc.w, bp.w);
            float wx = fmaxf(rbx - ltx, 0.f), wy = fmaxf(rby - lty, 0.f);
            float inter = wx * wy;
            float denom = (arc + arp) - inter + 1e-9f;
            bool pred = (inter / denom) > 0.7f;
            u64 db = __ballot(pred);
            if (lane == 0) diagWS[r] = db;
        }
        __syncthreads();
        // serial phase: wave 0; diag row b reconstructed by symmetry via ballot
        if (wave == 0) {
            u64 dreg = diagWS[lane];           // lane's own row (symmetric matrix)
            u64 smv = partS[0];
#pragma unroll
            for (int q = 1; q < 16; ++q) smv |= partS[q];
            int rem = V - base;
            u64 vmask = (rem >= 64) ? ~0ULL : ((1ULL << rem) - 1ULL);
            u64 cur = (~smv) & vmask;
            int em = emitted;
            int dn = 0;
            u64 embits = 0ULL;
            while (cur) {
                int b = __builtin_ctzll(cur);
                embits |= 1ULL << b;
                ++em;
                if (em == NPOST) { dn = 1; break; }
                u64 row = __ballot((dreg >> b) & 1ULL);   // row[b] via symmetry
                cur &= ~row;
                cur &= ~(1ULL << b);
            }
            // parallel write-back: pops were in ascending bit order
            if ((embits >> lane) & 1ULL) {
                int rank = __popcll(embits & ((1ULL << lane) - 1ULL));
                emS[emitted + rank]     = (unsigned)(base + lane);
                pboxAll[emitted + rank] = wboxS[lane];
            }
            if (lane == 0) { stateS[0] = em; stateS[1] = dn; }
        }
        __syncthreads();
        emitted = stateS[0];
        done = (stateS[1] != 0);
    }
    __syncthreads();
    // ---- parallel output gather ----
    for (int rr = tid; rr < NPOST; rr += 1024) {
        float* o = out + ((size_t)img * NPOST + rr) * 5;
        if (rr < emitted) {
            unsigned i = emS[rr];
            unsigned g = midxG[imgb + i];
            float4 cb = cbox[imgb + g];
            float sc = cscore[imgb + g];
            o[0] = cb.x; o[1] = cb.y; o[2] = cb.z; o[3] = cb.w; o[4] = sc;
        } else {
            o[0] = 0.f; o[1] = 0.f; o[2] = 0.f; o[3] = 0.f; o[4] = NEGF;
        }
    }
}

extern "C" void kernel_launch(void* const* d_in, const int* in_sizes, int n_in,
                              void* d_out, int out_size, void* d_ws, size_t ws_size,
                              hipStream_t stream) {
    Ptrs P;
    for (int l = 0; l < 5; ++l) {
        P.lg[l] = (const float*)d_in[2 * l];
        P.dl[l] = (const float*)d_in[2 * l + 1];
    }
    char* w = (char*)d_ws;
    size_t off = 0;
    auto alloc = [&](size_t bytes) -> void* {
        void* pp = (void*)(w + off);
        off = (off + bytes + 255) & ~(size_t)255;
        return pp;
    };
    unsigned* hist  = (unsigned*)alloc((size_t)NTASK * NB1 * 4);
    unsigned* tinfo = (unsigned*)alloc(NTASK * 2 * 4);
    unsigned* cnt   = (unsigned*)alloc(NTASK * 4);
    u64* compb      = (u64*)alloc((size_t)NTASK * CAP * 8);
    float*  cscore  = (float*)alloc((size_t)NTASK * K_TOP * 4);
    float4* cbox    = (float4*)alloc((size_t)NTASK * K_TOP * 16);
    float4* cobox   = (float4*)alloc((size_t)NTASK * K_TOP * 16);
    unsigned* cog   = (unsigned*)alloc((size_t)NTASK * K_TOP * 4);
    unsigned* vcnt  = (unsigned*)alloc(NTASK * 4);
    float4* mobG    = (float4*)alloc((size_t)NIMG * NPAD * 16);
    unsigned* midxG = (unsigned*)alloc((size_t)NIMG * NCAND * 4);
    (void)in_sizes; (void)n_in; (void)out_size; (void)ws_size;

    hipMemsetAsync(hist, 0, (size_t)NTASK * NB1 * 4, stream);
    kHistAll<<<dim3(23, NIMG), 1024, 0, stream>>>(P, hist);
    kSelectBin<<<NTASK, 256, 0, stream>>>(hist, tinfo, cnt);
    kCompactAll<<<dim3(44, NIMG), 1024, 0, stream>>>(P, tinfo, cnt, compb);
    kSortSelect<<<NTASK, 1024, 0, stream>>>(P, cnt, tinfo, compb,
                                            cscore, cbox, cobox, cog, vcnt);
    kMergeRank<<<NTASK, 1024, 0, stream>>>(cscore, cobox, cog, vcnt, mobG, midxG);
    kScan<<<NIMG, 1024, 0, stream>>>(mobG, midxG, cscore, cbox, vcnt,
                                     (float*)d_out);
}

// Round 17
// 84.134 us; speedup vs baseline: 8.5719x; 1.3176x over previous
//
#include <hip/hip_runtime.h>
#include <cstdint>
#include <cstddef>

#define NB1      16384      // 2^14 first-level radix bins
#define L1SHIFT  18         // key >> 18 -> 14-bit bin
#define CAP      4096       // compaction buffer per task
#define K_TOP    1000
#define NCAND    5000
#define NIMG     8
#define NLVL     5
#define NTASK    40
#define NPOST    300
#define NEGF     (-1e9f)
#define NWORDS   79         // ceil(5000/64)
#define NPAD     (NWORDS * 64)   // 5056, padded candidate count

typedef unsigned long long u64;

struct Ptrs {
    const float* lg[5];
    const float* dl[5];
};

__device__ __forceinline__ unsigned key_of(float f) {
    unsigned u = __float_as_uint(f);
    return (u & 0x80000000u) ? ~u : (u | 0x80000000u);
}

// ---------------- pass 1: all-level LDS-privatized histogram (1 dispatch) ----------------
__global__ __launch_bounds__(1024) void kHistAll(Ptrs p, unsigned* __restrict__ hist) {
    int bx = blockIdx.x;
    int lvl = (bx < 16) ? 0 : (bx < 20) ? 1 : (bx < 21) ? 2 : (bx < 22) ? 3 : 4;
    int lb  = bx - ((lvl == 0) ? 0 : (lvl == 1) ? 16 : (lvl == 2) ? 20 : (lvl == 3) ? 21 : 22);
    int gx  = (lvl == 0) ? 16 : (lvl == 1) ? 4 : 1;
    int m   = (lvl == 0) ? 516096 : (lvl == 1) ? 129024 : (lvl == 2) ? 32256
              : (lvl == 3) ? 8064 : 2016;
    int img  = blockIdx.y;
    int task = img * NLVL + lvl;
    const float* lg = p.lg[lvl];
    __shared__ unsigned h[NB1];
    for (int i = threadIdx.x; i < NB1; i += 1024) h[i] = 0u;
    __syncthreads();
    int m4 = m >> 2;
    int chunk4 = (m4 + gx - 1) / gx;
    int start4 = lb * chunk4;
    int end4   = min(start4 + chunk4, m4);
    const float4* src = (const float4*)(lg + (size_t)img * m);
    for (int i = start4 + threadIdx.x; i < end4; i += 1024) {
        float4 v = src[i];
        atomicAdd(&h[key_of(v.x) >> L1SHIFT], 1u);
        atomicAdd(&h[key_of(v.y) >> L1SHIFT], 1u);
        atomicAdd(&h[key_of(v.z) >> L1SHIFT], 1u);
        atomicAdd(&h[key_of(v.w) >> L1SHIFT], 1u);
    }
    __syncthreads();
    unsigned* gh = hist + (size_t)task * NB1;
    for (int i = threadIdx.x; i < NB1; i += 1024) {
        unsigned c = h[i];
        if (c) atomicAdd(&gh[i], c);
    }
}

// ---------------- pass 2: find 14-bit prefix of the K-th largest ----------------
__global__ __launch_bounds__(256) void kSelectBin(const unsigned* __restrict__ hist,
                                                  unsigned* __restrict__ tinfo,
                                                  unsigned* __restrict__ cnt) {
    int task = blockIdx.x;
    const unsigned* h = hist + (size_t)task * NB1;
    __shared__ unsigned sblk[256];
    __shared__ unsigned sbin[64];
    __shared__ int sh_tb;
    __shared__ unsigned sh_rem;
    int t = threadIdx.x;
    unsigned s = 0;
    for (int i = 0; i < 64; ++i) s += h[t * 64 + i];
    sblk[t] = s;
    __syncthreads();
    if (t == 0) {
        unsigned rem = K_TOP; int tb = 0;
        for (int b = 255; b >= 0; --b) {
            if (sblk[b] < rem) rem -= sblk[b];
            else { tb = b; break; }
        }
        sh_tb = tb; sh_rem = rem;
    }
    __syncthreads();
    if (t < 64) sbin[t] = h[sh_tb * 64 + t];
    __syncthreads();
    if (t == 0) {
        unsigned rem = sh_rem; int pfx = sh_tb * 64;
        for (int b = 63; b >= 0; --b) {
            if (sbin[b] < rem) rem -= sbin[b];
            else { pfx = sh_tb * 64 + b; break; }
        }
        tinfo[task * 2]     = (unsigned)pfx;
        tinfo[task * 2 + 1] = rem;
        cnt[task] = 0u;
    }
}

// ---------------- pass 3: all-level compact (1 dispatch) ----------------
__global__ __launch_bounds__(1024) void kCompactAll(Ptrs p,
                                                    const unsigned* __restrict__ tinfo,
                                                    unsigned* __restrict__ cnt,
                                                    u64* __restrict__ compbuf) {
    int bx = blockIdx.x;
    int lvl = (bx < 32) ? 0 : (bx < 40) ? 1 : (bx < 42) ? 2 : (bx < 43) ? 3 : 4;
    int lb  = bx - ((lvl == 0) ? 0 : (lvl == 1) ? 32 : (lvl == 2) ? 40 : (lvl == 3) ? 42 : 43);
    int gx  = (lvl == 0) ? 32 : (lvl == 1) ? 8 : (lvl == 2) ? 2 : 1;
    int m   = (lvl == 0) ? 516096 : (lvl == 1) ? 129024 : (lvl == 2) ? 32256
              : (lvl == 3) ? 8064 : 2016;
    int img  = blockIdx.y;
    int task = img * NLVL + lvl;
    const float* lg = p.lg[lvl];
    unsigned pfx = tinfo[task * 2];
    __shared__ u64 stage[CAP];
    __shared__ unsigned lcnt, gbase;
    if (threadIdx.x == 0) lcnt = 0u;
    __syncthreads();
    int m4 = m >> 2;
    int chunk4 = (m4 + gx - 1) / gx;
    int start4 = lb * chunk4;
    int end4   = min(start4 + chunk4, m4);
    const float4* src = (const float4*)(lg + (size_t)img * m);
    for (int i = start4 + threadIdx.x; i < end4; i += 1024) {
        float4 v = src[i];
        int j = i * 4;
        unsigned k0 = key_of(v.x);
        unsigned k1 = key_of(v.y);
        unsigned k2 = key_of(v.z);
        unsigned k3 = key_of(v.w);
        if ((k0 >> L1SHIFT) >= pfx) {
            unsigned q = atomicAdd(&lcnt, 1u);
            if (q < CAP) stage[q] = ((u64)k0 << 32) | (unsigned)(~(unsigned)(j));
        }
        if ((k1 >> L1SHIFT) >= pfx) {
            unsigned q = atomicAdd(&lcnt, 1u);
            if (q < CAP) stage[q] = ((u64)k1 << 32) | (unsigned)(~(unsigned)(j + 1));
        }
        if ((k2 >> L1SHIFT) >= pfx) {
            unsigned q = atomicAdd(&lcnt, 1u);
            if (q < CAP) stage[q] = ((u64)k2 << 32) | (unsigned)(~(unsigned)(j + 2));
        }
        if ((k3 >> L1SHIFT) >= pfx) {
            unsigned q = atomicAdd(&lcnt, 1u);
            if (q < CAP) stage[q] = ((u64)k3 << 32) | (unsigned)(~(unsigned)(j + 3));
        }
    }
    __syncthreads();
    if (threadIdx.x == 0) gbase = atomicAdd(&cnt[task], lcnt);
    __syncthreads();
    unsigned total = min(lcnt, (unsigned)CAP);
    unsigned base  = gbase;
    for (unsigned q = threadIdx.x; q < total; q += 1024) {
        unsigned pos = base + q;
        if (pos < CAP) compbuf[(size_t)task * CAP + pos] = stage[q];
    }
}

// ---------------- pass 4: split-sort (sure/boundary), decode, valid-compact ----
__global__ __launch_bounds__(1024) void kSortSelect(
        Ptrs p,
        const unsigned* __restrict__ cnt,
        const unsigned* __restrict__ tinfo,
        const u64* __restrict__ compbuf,
        float* __restrict__ cscore,
        float4* __restrict__ cbox,
        float4* __restrict__ cobox,
        unsigned* __restrict__ cog,
        unsigned* __restrict__ vcnt) {
    int task = blockIdx.x;
    int img = task / NLVL, lvl = task % NLVL;
    int tid = threadIdx.x;
    __shared__ u64 sure[1024];
    __shared__ u64 bnd[2048];
    __shared__ unsigned cS, cB;
    if (tid == 0) { cS = 0u; cB = 0u; }
    sure[tid] = 0ULL;
    bnd[tid] = 0ULL; bnd[tid + 1024] = 0ULL;
    __syncthreads();
    int n = min((int)cnt[task], CAP);
    unsigned pfx = tinfo[task * 2];
    for (int i = tid; i < n; i += 1024) {
        u64 c = compbuf[(size_t)task * CAP + i];
        unsigned bin = (unsigned)(c >> (32 + L1SHIFT));
        if (bin > pfx) {
            unsigned q = atomicAdd(&cS, 1u);
            if (q < 1024) sure[q] = c;
        } else {
            unsigned q = atomicAdd(&cB, 1u);
            if (q < 2048) bnd[q] = c;
        }
    }
    __syncthreads();
    unsigned S = cS;
    unsigned B = cB;
    {
        u64* arr = (tid < 512) ? sure : bnd;
        int q = tid & 511;
        for (int k = 2; k <= 1024; k <<= 1) {
            for (int j = k >> 1; j > 0; j >>= 1) {
                int i = ((q & ~(j - 1)) << 1) | (q & (j - 1));
                int pp = i | j;
                u64 A = arr[i], Bv = arr[pp];
                bool up = ((i & k) == 0);
                if (up ? (A < Bv) : (A > Bv)) { arr[i] = Bv; arr[pp] = A; }
                __syncthreads();
            }
        }
    }
    if (B > 1024) {    // statistically never; full 2048 network re-sorts bnd
        for (int k = 2; k <= 2048; k <<= 1)
            for (int j = k >> 1; j > 0; j >>= 1) {
                int i = ((tid & ~(j - 1)) << 1) | (tid & (j - 1));
                int pp = i | j;
                u64 A = bnd[i], Bv = bnd[pp];
                bool up = ((i & k) == 0);
                if (up ? (A < Bv) : (A > Bv)) { bnd[i] = Bv; bnd[pp] = A; }
                __syncthreads();
            }
    }
    int r = tid;
    u64 c = 0ULL;
    if (r < K_TOP) c = (r < (int)S) ? sure[r] : ((r - (int)S < (int)B) ? bnd[r - (int)S] : 0ULL);
    __syncthreads();                 // all sure/bnd reads done (bnd reused for scan)

    const int   MS[5]     = {516096, 129024, 32256, 8064, 2016};
    const int   GW[5]     = {512, 256, 128, 64, 32};
    const float STRIDEF[5]= {4.f, 8.f, 16.f, 32.f, 64.f};
    const int   SIZEI[5]  = {32, 64, 128, 256, 512};
    float sm = NEGF, x0 = 0.f, y0 = 0.f, x1 = 0.f, y1 = 0.f;
    float b0 = 0.f, b1 = 0.f, b2 = 0.f, b3 = 0.f;
    bool valid = false;
    if (r < K_TOP) {
        int idx = (int)(~(unsigned)c);
        int m = MS[lvl];
        if ((unsigned)idx >= (unsigned)m) idx = 0;   // safety (never expected)
        const float* lg = p.lg[lvl];
        const float* dl = p.dl[lvl];
        float score = lg[(size_t)img * m + idx];
        int a   = idx % 3;
        int loc = idx / 3;
        int gw  = GW[lvl];
        int x = loc % gw, y = loc / gw;
        double ssz = (double)SIZEI[lvl];
        double arr = (a == 0) ? 0.5 : ((a == 1) ? 1.0 : 2.0);
        double wd = sqrt(ssz * ssz / arr);
        double hd = arr * wd;
        float sx = (float)x * STRIDEF[lvl];
        float sy = (float)y * STRIDEF[lvl];
        float a0 = sx + (float)(-wd * 0.5);
        float a1 = sy + (float)(-hd * 0.5);
        float a2 = sx + (float)( wd * 0.5);
        float a3 = sy + (float)( hd * 0.5);
        float aw = a2 - a0, ah = a3 - a1;
        float acx = a0 + 0.5f * aw, acy = a1 + 0.5f * ah;
        size_t db = ((size_t)img * m + idx) * 4;
        float dx = dl[db], dy = dl[db + 1], dwv = dl[db + 2], dhv = dl[db + 3];
        const float CL = 4.135166556742356f;   // log(1000/16)
        float pw = expf(fminf(dwv, CL)) * aw;
        float ph = expf(fminf(dhv, CL)) * ah;
        float pcx = dx * aw + acx;
        float pcy = dy * ah + acy;
        x0 = pcx - 0.5f * pw; y0 = pcy - 0.5f * ph;
        x1 = pcx + 0.5f * pw; y1 = pcy + 0.5f * ph;
        x0 = fminf(fmaxf(x0, 0.f), 2048.f);
        x1 = fminf(fmaxf(x1, 0.f), 2048.f);
        y0 = fminf(fmaxf(y0, 0.f), 1344.f);
        y1 = fminf(fmaxf(y1, 0.f), 1344.f);
        bool keep = ((x1 - x0) > 0.f) && ((y1 - y0) > 0.f);
        valid = keep;
        sm = score;
        float off = (float)lvl * 2049.0f;
        b0 = x0 + off; b1 = y0 + off; b2 = x1 + off; b3 = y1 + off;
    }
    // block prefix scan over valid flags (Hillis-Steele, ping-pong in bnd region)
    int* sc1 = (int*)bnd;
    int* sc2 = sc1 + 1024;
    sc1[tid] = valid ? 1 : 0;
    __syncthreads();
    int* sA = sc1; int* sB = sc2;
    for (int dd = 1; dd < 1024; dd <<= 1) {
        int v = sA[tid];
        if (tid >= dd) v += sA[tid - dd];
        sB[tid] = v;
        __syncthreads();
        int* t2 = sA; sA = sB; sB = t2;
    }
    int incl  = sA[tid];
    int total = sA[1023];
    int pos   = incl - (valid ? 1 : 0);
    if (valid) {
        int ci = img * NCAND + lvl * K_TOP + pos;
        cscore[ci] = sm;
        cbox[ci]   = make_float4(x0, y0, x1, y1);
        cobox[ci]  = make_float4(b0, b1, b2, b3);
        cog[ci]    = (unsigned)r;
    }
    if (tid == 0) vcnt[task] = (unsigned)total;
}

// ---------------- pass 5a: rank-merge, 1 block per (img,lvl), scatter to global ----
__global__ __launch_bounds__(1024) void kMergeRank(
        const float* __restrict__ cscore,
        const float4* __restrict__ cobox,
        const unsigned* __restrict__ cog,
        const unsigned* __restrict__ vcnt,
        float4* __restrict__ mobG,
        unsigned* __restrict__ midxG) {
    int task = blockIdx.x;
    int img = task / NLVL, lvl = task % NLVL;
    int tid = threadIdx.x;
    const int imgb = img * NCAND;
    __shared__ u64 compO[4 * K_TOP];    // other 4 levels' composites (32 KB)
    __shared__ int LSs[NLVL];
    if (tid < NLVL) LSs[tid] = (int)vcnt[img * NLVL + tid];
    __syncthreads();
    for (int idx = tid; idx < 4 * K_TOP; idx += 1024) {
        int q = idx / K_TOP, gl2 = idx - q * K_TOP;
        int l2 = q + (q >= lvl ? 1 : 0);
        u64 c = 0ULL;
        if (gl2 < LSs[l2]) {
            int g2 = l2 * K_TOP + gl2;
            unsigned og = (unsigned)(l2 * K_TOP) + cog[imgb + g2];
            c = ((u64)key_of(cscore[imgb + g2]) << 32) | (unsigned)(~og);
        }
        compO[idx] = c;
    }
    __syncthreads();
    int gl = tid;
    if (gl < LSs[lvl]) {
        int g = lvl * K_TOP + gl;
        float4 pref = cobox[imgb + g];             // overlap HBM with LDS searches
        unsigned og = (unsigned)(lvl * K_TOP) + cog[imgb + g];
        u64 c = ((u64)key_of(cscore[imgb + g]) << 32) | (unsigned)(~og);
        int h0v = LSs[0 + (0 >= lvl ? 1 : 0)];
        int h1v = LSs[1 + (1 >= lvl ? 1 : 0)];
        int h2v = LSs[2 + (2 >= lvl ? 1 : 0)];
        int h3v = LSs[3 + (3 >= lvl ? 1 : 0)];
        int l0 = 0, h0 = h0v;
        int l1 = 0, h1 = h1v;
        int l2 = 0, h2 = h2v;
        int l3 = 0, h3 = h3v;
#pragma unroll
        for (int step = 0; step < 10; ++step) {    // lists <= 1000 -> 10 steps
            if (l0 < h0) { int m0 = (l0 + h0) >> 1; if (compO[0 * K_TOP + m0] > c) l0 = m0 + 1; else h0 = m0; }
            if (l1 < h1) { int m1 = (l1 + h1) >> 1; if (compO[1 * K_TOP + m1] > c) l1 = m1 + 1; else h1 = m1; }
            if (l2 < h2) { int m2 = (l2 + h2) >> 1; if (compO[2 * K_TOP + m2] > c) l2 = m2 + 1; else h2 = m2; }
            if (l3 < h3) { int m3 = (l3 + h3) >> 1; if (compO[3 * K_TOP + m3] > c) l3 = m3 + 1; else h3 = m3; }
        }
        int pos = gl + l0 + l1 + l2 + l3;
        mobG[(size_t)img * NPAD + pos] = pref;
        midxG[imgb + pos] = (unsigned)g;
    }
}

// ---------------- pass 5b: greedy scan; within-word selection via MIS fixpoint ----------------
// Greedy-within-word = lexicographically-first MIS = unique fixpoint of
//   S = { j in A : dreg_j & S & below_j == 0 }   (dreg symmetric adjacency)
// iterated wave-parallel from S=A (converges in <= chain-depth ballots).
__global__ __launch_bounds__(1024) void kScan(
        const float4* __restrict__ mobG,
        const unsigned* __restrict__ midxG,
        const float* __restrict__ cscore,
        const float4* __restrict__ cbox,
        const unsigned* __restrict__ vcnt,
        float* __restrict__ out) {
    int img = blockIdx.x;
    int tid = threadIdx.x;
    int lane = tid & 63;
    int wave = tid >> 6;
    __shared__ float4 wboxS[2][64];     // double buffer (prefetch during serial)
    __shared__ u64    diagWS[64];
    __shared__ u64    partS[16];
    __shared__ float4 pboxAll[NPOST];
    __shared__ unsigned emS[NPOST];
    __shared__ int stateS[2];           // {emitted, done}
    const int imgb = img * NCAND;

    int V = 0;
    for (int l = 0; l < NLVL; ++l) V += (int)vcnt[img * NLVL + l];

    // prologue: stage word 0
    if (tid < 64 && V > 0) wboxS[0][tid] = mobG[(size_t)img * NPAD + tid];
    __syncthreads();

    int emitted = 0;
    bool done = (V == 0);
    for (int w = 0; w < NWORDS && !done; ++w) {
        int base = w * 64;
        if (base >= V) break;
        int buf = w & 1;
        // parallel phase (all 16 waves): suppression-by-emitted + own diag block
        float4 bc = wboxS[buf][lane];
        float  arc = (bc.z - bc.x) * (bc.w - bc.y);
        bool supp = false;
        for (int t = wave; t < emitted; t += 16) {
            float4 bp = pboxAll[t];
            float arp = (bp.z - bp.x) * (bp.w - bp.y);
            float ltx = fmaxf(bc.x, bp.x), lty = fmaxf(bc.y, bp.y);
            float rbx = fminf(bc.z, bp.z), rby = fminf(bc.w, bp.w);
            float wx = fmaxf(rbx - ltx, 0.f), wy = fmaxf(rby - lty, 0.f);
            float inter = wx * wy;
            float denom = (arc + arp) - inter + 1e-9f;
            supp |= (inter / denom) > 0.7f;
        }
        u64 sb = __ballot(supp);
        if (lane == 0) partS[wave] = sb;
#pragma unroll
        for (int rr = 0; rr < 4; ++rr) {
            int r = wave * 4 + rr;
            float4 bp = wboxS[buf][r];
            float arp = (bp.z - bp.x) * (bp.w - bp.y);
            float ltx = fmaxf(bc.x, bp.x), lty = fmaxf(bc.y, bp.y);
            float rbx = fminf(bc.z, bp.z), rby = fminf(bc.w, bp.w);
            float wx = fmaxf(rbx - ltx, 0.f), wy = fmaxf(rby - lty, 0.f);
            float inter = wx * wy;
            float denom = (arc + arp) - inter + 1e-9f;
            bool pred = (inter / denom) > 0.7f;
            u64 db = __ballot(pred);
            if (lane == 0) diagWS[r] = db;
        }
        __syncthreads();
        // wave 0: MIS fixpoint; wave 15: prefetch next word into other buffer
        if (wave == 0) {
            u64 dreg = diagWS[lane];           // lane's own adjacency row
            u64 smv = partS[0];
#pragma unroll
            for (int q = 1; q < 16; ++q) smv |= partS[q];
            int rem = V - base;
            u64 vmask = (rem >= 64) ? ~0ULL : ((1ULL << rem) - 1ULL);
            u64 A = (~smv) & vmask;
            u64 below = (1ULL << lane) - 1ULL;
            bool inA = (A >> lane) & 1ULL;
            u64 S = A;
            while (true) {
                bool pred = inA && ((dreg & S & below) == 0ULL);
                u64 Snew = __ballot(pred);
                if (Snew == S) break;
                S = Snew;
            }
            int cnt = __popcll(S);
            int rem0 = NPOST - emitted;
            int rank = __popcll(S & below);
            bool kept = ((S >> lane) & 1ULL) && (rank < rem0);
            if (kept) {
                emS[emitted + rank]     = (unsigned)(base + lane);
                pboxAll[emitted + rank] = wboxS[buf][lane];
            }
            if (lane == 0) {
                int emadd = (cnt < rem0) ? cnt : rem0;
                stateS[0] = emitted + emadd;
                stateS[1] = (cnt >= rem0) ? 1 : 0;
            }
        } else if (wave == 15) {
            int nb = base + 64;
            if (nb < V && (w + 1) < NWORDS)
                wboxS[buf ^ 1][lane] = mobG[(size_t)img * NPAD + nb + lane];
        }
        __syncthreads();
        emitted = stateS[0];
        done = (stateS[1] != 0);
    }
    __syncthreads();
    // ---- parallel output gather ----
    for (int rr = tid; rr < NPOST; rr += 1024) {
        float* o = out + ((size_t)img * NPOST + rr) * 5;
        if (rr < emitted) {
            unsigned i = emS[rr];
            unsigned g = midxG[imgb + i];
            float4 cb = cbox[imgb + g];
            float sc = cscore[imgb + g];
            o[0] = cb.x; o[1] = cb.y; o[2] = cb.z; o[3] = cb.w; o[4] = sc;
        } else {
            o[0] = 0.f; o[1] = 0.f; o[2] = 0.f; o[3] = 0.f; o[4] = NEGF;
        }
    }
}

extern "C" void kernel_launch(void* const* d_in, const int* in_sizes, int n_in,
                              void* d_out, int out_size, void* d_ws, size_t ws_size,
                              hipStream_t stream) {
    Ptrs P;
    for (int l = 0; l < 5; ++l) {
        P.lg[l] = (const float*)d_in[2 * l];
        P.dl[l] = (const float*)d_in[2 * l + 1];
    }
    char* w = (char*)d_ws;
    size_t off = 0;
    auto alloc = [&](size_t bytes) -> void* {
        void* pp = (void*)(w + off);
        off = (off + bytes + 255) & ~(size_t)255;
        return pp;
    };
    unsigned* hist  = (unsigned*)alloc((size_t)NTASK * NB1 * 4);
    unsigned* tinfo = (unsigned*)alloc(NTASK * 2 * 4);
    unsigned* cnt   = (unsigned*)alloc(NTASK * 4);
    u64* compb      = (u64*)alloc((size_t)NTASK * CAP * 8);
    float*  cscore  = (float*)alloc((size_t)NTASK * K_TOP * 4);
    float4* cbox    = (float4*)alloc((size_t)NTASK * K_TOP * 16);
    float4* cobox   = (float4*)alloc((size_t)NTASK * K_TOP * 16);
    unsigned* cog   = (unsigned*)alloc((size_t)NTASK * K_TOP * 4);
    unsigned* vcnt  = (unsigned*)alloc(NTASK * 4);
    float4* mobG    = (float4*)alloc((size_t)NIMG * NPAD * 16);
    unsigned* midxG = (unsigned*)alloc((size_t)NIMG * NCAND * 4);
    (void)in_sizes; (void)n_in; (void)out_size; (void)ws_size;

    hipMemsetAsync(hist, 0, (size_t)NTASK * NB1 * 4, stream);
    kHistAll<<<dim3(23, NIMG), 1024, 0, stream>>>(P, hist);
    kSelectBin<<<NTASK, 256, 0, stream>>>(hist, tinfo, cnt);
    kCompactAll<<<dim3(44, NIMG), 1024, 0, stream>>>(P, tinfo, cnt, compb);
    kSortSelect<<<NTASK, 1024, 0, stream>>>(P, cnt, tinfo, compb,
                                            cscore, cbox, cobox, cog, vcnt);
    kMergeRank<<<NTASK, 1024, 0, stream>>>(cscore, cobox, cog, vcnt, mobG, midxG);
    kScan<<<NIMG, 1024, 0, stream>>>(mobG, midxG, cscore, cbox, vcnt,
                                     (float*)d_out);
}

// Round 18
// 83.827 us; speedup vs baseline: 8.6033x; 1.0037x over previous
//
#include <hip/hip_runtime.h>
#include <cstdint>
#include <cstddef>

#define NB1      16384      // 2^14 first-level radix bins
#define L1SHIFT  18         // key >> 18 -> 14-bit bin
#define CAP      4096       // compaction buffer per task
#define K_TOP    1000
#define NCAND    5000
#define NIMG     8
#define NLVL     5
#define NTASK    40
#define NPOST    300
#define NEGF     (-1e9f)
#define NWORDS   79         // ceil(5000/64)
#define NPAD     (NWORDS * 64)   // 5056, padded candidate count

typedef unsigned long long u64;

struct Ptrs {
    const float* lg[5];
    const float* dl[5];
};

__device__ __forceinline__ unsigned key_of(float f) {
    unsigned u = __float_as_uint(f);
    return (u & 0x80000000u) ? ~u : (u | 0x80000000u);
}

// ---------------- zero scratch (uint4 stores, fat grid) ----------------
__global__ void kZero4(uint4* p, int n4) {
    int i = blockIdx.x * blockDim.x + threadIdx.x;
    int st = gridDim.x * blockDim.x;
    for (; i < n4; i += st) p[i] = make_uint4(0u, 0u, 0u, 0u);
}

// ---------------- pass 1: all-level LDS-privatized histogram (1 dispatch) ----------------
__global__ __launch_bounds__(1024) void kHistAll(Ptrs p, unsigned* __restrict__ hist) {
    int bx = blockIdx.x;
    int lvl = (bx < 16) ? 0 : (bx < 20) ? 1 : (bx < 21) ? 2 : (bx < 22) ? 3 : 4;
    int lb  = bx - ((lvl == 0) ? 0 : (lvl == 1) ? 16 : (lvl == 2) ? 20 : (lvl == 3) ? 21 : 22);
    int gx  = (lvl == 0) ? 16 : (lvl == 1) ? 4 : 1;
    int m   = (lvl == 0) ? 516096 : (lvl == 1) ? 129024 : (lvl == 2) ? 32256
              : (lvl == 3) ? 8064 : 2016;
    int img  = blockIdx.y;
    int task = img * NLVL + lvl;
    const float* lg = p.lg[lvl];
    __shared__ unsigned h[NB1];
    for (int i = threadIdx.x; i < NB1; i += 1024) h[i] = 0u;
    __syncthreads();
    int m4 = m >> 2;
    int chunk4 = (m4 + gx - 1) / gx;
    int start4 = lb * chunk4;
    int end4   = min(start4 + chunk4, m4);
    const float4* src = (const float4*)(lg + (size_t)img * m);
    for (int i = start4 + threadIdx.x; i < end4; i += 1024) {
        float4 v = src[i];
        atomicAdd(&h[key_of(v.x) >> L1SHIFT], 1u);
        atomicAdd(&h[key_of(v.y) >> L1SHIFT], 1u);
        atomicAdd(&h[key_of(v.z) >> L1SHIFT], 1u);
        atomicAdd(&h[key_of(v.w) >> L1SHIFT], 1u);
    }
    __syncthreads();
    unsigned* gh = hist + (size_t)task * NB1;
    for (int i = threadIdx.x; i < NB1; i += 1024) {
        unsigned c = h[i];
        if (c) atomicAdd(&gh[i], c);
    }
}

// ---------------- pass 2: find 14-bit prefix of the K-th largest ----------------
__global__ __launch_bounds__(256) void kSelectBin(const unsigned* __restrict__ hist,
                                                  unsigned* __restrict__ tinfo,
                                                  unsigned* __restrict__ cnt) {
    int task = blockIdx.x;
    const unsigned* h = hist + (size_t)task * NB1;
    __shared__ unsigned sblk[256];
    __shared__ unsigned sbin[64];
    __shared__ int sh_tb;
    __shared__ unsigned sh_rem;
    int t = threadIdx.x;
    unsigned s = 0;
    for (int i = 0; i < 64; ++i) s += h[t * 64 + i];
    sblk[t] = s;
    __syncthreads();
    if (t == 0) {
        unsigned rem = K_TOP; int tb = 0;
        for (int b = 255; b >= 0; --b) {
            if (sblk[b] < rem) rem -= sblk[b];
            else { tb = b; break; }
        }
        sh_tb = tb; sh_rem = rem;
    }
    __syncthreads();
    if (t < 64) sbin[t] = h[sh_tb * 64 + t];
    __syncthreads();
    if (t == 0) {
        unsigned rem = sh_rem; int pfx = sh_tb * 64;
        for (int b = 63; b >= 0; --b) {
            if (sbin[b] < rem) rem -= sbin[b];
            else { pfx = sh_tb * 64 + b; break; }
        }
        tinfo[task * 2]     = (unsigned)pfx;
        tinfo[task * 2 + 1] = rem;
        cnt[task] = 0u;
    }
}

// ---------------- pass 3: all-level compact (1 dispatch) ----------------
__global__ __launch_bounds__(1024) void kCompactAll(Ptrs p,
                                                    const unsigned* __restrict__ tinfo,
                                                    unsigned* __restrict__ cnt,
                                                    u64* __restrict__ compbuf) {
    int bx = blockIdx.x;
    int lvl = (bx < 32) ? 0 : (bx < 40) ? 1 : (bx < 42) ? 2 : (bx < 43) ? 3 : 4;
    int lb  = bx - ((lvl == 0) ? 0 : (lvl == 1) ? 32 : (lvl == 2) ? 40 : (lvl == 3) ? 42 : 43);
    int gx  = (lvl == 0) ? 32 : (lvl == 1) ? 8 : (lvl == 2) ? 2 : 1;
    int m   = (lvl == 0) ? 516096 : (lvl == 1) ? 129024 : (lvl == 2) ? 32256
              : (lvl == 3) ? 8064 : 2016;
    int img  = blockIdx.y;
    int task = img * NLVL + lvl;
    const float* lg = p.lg[lvl];
    unsigned pfx = tinfo[task * 2];
    __shared__ u64 stage[CAP];
    __shared__ unsigned lcnt, gbase;
    if (threadIdx.x == 0) lcnt = 0u;
    __syncthreads();
    int m4 = m >> 2;
    int chunk4 = (m4 + gx - 1) / gx;
    int start4 = lb * chunk4;
    int end4   = min(start4 + chunk4, m4);
    const float4* src = (const float4*)(lg + (size_t)img * m);
    for (int i = start4 + threadIdx.x; i < end4; i += 1024) {
        float4 v = src[i];
        int j = i * 4;
        unsigned k0 = key_of(v.x);
        unsigned k1 = key_of(v.y);
        unsigned k2 = key_of(v.z);
        unsigned k3 = key_of(v.w);
        if ((k0 >> L1SHIFT) >= pfx) {
            unsigned q = atomicAdd(&lcnt, 1u);
            if (q < CAP) stage[q] = ((u64)k0 << 32) | (unsigned)(~(unsigned)(j));
        }
        if ((k1 >> L1SHIFT) >= pfx) {
            unsigned q = atomicAdd(&lcnt, 1u);
            if (q < CAP) stage[q] = ((u64)k1 << 32) | (unsigned)(~(unsigned)(j + 1));
        }
        if ((k2 >> L1SHIFT) >= pfx) {
            unsigned q = atomicAdd(&lcnt, 1u);
            if (q < CAP) stage[q] = ((u64)k2 << 32) | (unsigned)(~(unsigned)(j + 2));
        }
        if ((k3 >> L1SHIFT) >= pfx) {
            unsigned q = atomicAdd(&lcnt, 1u);
            if (q < CAP) stage[q] = ((u64)k3 << 32) | (unsigned)(~(unsigned)(j + 3));
        }
    }
    __syncthreads();
    if (threadIdx.x == 0) gbase = atomicAdd(&cnt[task], lcnt);
    __syncthreads();
    unsigned total = min(lcnt, (unsigned)CAP);
    unsigned base  = gbase;
    for (unsigned q = threadIdx.x; q < total; q += 1024) {
        unsigned pos = base + q;
        if (pos < CAP) compbuf[(size_t)task * CAP + pos] = stage[q];
    }
}

// ---------------- pass 4: split-sort (sure/boundary), decode, valid-compact ----
__global__ __launch_bounds__(1024) void kSortSelect(
        Ptrs p,
        const unsigned* __restrict__ cnt,
        const unsigned* __restrict__ tinfo,
        const u64* __restrict__ compbuf,
        float* __restrict__ cscore,
        float4* __restrict__ cbox,
        float4* __restrict__ cobox,
        unsigned* __restrict__ cog,
        unsigned* __restrict__ vcnt) {
    int task = blockIdx.x;
    int img = task / NLVL, lvl = task % NLVL;
    int tid = threadIdx.x;
    __shared__ u64 sure[1024];
    __shared__ u64 bnd[2048];
    __shared__ unsigned cS, cB;
    if (tid == 0) { cS = 0u; cB = 0u; }
    sure[tid] = 0ULL;
    bnd[tid] = 0ULL; bnd[tid + 1024] = 0ULL;
    __syncthreads();
    int n = min((int)cnt[task], CAP);
    unsigned pfx = tinfo[task * 2];
    for (int i = tid; i < n; i += 1024) {
        u64 c = compbuf[(size_t)task * CAP + i];
        unsigned bin = (unsigned)(c >> (32 + L1SHIFT));
        if (bin > pfx) {
            unsigned q = atomicAdd(&cS, 1u);
            if (q < 1024) sure[q] = c;
        } else {
            unsigned q = atomicAdd(&cB, 1u);
            if (q < 2048) bnd[q] = c;
        }
    }
    __syncthreads();
    unsigned S = cS;
    unsigned B = cB;
    {
        u64* arr = (tid < 512) ? sure : bnd;
        int q = tid & 511;
        for (int k = 2; k <= 1024; k <<= 1) {
            for (int j = k >> 1; j > 0; j >>= 1) {
                int i = ((q & ~(j - 1)) << 1) | (q & (j - 1));
                int pp = i | j;
                u64 A = arr[i], Bv = arr[pp];
                bool up = ((i & k) == 0);
                if (up ? (A < Bv) : (A > Bv)) { arr[i] = Bv; arr[pp] = A; }
                __syncthreads();
            }
        }
    }
    if (B > 1024) {    // statistically never; full 2048 network re-sorts bnd
        for (int k = 2; k <= 2048; k <<= 1)
            for (int j = k >> 1; j > 0; j >>= 1) {
                int i = ((tid & ~(j - 1)) << 1) | (tid & (j - 1));
                int pp = i | j;
                u64 A = bnd[i], Bv = bnd[pp];
                bool up = ((i & k) == 0);
                if (up ? (A < Bv) : (A > Bv)) { bnd[i] = Bv; bnd[pp] = A; }
                __syncthreads();
            }
    }
    int r = tid;
    u64 c = 0ULL;
    if (r < K_TOP) c = (r < (int)S) ? sure[r] : ((r - (int)S < (int)B) ? bnd[r - (int)S] : 0ULL);
    __syncthreads();                 // all sure/bnd reads done (bnd reused for scan)

    const int   MS[5]     = {516096, 129024, 32256, 8064, 2016};
    const int   GW[5]     = {512, 256, 128, 64, 32};
    const float STRIDEF[5]= {4.f, 8.f, 16.f, 32.f, 64.f};
    const int   SIZEI[5]  = {32, 64, 128, 256, 512};
    float sm = NEGF, x0 = 0.f, y0 = 0.f, x1 = 0.f, y1 = 0.f;
    float b0 = 0.f, b1 = 0.f, b2 = 0.f, b3 = 0.f;
    bool valid = false;
    if (r < K_TOP) {
        int idx = (int)(~(unsigned)c);
        int m = MS[lvl];
        if ((unsigned)idx >= (unsigned)m) idx = 0;   // safety (never expected)
        const float* lg = p.lg[lvl];
        const float* dl = p.dl[lvl];
        float score = lg[(size_t)img * m + idx];
        int a   = idx % 3;
        int loc = idx / 3;
        int gw  = GW[lvl];
        int x = loc % gw, y = loc / gw;
        double ssz = (double)SIZEI[lvl];
        double arr = (a == 0) ? 0.5 : ((a == 1) ? 1.0 : 2.0);
        double wd = sqrt(ssz * ssz / arr);
        double hd = arr * wd;
        float sx = (float)x * STRIDEF[lvl];
        float sy = (float)y * STRIDEF[lvl];
        float a0 = sx + (float)(-wd * 0.5);
        float a1 = sy + (float)(-hd * 0.5);
        float a2 = sx + (float)( wd * 0.5);
        float a3 = sy + (float)( hd * 0.5);
        float aw = a2 - a0, ah = a3 - a1;
        float acx = a0 + 0.5f * aw, acy = a1 + 0.5f * ah;
        size_t db = ((size_t)img * m + idx) * 4;
        float dx = dl[db], dy = dl[db + 1], dwv = dl[db + 2], dhv = dl[db + 3];
        const float CL = 4.135166556742356f;   // log(1000/16)
        float pw = expf(fminf(dwv, CL)) * aw;
        float ph = expf(fminf(dhv, CL)) * ah;
        float pcx = dx * aw + acx;
        float pcy = dy * ah + acy;
        x0 = pcx - 0.5f * pw; y0 = pcy - 0.5f * ph;
        x1 = pcx + 0.5f * pw; y1 = pcy + 0.5f * ph;
        x0 = fminf(fmaxf(x0, 0.f), 2048.f);
        x1 = fminf(fmaxf(x1, 0.f), 2048.f);
        y0 = fminf(fmaxf(y0, 0.f), 1344.f);
        y1 = fminf(fmaxf(y1, 0.f), 1344.f);
        bool keep = ((x1 - x0) > 0.f) && ((y1 - y0) > 0.f);
        valid = keep;
        sm = score;
        float off = (float)lvl * 2049.0f;
        b0 = x0 + off; b1 = y0 + off; b2 = x1 + off; b3 = y1 + off;
    }
    // block prefix scan over valid flags (Hillis-Steele, ping-pong in bnd region)
    int* sc1 = (int*)bnd;
    int* sc2 = sc1 + 1024;
    sc1[tid] = valid ? 1 : 0;
    __syncthreads();
    int* sA = sc1; int* sB = sc2;
    for (int dd = 1; dd < 1024; dd <<= 1) {
        int v = sA[tid];
        if (tid >= dd) v += sA[tid - dd];
        sB[tid] = v;
        __syncthreads();
        int* t2 = sA; sA = sB; sB = t2;
    }
    int incl  = sA[tid];
    int total = sA[1023];
    int pos   = incl - (valid ? 1 : 0);
    if (valid) {
        int ci = img * NCAND + lvl * K_TOP + pos;
        cscore[ci] = sm;
        cbox[ci]   = make_float4(x0, y0, x1, y1);
        cobox[ci]  = make_float4(b0, b1, b2, b3);
        cog[ci]    = (unsigned)r;
    }
    if (tid == 0) vcnt[task] = (unsigned)total;
}

// ---------------- pass 5a: rank-merge, 1 block per (img,lvl), scatter to global ----
__global__ __launch_bounds__(1024) void kMergeRank(
        const float* __restrict__ cscore,
        const float4* __restrict__ cobox,
        const unsigned* __restrict__ cog,
        const unsigned* __restrict__ vcnt,
        float4* __restrict__ mobG,
        unsigned* __restrict__ midxG) {
    int task = blockIdx.x;
    int img = task / NLVL, lvl = task % NLVL;
    int tid = threadIdx.x;
    const int imgb = img * NCAND;
    __shared__ u64 compO[4 * K_TOP];    // other 4 levels' composites (32 KB)
    __shared__ int LSs[NLVL];
    if (tid < NLVL) LSs[tid] = (int)vcnt[img * NLVL + tid];
    __syncthreads();
    for (int idx = tid; idx < 4 * K_TOP; idx += 1024) {
        int q = idx / K_TOP, gl2 = idx - q * K_TOP;
        int l2 = q + (q >= lvl ? 1 : 0);
        u64 c = 0ULL;
        if (gl2 < LSs[l2]) {
            int g2 = l2 * K_TOP + gl2;
            unsigned og = (unsigned)(l2 * K_TOP) + cog[imgb + g2];
            c = ((u64)key_of(cscore[imgb + g2]) << 32) | (unsigned)(~og);
        }
        compO[idx] = c;
    }
    __syncthreads();
    int gl = tid;
    if (gl < LSs[lvl]) {
        int g = lvl * K_TOP + gl;
        float4 pref = cobox[imgb + g];             // overlap HBM with LDS searches
        unsigned og = (unsigned)(lvl * K_TOP) + cog[imgb + g];
        u64 c = ((u64)key_of(cscore[imgb + g]) << 32) | (unsigned)(~og);
        int h0v = LSs[0 + (0 >= lvl ? 1 : 0)];
        int h1v = LSs[1 + (1 >= lvl ? 1 : 0)];
        int h2v = LSs[2 + (2 >= lvl ? 1 : 0)];
        int h3v = LSs[3 + (3 >= lvl ? 1 : 0)];
        int l0 = 0, h0 = h0v;
        int l1 = 0, h1 = h1v;
        int l2 = 0, h2 = h2v;
        int l3 = 0, h3 = h3v;
#pragma unroll
        for (int step = 0; step < 10; ++step) {    // lists <= 1000 -> 10 steps
            if (l0 < h0) { int m0 = (l0 + h0) >> 1; if (compO[0 * K_TOP + m0] > c) l0 = m0 + 1; else h0 = m0; }
            if (l1 < h1) { int m1 = (l1 + h1) >> 1; if (compO[1 * K_TOP + m1] > c) l1 = m1 + 1; else h1 = m1; }
            if (l2 < h2) { int m2 = (l2 + h2) >> 1; if (compO[2 * K_TOP + m2] > c) l2 = m2 + 1; else h2 = m2; }
            if (l3 < h3) { int m3 = (l3 + h3) >> 1; if (compO[3 * K_TOP + m3] > c) l3 = m3 + 1; else h3 = m3; }
        }
        int pos = gl + l0 + l1 + l2 + l3;
        mobG[(size_t)img * NPAD + pos] = pref;
        midxG[imgb + pos] = (unsigned)g;
    }
}

// ---------------- pass 5b: greedy scan; within-word selection via MIS fixpoint ----------------
__global__ __launch_bounds__(1024) void kScan(
        const float4* __restrict__ mobG,
        const unsigned* __restrict__ midxG,
        const float* __restrict__ cscore,
        const float4* __restrict__ cbox,
        const unsigned* __restrict__ vcnt,
        float* __restrict__ out) {
    int img = blockIdx.x;
    int tid = threadIdx.x;
    int lane = tid & 63;
    int wave = tid >> 6;
    __shared__ float4 wboxS[2][64];     // double buffer (prefetch during serial)
    __shared__ u64    diagWS[64];
    __shared__ u64    partS[16];
    __shared__ float4 pboxAll[NPOST];
    __shared__ unsigned emS[NPOST];
    __shared__ int stateS[2];           // {emitted, done}
    const int imgb = img * NCAND;

    int V = 0;
    for (int l = 0; l < NLVL; ++l) V += (int)vcnt[img * NLVL + l];

    // prologue: stage word 0
    if (tid < 64 && V > 0) wboxS[0][tid] = mobG[(size_t)img * NPAD + tid];
    __syncthreads();

    int emitted = 0;
    bool done = (V == 0);
    for (int w = 0; w < NWORDS && !done; ++w) {
        int base = w * 64;
        if (base >= V) break;
        int buf = w & 1;
        // parallel phase (all 16 waves): suppression-by-emitted + own diag block
        float4 bc = wboxS[buf][lane];
        float  arc = (bc.z - bc.x) * (bc.w - bc.y);
        bool supp = false;
        for (int t = wave; t < emitted; t += 16) {
            float4 bp = pboxAll[t];
            float arp = (bp.z - bp.x) * (bp.w - bp.y);
            float ltx = fmaxf(bc.x, bp.x), lty = fmaxf(bc.y, bp.y);
            float rbx = fminf(bc.z, bp.z), rby = fminf(bc.w, bp.w);
            float wx = fmaxf(rbx - ltx, 0.f), wy = fmaxf(rby - lty, 0.f);
            float inter = wx * wy;
            float denom = (arc + arp) - inter + 1e-9f;
            supp |= (inter / denom) > 0.7f;
        }
        u64 sb = __ballot(supp);
        if (lane == 0) partS[wave] = sb;
#pragma unroll
        for (int rr = 0; rr < 4; ++rr) {
            int r = wave * 4 + rr;
            float4 bp = wboxS[buf][r];
            float arp = (bp.z - bp.x) * (bp.w - bp.y);
            float ltx = fmaxf(bc.x, bp.x), lty = fmaxf(bc.y, bp.y);
            float rbx = fminf(bc.z, bp.z), rby = fminf(bc.w, bp.w);
            float wx = fmaxf(rbx - ltx, 0.f), wy = fmaxf(rby - lty, 0.f);
            float inter = wx * wy;
            float denom = (arc + arp) - inter + 1e-9f;
            bool pred = (inter / denom) > 0.7f;
            u64 db = __ballot(pred);
            if (lane == 0) diagWS[r] = db;
        }
        __syncthreads();
        // wave 0: MIS fixpoint; wave 15: prefetch next word into other buffer
        if (wave == 0) {
            u64 dreg = diagWS[lane];           // lane's own adjacency row
            u64 smv = partS[0];
#pragma unroll
            for (int q = 1; q < 16; ++q) smv |= partS[q];
            int rem = V - base;
            u64 vmask = (rem >= 64) ? ~0ULL : ((1ULL << rem) - 1ULL);
            u64 A = (~smv) & vmask;
            u64 below = (1ULL << lane) - 1ULL;
            bool inA = (A >> lane) & 1ULL;
            u64 S = A;
            while (true) {
                bool pred = inA && ((dreg & S & below) == 0ULL);
                u64 Snew = __ballot(pred);
                if (Snew == S) break;
                S = Snew;
            }
            int cnt = __popcll(S);
            int rem0 = NPOST - emitted;
            int rank = __popcll(S & below);
            bool kept = ((S >> lane) & 1ULL) && (rank < rem0);
            if (kept) {
                emS[emitted + rank]     = (unsigned)(base + lane);
                pboxAll[emitted + rank] = wboxS[buf][lane];
            }
            if (lane == 0) {
                int emadd = (cnt < rem0) ? cnt : rem0;
                stateS[0] = emitted + emadd;
                stateS[1] = (cnt >= rem0) ? 1 : 0;
            }
        } else if (wave == 15) {
            int nb = base + 64;
            if (nb < V && (w + 1) < NWORDS)
                wboxS[buf ^ 1][lane] = mobG[(size_t)img * NPAD + nb + lane];
        }
        __syncthreads();
        emitted = stateS[0];
        done = (stateS[1] != 0);
    }
    __syncthreads();
    // ---- parallel output gather ----
    for (int rr = tid; rr < NPOST; rr += 1024) {
        float* o = out + ((size_t)img * NPOST + rr) * 5;
        if (rr < emitted) {
            unsigned i = emS[rr];
            unsigned g = midxG[imgb + i];
            float4 cb = cbox[imgb + g];
            float sc = cscore[imgb + g];
            o[0] = cb.x; o[1] = cb.y; o[2] = cb.z; o[3] = cb.w; o[4] = sc;
        } else {
            o[0] = 0.f; o[1] = 0.f; o[2] = 0.f; o[3] = 0.f; o[4] = NEGF;
        }
    }
}

extern "C" void kernel_launch(void* const* d_in, const int* in_sizes, int n_in,
                              void* d_out, int out_size, void* d_ws, size_t ws_size,
                              hipStream_t stream) {
    Ptrs P;
    for (int l = 0; l < 5; ++l) {
        P.lg[l] = (const float*)d_in[2 * l];
        P.dl[l] = (const float*)d_in[2 * l + 1];
    }
    char* w = (char*)d_ws;
    size_t off = 0;
    auto alloc = [&](size_t bytes) -> void* {
        void* pp = (void*)(w + off);
        off = (off + bytes + 255) & ~(size_t)255;
        return pp;
    };
    unsigned* hist  = (unsigned*)alloc((size_t)NTASK * NB1 * 4);
    unsigned* tinfo = (unsigned*)alloc(NTASK * 2 * 4);
    unsigned* cnt   = (unsigned*)alloc(NTASK * 4);
    u64* compb      = (u64*)alloc((size_t)NTASK * CAP * 8);
    float*  cscore  = (float*)alloc((size_t)NTASK * K_TOP * 4);
    float4* cbox    = (float4*)alloc((size_t)NTASK * K_TOP * 16);
    float4* cobox   = (float4*)alloc((size_t)NTASK * K_TOP * 16);
    unsigned* cog   = (unsigned*)alloc((size_t)NTASK * K_TOP * 4);
    unsigned* vcnt  = (unsigned*)alloc(NTASK * 4);
    float4* mobG    = (float4*)alloc((size_t)NIMG * NPAD * 16);
    unsigned* midxG = (unsigned*)alloc((size_t)NIMG * NCAND * 4);
    (void)in_sizes; (void)n_in; (void)out_size; (void)ws_size;

    int n4 = (NTASK * NB1) / 4;          // 163840 uint4s
    kZero4<<<512, 256, 0, stream>>>((uint4*)hist, n4);
    kHistAll<<<dim3(23, NIMG), 1024, 0, stream>>>(P, hist);
    kSelectBin<<<NTASK, 256, 0, stream>>>(hist, tinfo, cnt);
    kCompactAll<<<dim3(44, NIMG), 1024, 0, stream>>>(P, tinfo, cnt, compb);
    kSortSelect<<<NTASK, 1024, 0, stream>>>(P, cnt, tinfo, compb,
                                            cscore, cbox, cobox, cog, vcnt);
    kMergeRank<<<NTASK, 1024, 0, stream>>>(cscore, cobox, cog, vcnt, mobG, midxG);
    kScan<<<NIMG, 1024, 0, stream>>>(mobG, midxG, cscore, cbox, vcnt,
                                     (float*)d_out);
}

// Round 19
// 82.831 us; speedup vs baseline: 8.7068x; 1.0120x over previous
//
#include <hip/hip_runtime.h>
#include <cstdint>
#include <cstddef>

#define NB1      16384      // 2^14 first-level radix bins
#define L1SHIFT  18         // key >> 18 -> 14-bit bin
#define K_TOP    1000
#define NCAND    5000
#define NIMG     8
#define NLVL     5
#define NTASK    40
#define NPOST    300
#define NEGF     (-1e9f)
#define NWORDS   79         // ceil(5000/64)
#define NPAD     (NWORDS * 64)
#define NSLOT    23         // per-image hist/compact blocks: 16+4+1+1+1
#define SCAP     2048       // per-slice winner cap

typedef unsigned long long u64;

struct Ptrs {
    const float* lg[5];
    const float* dl[5];
};

__device__ __forceinline__ unsigned key_of(float f) {
    unsigned u = __float_as_uint(f);
    return (u & 0x80000000u) ? ~u : (u | 0x80000000u);
}

__device__ __forceinline__ void lvl_of_slot(int bx, int& lvl, int& lb, int& gx, int& m) {
    lvl = (bx < 16) ? 0 : (bx < 20) ? 1 : (bx < 21) ? 2 : (bx < 22) ? 3 : 4;
    const int S0[5] = {0, 16, 20, 21, 22};
    const int GX[5] = {16, 4, 1, 1, 1};
    const int MS[5] = {516096, 129024, 32256, 8064, 2016};
    lb = bx - S0[lvl];
    gx = GX[lvl];
    m  = MS[lvl];
}

// ---- pfx from per-slice histograms; exact replica of serial suffix logic ----
// Needs LDS: sblk[256], sS[256], tmp[8] (unsigned). Returns uniform pfx.
__device__ int compute_pfx(const unsigned* __restrict__ histC,
                           const unsigned* __restrict__ histF,
                           int img, int lvl,
                           unsigned* sblk, unsigned* sS, unsigned* tmp) {
    const int S0[5] = {0, 16, 20, 21, 22};
    const int NS[5] = {16, 4, 1, 1, 1};
    int s0 = S0[lvl], ns = NS[lvl];
    int tid = threadIdx.x, lane = tid & 63, wv = tid >> 6;
    if (tid < 256) {
        unsigned v = 0;
        for (int s = 0; s < ns; ++s)
            v += histC[((size_t)img * NSLOT + (s0 + s)) * 256 + tid];
        sblk[tid] = v;
    }
    __syncthreads();
    unsigned SSv = 0;
    if (tid < 256) {
        SSv = sblk[tid];
        for (int d = 1; d < 64; d <<= 1) {
            unsigned o = __shfl_down(SSv, d, 64);
            if (lane < 64 - d) SSv += o;
        }
        unsigned wtot = __shfl(SSv, 0, 64);
        if (lane == 0) tmp[wv] = wtot;
    }
    __syncthreads();
    if (tid < 256) {
        unsigned add = 0;
        for (int w2 = wv + 1; w2 < 4; ++w2) add += tmp[w2];
        SSv += add;
        sS[tid] = SSv;
    }
    __syncthreads();
    if (tid < 256) {
        bool pred = (SSv >= (unsigned)K_TOP);
        u64 mk = __ballot(pred);
        if (lane == 0)
            ((int*)tmp)[4 + wv] = mk ? (wv * 64 + (63 - __builtin_clzll(mk))) : -1;
    }
    __syncthreads();
    int c0 = ((int*)tmp)[4], c1 = ((int*)tmp)[5];
    int c2 = ((int*)tmp)[6], c3 = ((int*)tmp)[7];
    int tb = max(max(c0, c1), max(c2, c3));
    if (tid < 64) {
        unsigned rem = (unsigned)K_TOP - (sS[tb] - sblk[tb]);
        unsigned F = 0;
        for (int s = 0; s < ns; ++s)
            F += histF[(((size_t)img * NSLOT + (s0 + s)) << 14) + tb * 64 + tid];
        for (int d = 1; d < 64; d <<= 1) {
            unsigned o = __shfl_down(F, d, 64);
            if (lane < 64 - d) F += o;
        }
        bool pred = (F >= rem);
        u64 mk = __ballot(pred);
        if (lane == 0) ((int*)tmp)[0] = tb * 64 + (63 - __builtin_clzll(mk));
    }
    __syncthreads();
    int pfx = ((int*)tmp)[0];
    __syncthreads();
    return pfx;
}

// ---------------- pass 1: per-slice histogram, plain stores, no zero needed ----
__global__ __launch_bounds__(1024) void kHist23(Ptrs p,
                                                unsigned* __restrict__ histF,
                                                unsigned* __restrict__ histC) {
    int lvl, lb, gx, m;
    lvl_of_slot(blockIdx.x, lvl, lb, gx, m);
    int img = blockIdx.y;
    size_t slice = (size_t)img * NSLOT + blockIdx.x;
    const float* lg = p.lg[lvl];
    __shared__ unsigned h[NB1];
    for (int i = threadIdx.x; i < NB1; i += 1024) h[i] = 0u;
    __syncthreads();
    int m4 = m >> 2;
    int chunk4 = (m4 + gx - 1) / gx;
    int start4 = lb * chunk4;
    int end4   = min(start4 + chunk4, m4);
    const float4* src = (const float4*)(lg + (size_t)img * m);
    for (int i = start4 + threadIdx.x; i < end4; i += 1024) {
        float4 v = src[i];
        atomicAdd(&h[key_of(v.x) >> L1SHIFT], 1u);
        atomicAdd(&h[key_of(v.y) >> L1SHIFT], 1u);
        atomicAdd(&h[key_of(v.z) >> L1SHIFT], 1u);
        atomicAdd(&h[key_of(v.w) >> L1SHIFT], 1u);
    }
    __syncthreads();
    unsigned* gf = histF + (slice << 14);
    for (int i = threadIdx.x; i < NB1; i += 1024) gf[i] = h[i];
    if (threadIdx.x < 256) {
        int t = threadIdx.x;
        unsigned v = 0;
        for (int ii = 0; ii < 64; ++ii) v += h[t * 64 + ((ii + t) & 63)];  // rotated: no bank conflict
        histC[slice * 256 + t] = v;
    }
}

// ---------------- pass 2: compact winners into private slice (no global atomics) ----
__global__ __launch_bounds__(1024) void kCompact23(Ptrs p,
                                                   const unsigned* __restrict__ histF,
                                                   const unsigned* __restrict__ histC,
                                                   u64* __restrict__ compS,
                                                   unsigned* __restrict__ bcnt) {
    int lvl, lb, gx, m;
    lvl_of_slot(blockIdx.x, lvl, lb, gx, m);
    int img = blockIdx.y;
    size_t slice = (size_t)img * NSLOT + blockIdx.x;
    const float* lg = p.lg[lvl];
    __shared__ unsigned sblk[256], sS[256], tmp[8];
    __shared__ u64 stage[SCAP];
    __shared__ unsigned lcnt;
    int pfxi = compute_pfx(histC, histF, img, lvl, sblk, sS, tmp);
    unsigned pfx = (unsigned)pfxi;
    if (threadIdx.x == 0) lcnt = 0u;
    __syncthreads();
    int m4 = m >> 2;
    int chunk4 = (m4 + gx - 1) / gx;
    int start4 = lb * chunk4;
    int end4   = min(start4 + chunk4, m4);
    const float4* src = (const float4*)(lg + (size_t)img * m);
    for (int i = start4 + threadIdx.x; i < end4; i += 1024) {
        float4 v = src[i];
        int j = i * 4;
        unsigned k0 = key_of(v.x);
        unsigned k1 = key_of(v.y);
        unsigned k2 = key_of(v.z);
        unsigned k3 = key_of(v.w);
        if ((k0 >> L1SHIFT) >= pfx) {
            unsigned q = atomicAdd(&lcnt, 1u);
            if (q < SCAP) stage[q] = ((u64)k0 << 32) | (unsigned)(~(unsigned)(j));
        }
        if ((k1 >> L1SHIFT) >= pfx) {
            unsigned q = atomicAdd(&lcnt, 1u);
            if (q < SCAP) stage[q] = ((u64)k1 << 32) | (unsigned)(~(unsigned)(j + 1));
        }
        if ((k2 >> L1SHIFT) >= pfx) {
            unsigned q = atomicAdd(&lcnt, 1u);
            if (q < SCAP) stage[q] = ((u64)k2 << 32) | (unsigned)(~(unsigned)(j + 2));
        }
        if ((k3 >> L1SHIFT) >= pfx) {
            unsigned q = atomicAdd(&lcnt, 1u);
            if (q < SCAP) stage[q] = ((u64)k3 << 32) | (unsigned)(~(unsigned)(j + 3));
        }
    }
    __syncthreads();
    unsigned total = min(lcnt, (unsigned)SCAP);
    for (unsigned q = threadIdx.x; q < total; q += 1024)
        compS[slice * SCAP + q] = stage[q];
    if (threadIdx.x == 0) bcnt[slice] = total;
}

// ---------------- pass 3: split-sort (register bitonic + shfl), decode, compact ----
__global__ __launch_bounds__(1024) void kSortSelect(
        Ptrs p,
        const unsigned* __restrict__ histF,
        const unsigned* __restrict__ histC,
        const u64* __restrict__ compS,
        const unsigned* __restrict__ bcnt,
        float* __restrict__ cscore,
        float4* __restrict__ cbox,
        float4* __restrict__ cobox,
        unsigned* __restrict__ cog,
        unsigned* __restrict__ vcnt) {
    int task = blockIdx.x;
    int img = task / NLVL, lvl = task % NLVL;
    int tid = threadIdx.x, lane = tid & 63, wv = tid >> 6;
    __shared__ unsigned sblk[256], sS[256], tmp[8];
    __shared__ u64 sure[1024];
    __shared__ u64 bnd[2048];
    __shared__ unsigned cS, cB;
    __shared__ int wTot[16];
    int pfxi = compute_pfx(histC, histF, img, lvl, sblk, sS, tmp);
    unsigned pfx = (unsigned)pfxi;
    if (tid == 0) { cS = 0u; cB = 0u; }
    sure[tid] = 0ULL;
    bnd[tid] = 0ULL; bnd[tid + 1024] = 0ULL;
    __syncthreads();
    const int S0[5] = {0, 16, 20, 21, 22};
    const int NS[5] = {16, 4, 1, 1, 1};
    for (int s = 0; s < NS[lvl]; ++s) {
        size_t slice = (size_t)img * NSLOT + S0[lvl] + s;
        unsigned csn = bcnt[slice];
        for (int idx = tid; idx < (int)csn; idx += 1024) {
            u64 c = compS[slice * SCAP + idx];
            unsigned bin = (unsigned)(c >> (32 + L1SHIFT));
            if (bin > pfx) {
                unsigned q = atomicAdd(&cS, 1u);
                if (q < 1024) sure[q] = c;
            } else {
                unsigned q = atomicAdd(&cB, 1u);
                if (q < 2048) bnd[q] = c;
            }
        }
    }
    __syncthreads();
    unsigned S = cS;
    unsigned B = cB;
    // register bitonic (desc), 1 elem/thread per array; shfl for j<64, LDS for j>=64
    u64 xs = sure[tid], xb = bnd[tid];
    for (int k = 2; k <= 1024; k <<= 1) {
        for (int j = k >> 1; j > 0; j >>= 1) {
            bool up   = ((tid & k) == 0);
            bool iLow = ((tid & j) == 0);
            u64 ys, yb;
            if (j >= 64) {
                sure[tid] = xs; bnd[tid] = xb;
                __syncthreads();
                ys = sure[tid ^ j]; yb = bnd[tid ^ j];
                __syncthreads();
            } else {
                ys = __shfl_xor(xs, j, 64);
                yb = __shfl_xor(xb, j, 64);
            }
            bool takeMax = (iLow == up);
            xs = takeMax ? ((xs > ys) ? xs : ys) : ((xs < ys) ? xs : ys);
            xb = takeMax ? ((xb > yb) ? xb : yb) : ((xb < yb) ? xb : yb);
        }
    }
    sure[tid] = xs; bnd[tid] = xb;
    __syncthreads();
    if (B > 1024) {    // statistically never; full 2048 network re-sorts bnd
        for (int k = 2; k <= 2048; k <<= 1)
            for (int j = k >> 1; j > 0; j >>= 1) {
                int i = ((tid & ~(j - 1)) << 1) | (tid & (j - 1));
                int pp = i | j;
                u64 A = bnd[i], Bv = bnd[pp];
                bool up = ((i & k) == 0);
                if (up ? (A < Bv) : (A > Bv)) { bnd[i] = Bv; bnd[pp] = A; }
                __syncthreads();
            }
    }
    int r = tid;
    u64 c = 0ULL;
    if (r < K_TOP) c = (r < (int)S) ? sure[r] : ((r - (int)S < (int)B) ? bnd[r - (int)S] : 0ULL);

    const int   MS[5]     = {516096, 129024, 32256, 8064, 2016};
    const int   GW[5]     = {512, 256, 128, 64, 32};
    const float STRIDEF[5]= {4.f, 8.f, 16.f, 32.f, 64.f};
    const int   SIZEI[5]  = {32, 64, 128, 256, 512};
    float sm = NEGF, x0 = 0.f, y0 = 0.f, x1 = 0.f, y1 = 0.f;
    float b0 = 0.f, b1 = 0.f, b2 = 0.f, b3 = 0.f;
    bool valid = false;
    if (r < K_TOP) {
        int idx = (int)(~(unsigned)c);
        int m = MS[lvl];
        if ((unsigned)idx >= (unsigned)m) idx = 0;   // safety (never expected)
        const float* lg = p.lg[lvl];
        const float* dl = p.dl[lvl];
        float score = lg[(size_t)img * m + idx];
        int a   = idx % 3;
        int loc = idx / 3;
        int gw  = GW[lvl];
        int x = loc % gw, y = loc / gw;
        double ssz = (double)SIZEI[lvl];
        double arr = (a == 0) ? 0.5 : ((a == 1) ? 1.0 : 2.0);
        double wd = sqrt(ssz * ssz / arr);
        double hd = arr * wd;
        float sx = (float)x * STRIDEF[lvl];
        float sy = (float)y * STRIDEF[lvl];
        float a0 = sx + (float)(-wd * 0.5);
        float a1 = sy + (float)(-hd * 0.5);
        float a2 = sx + (float)( wd * 0.5);
        float a3 = sy + (float)( hd * 0.5);
        float aw = a2 - a0, ah = a3 - a1;
        float acx = a0 + 0.5f * aw, acy = a1 + 0.5f * ah;
        size_t db = ((size_t)img * m + idx) * 4;
        float dx = dl[db], dy = dl[db + 1], dwv = dl[db + 2], dhv = dl[db + 3];
        const float CL = 4.135166556742356f;   // log(1000/16)
        float pw = expf(fminf(dwv, CL)) * aw;
        float ph = expf(fminf(dhv, CL)) * ah;
        float pcx = dx * aw + acx;
        float pcy = dy * ah + acy;
        x0 = pcx - 0.5f * pw; y0 = pcy - 0.5f * ph;
        x1 = pcx + 0.5f * pw; y1 = pcy + 0.5f * ph;
        x0 = fminf(fmaxf(x0, 0.f), 2048.f);
        x1 = fminf(fmaxf(x1, 0.f), 2048.f);
        y0 = fminf(fmaxf(y0, 0.f), 1344.f);
        y1 = fminf(fmaxf(y1, 0.f), 1344.f);
        bool keep = ((x1 - x0) > 0.f) && ((y1 - y0) > 0.f);
        valid = keep;
        sm = score;
        float off = (float)lvl * 2049.0f;
        b0 = x0 + off; b1 = y0 + off; b2 = x1 + off; b3 = y1 + off;
    }
    // ballot-based valid compaction (exclusive pos, total)
    u64 vm = __ballot(valid);
    int lanePre = (int)__popcll(vm & ((1ULL << lane) - 1ULL));
    if (lane == 0) wTot[wv] = (int)__popcll(vm);
    __syncthreads();
    int offset = 0, total = 0;
    for (int w2 = 0; w2 < 16; ++w2) {
        int t2 = wTot[w2];
        total += t2;
        if (w2 < wv) offset += t2;
    }
    int pos = offset + lanePre;
    if (valid) {
        int ci = img * NCAND + lvl * K_TOP + pos;
        cscore[ci] = sm;
        cbox[ci]   = make_float4(x0, y0, x1, y1);
        cobox[ci]  = make_float4(b0, b1, b2, b3);
        cog[ci]    = (unsigned)r;
    }
    if (tid == 0) vcnt[task] = (unsigned)total;
}

// ---------------- pass 4: rank-merge, 1 block per (img,lvl), scatter to global ----
__global__ __launch_bounds__(1024) void kMergeRank(
        const float* __restrict__ cscore,
        const float4* __restrict__ cobox,
        const unsigned* __restrict__ cog,
        const unsigned* __restrict__ vcnt,
        float4* __restrict__ mobG,
        unsigned* __restrict__ midxG) {
    int task = blockIdx.x;
    int img = task / NLVL, lvl = task % NLVL;
    int tid = threadIdx.x;
    const int imgb = img * NCAND;
    __shared__ u64 compO[4 * K_TOP];    // other 4 levels' composites (32 KB)
    __shared__ int LSs[NLVL];
    if (tid < NLVL) LSs[tid] = (int)vcnt[img * NLVL + tid];
    __syncthreads();
    for (int idx = tid; idx < 4 * K_TOP; idx += 1024) {
        int q = idx / K_TOP, gl2 = idx - q * K_TOP;
        int l2 = q + (q >= lvl ? 1 : 0);
        u64 c = 0ULL;
        if (gl2 < LSs[l2]) {
            int g2 = l2 * K_TOP + gl2;
            unsigned og = (unsigned)(l2 * K_TOP) + cog[imgb + g2];
            c = ((u64)key_of(cscore[imgb + g2]) << 32) | (unsigned)(~og);
        }
        compO[idx] = c;
    }
    __syncthreads();
    int gl = tid;
    if (gl < LSs[lvl]) {
        int g = lvl * K_TOP + gl;
        float4 pref = cobox[imgb + g];             // overlap HBM with LDS searches
        unsigned og = (unsigned)(lvl * K_TOP) + cog[imgb + g];
        u64 c = ((u64)key_of(cscore[imgb + g]) << 32) | (unsigned)(~og);
        int l0 = 0, h0 = LSs[0 + (0 >= lvl ? 1 : 0)];
        int l1 = 0, h1 = LSs[1 + (1 >= lvl ? 1 : 0)];
        int l2 = 0, h2 = LSs[2 + (2 >= lvl ? 1 : 0)];
        int l3 = 0, h3 = LSs[3 + (3 >= lvl ? 1 : 0)];
#pragma unroll
        for (int step = 0; step < 10; ++step) {    // lists <= 1000 -> 10 steps
            if (l0 < h0) { int m0 = (l0 + h0) >> 1; if (compO[0 * K_TOP + m0] > c) l0 = m0 + 1; else h0 = m0; }
            if (l1 < h1) { int m1 = (l1 + h1) >> 1; if (compO[1 * K_TOP + m1] > c) l1 = m1 + 1; else h1 = m1; }
            if (l2 < h2) { int m2 = (l2 + h2) >> 1; if (compO[2 * K_TOP + m2] > c) l2 = m2 + 1; else h2 = m2; }
            if (l3 < h3) { int m3 = (l3 + h3) >> 1; if (compO[3 * K_TOP + m3] > c) l3 = m3 + 1; else h3 = m3; }
        }
        int pos = gl + l0 + l1 + l2 + l3;
        mobG[(size_t)img * NPAD + pos] = pref;
        midxG[imgb + pos] = (unsigned)g;
    }
}

// ---------------- pass 5: greedy scan; within-word selection via MIS fixpoint ----------------
__global__ __launch_bounds__(1024) void kScan(
        const float4* __restrict__ mobG,
        const unsigned* __restrict__ midxG,
        const float* __restrict__ cscore,
        const float4* __restrict__ cbox,
        const unsigned* __restrict__ vcnt,
        float* __restrict__ out) {
    int img = blockIdx.x;
    int tid = threadIdx.x;
    int lane = tid & 63;
    int wave = tid >> 6;
    __shared__ float4 wboxS[2][64];     // double buffer (prefetch during serial)
    __shared__ u64    diagWS[64];
    __shared__ u64    partS[16];
    __shared__ float4 pboxAll[NPOST];
    __shared__ unsigned emS[NPOST];
    __shared__ int stateS[2];           // {emitted, done}
    const int imgb = img * NCAND;

    int V = 0;
    for (int l = 0; l < NLVL; ++l) V += (int)vcnt[img * NLVL + l];

    if (tid < 64 && V > 0) wboxS[0][tid] = mobG[(size_t)img * NPAD + tid];
    __syncthreads();

    int emitted = 0;
    bool done = (V == 0);
    for (int w = 0; w < NWORDS && !done; ++w) {
        int base = w * 64;
        if (base >= V) break;
        int buf = w & 1;
        float4 bc = wboxS[buf][lane];
        float  arc = (bc.z - bc.x) * (bc.w - bc.y);
        bool supp = false;
        for (int t = wave; t < emitted; t += 16) {
            float4 bp = pboxAll[t];
            float arp = (bp.z - bp.x) * (bp.w - bp.y);
            float ltx = fmaxf(bc.x, bp.x), lty = fmaxf(bc.y, bp.y);
            float rbx = fminf(bc.z, bp.z), rby = fminf(bc.w, bp.w);
            float wx = fmaxf(rbx - ltx, 0.f), wy = fmaxf(rby - lty, 0.f);
            float inter = wx * wy;
            float denom = (arc + arp) - inter + 1e-9f;
            supp |= (inter / denom) > 0.7f;
        }
        u64 sb = __ballot(supp);
        if (lane == 0) partS[wave] = sb;
#pragma unroll
        for (int rr = 0; rr < 4; ++rr) {
            int r = wave * 4 + rr;
            float4 bp = wboxS[buf][r];
            float arp = (bp.z - bp.x) * (bp.w - bp.y);
            float ltx = fmaxf(bc.x, bp.x), lty = fmaxf(bc.y, bp.y);
            float rbx = fminf(bc.z, bp.z), rby = fminf(bc.w, bp.w);
            float wx = fmaxf(rbx - ltx, 0.f), wy = fmaxf(rby - lty, 0.f);
            float inter = wx * wy;
            float denom = (arc + arp) - inter + 1e-9f;
            bool pred = (inter / denom) > 0.7f;
            u64 db = __ballot(pred);
            if (lane == 0) diagWS[r] = db;
        }
        __syncthreads();
        if (wave == 0) {
            u64 dreg = diagWS[lane];           // lane's own adjacency row (symmetric)
            u64 smv = partS[0];
#pragma unroll
            for (int q = 1; q < 16; ++q) smv |= partS[q];
            int rem = V - base;
            u64 vmask = (rem >= 64) ? ~0ULL : ((1ULL << rem) - 1ULL);
            u64 A = (~smv) & vmask;
            u64 below = (1ULL << lane) - 1ULL;
            bool inA = (A >> lane) & 1ULL;
            u64 S = A;
            while (true) {
                bool pred = inA && ((dreg & S & below) == 0ULL);
                u64 Snew = __ballot(pred);
                if (Snew == S) break;
                S = Snew;
            }
            int cnt = __popcll(S);
            int rem0 = NPOST - emitted;
            int rank = __popcll(S & below);
            bool kept = ((S >> lane) & 1ULL) && (rank < rem0);
            if (kept) {
                emS[emitted + rank]     = (unsigned)(base + lane);
                pboxAll[emitted + rank] = wboxS[buf][lane];
            }
            if (lane == 0) {
                int emadd = (cnt < rem0) ? cnt : rem0;
                stateS[0] = emitted + emadd;
                stateS[1] = (cnt >= rem0) ? 1 : 0;
            }
        } else if (wave == 15) {
            int nb = base + 64;
            if (nb < V && (w + 1) < NWORDS)
                wboxS[buf ^ 1][lane] = mobG[(size_t)img * NPAD + nb + lane];
        }
        __syncthreads();
        emitted = stateS[0];
        done = (stateS[1] != 0);
    }
    __syncthreads();
    for (int rr = tid; rr < NPOST; rr += 1024) {
        float* o = out + ((size_t)img * NPOST + rr) * 5;
        if (rr < emitted) {
            unsigned i = emS[rr];
            unsigned g = midxG[imgb + i];
            float4 cb = cbox[imgb + g];
            float sc = cscore[imgb + g];
            o[0] = cb.x; o[1] = cb.y; o[2] = cb.z; o[3] = cb.w; o[4] = sc;
        } else {
            o[0] = 0.f; o[1] = 0.f; o[2] = 0.f; o[3] = 0.f; o[4] = NEGF;
        }
    }
}

extern "C" void kernel_launch(void* const* d_in, const int* in_sizes, int n_in,
                              void* d_out, int out_size, void* d_ws, size_t ws_size,
                              hipStream_t stream) {
    Ptrs P;
    for (int l = 0; l < 5; ++l) {
        P.lg[l] = (const float*)d_in[2 * l];
        P.dl[l] = (const float*)d_in[2 * l + 1];
    }
    char* w = (char*)d_ws;
    size_t off = 0;
    auto alloc = [&](size_t bytes) -> void* {
        void* pp = (void*)(w + off);
        off = (off + bytes + 255) & ~(size_t)255;
        return pp;
    };
    unsigned* histF = (unsigned*)alloc((size_t)NIMG * NSLOT * NB1 * 4);   // 12.06 MB
    unsigned* histC = (unsigned*)alloc((size_t)NIMG * NSLOT * 256 * 4);
    unsigned* bcnt  = (unsigned*)alloc((size_t)NIMG * NSLOT * 4);
    u64* compS      = (u64*)alloc((size_t)NIMG * NSLOT * SCAP * 8);       // 3.01 MB
    float*  cscore  = (float*)alloc((size_t)NTASK * K_TOP * 4);
    float4* cbox    = (float4*)alloc((size_t)NTASK * K_TOP * 16);
    float4* cobox   = (float4*)alloc((size_t)NTASK * K_TOP * 16);
    unsigned* cog   = (unsigned*)alloc((size_t)NTASK * K_TOP * 4);
    unsigned* vcnt  = (unsigned*)alloc(NTASK * 4);
    float4* mobG    = (float4*)alloc((size_t)NIMG * NPAD * 16);
    unsigned* midxG = (unsigned*)alloc((size_t)NIMG * NCAND * 4);
    (void)in_sizes; (void)n_in; (void)out_size; (void)ws_size;

    kHist23<<<dim3(NSLOT, NIMG), 1024, 0, stream>>>(P, histF, histC);
    kCompact23<<<dim3(NSLOT, NIMG), 1024, 0, stream>>>(P, histF, histC, compS, bcnt);
    kSortSelect<<<NTASK, 1024, 0, stream>>>(P, histF, histC, compS, bcnt,
                                            cscore, cbox, cobox, cog, vcnt);
    kMergeRank<<<NTASK, 1024, 0, stream>>>(cscore, cobox, cog, vcnt, mobG, midxG);
    kScan<<<NIMG, 1024, 0, stream>>>(mobG, midxG, cscore, cbox, vcnt,
                                     (float*)d_out);
}